// Round 3
// baseline (1131.823 us; speedup 1.0000x reference)
//
#include <hip/hip_runtime.h>
#include <hip/hip_fp16.h>
#include <stdint.h>

#define N_NODES 50000
#define FIN_D   100
#define E_EDGES 800000
#define NRELS   200
#define B_BATCH 512
#define HDIM    100

__device__ __forceinline__ unsigned short f2bf(float f){
  unsigned int x = __builtin_bit_cast(unsigned int, f);
  unsigned int lsb = (x >> 16) & 1u;
  x += 0x7fffu + lsb;
  return (unsigned short)(x >> 16);
}
// float-tensor load: fdt 2=fp16, 1=bf16, 0=f32
__device__ __forceinline__ float ldf(const void* p, size_t i, int fdt){
  if (fdt == 2) return __half2float(((const __half*)p)[i]);
  if (fdt == 1){ unsigned int x = ((unsigned int)((const unsigned short*)p)[i]) << 16;
                 return __builtin_bit_cast(float, x); }
  return ((const float*)p)[i];
}
// output store, same dtype as inputs
__device__ __forceinline__ void stf(void* p, size_t i, float v, int fdt){
  if (fdt == 2) ((__half*)p)[i] = __float2half_rn(v);
  else if (fdt == 1) ((unsigned short*)p)[i] = f2bf(v);
  else ((float*)p)[i] = v;
}
// integer-tensor load: i64 flag
__device__ __forceinline__ int ild(const void* p, size_t i, int i64){
  return i64 ? (int)((const long long*)p)[i] : ((const int*)p)[i];
}

// block-wide reduce of C per-thread values -> outr[C] in LDS (synced)
template<int C>
__device__ __forceinline__ void blockRed(float* v, float* scr /*[4*C]*/, float* outr /*[C]*/){
  #pragma unroll
  for (int i = 0; i < C; ++i){
    #pragma unroll
    for (int o = 1; o < 64; o <<= 1) v[i] += __shfl_xor(v[i], o);
  }
  const int w = threadIdx.x >> 6, l = threadIdx.x & 63;
  if (l == 0){
    #pragma unroll
    for (int i = 0; i < C; ++i) scr[w*C + i] = v[i];
  }
  __syncthreads();
  if ((int)threadIdx.x < C)
    outr[threadIdx.x] = scr[threadIdx.x] + scr[C+threadIdx.x] + scr[2*C+threadIdx.x] + scr[3*C+threadIdx.x];
  __syncthreads();
}

// ---------------- dtype probes ----------------
__global__ void k_probe(const unsigned short* __restrict__ eh, const unsigned int* __restrict__ ew,
                        const unsigned int* __restrict__ elw, int* __restrict__ ifl){
  int t = threadIdx.x;   // 64 lanes
  int cF = 0, cB = 0, c32 = 0;
  #pragma unroll
  for (int j = 0; j < 4; ++j){
    unsigned short u = eh[4*t + j];
    {
      int e5 = (u >> 10) & 31, m = u & 1023;
      float v = (e5 == 0) ? ldexpf((float)m, -24) : ldexpf(1.f + m/1024.f, e5 - 15);
      if (v >= 0.004f && v <= 0.30f) cF++;
    }
    {
      unsigned int x = ((unsigned int)(u & 0x7FFF)) << 16;
      float v = __builtin_bit_cast(float, x);
      if (v >= 0.004f && v <= 0.30f) cB++;
    }
  }
  #pragma unroll
  for (int j = 0; j < 2; ++j){
    unsigned int w = ew[2*t + j] & 0x7FFFFFFFu;
    float v = __builtin_bit_cast(float, w);
    if (v >= 0.004f && v <= 0.30f) c32++;
  }
  for (int o = 1; o < 64; o <<= 1){
    cF += __shfl_xor(cF, o); cB += __shfl_xor(cB, o); c32 += __shfl_xor(c32, o);
  }
  int z = (elw[2*t + 1] == 0u) ? 1 : 0;
  unsigned long long mb = __ballot(z);
  if (t == 0){
    int fdt;
    if (c32 >= 96) fdt = 0;
    else fdt = (cB > cF) ? 1 : 2;
    ifl[1] = fdt;
    ifl[0] = (__popcll(mb) >= 60) ? 1 : 0;
  }
}

// ---------------- setup ----------------
__global__ void k_fillm(int* __restrict__ p, int v, int n){
  int i = blockIdx.x * blockDim.x + threadIdx.x;
  if (i < n) p[i] = v;
}
__global__ void k_cvtb(const void* __restrict__ binp, const int* __restrict__ ifl, int* __restrict__ b32){
  int i = blockIdx.x*256 + threadIdx.x;
  if (i >= B_BATCH*4) return;
  b32[i] = ild(binp, i, ifl[0]);
}
__global__ void k_mset(const int* __restrict__ b32, int* __restrict__ midx){
  int i = blockIdx.x*256 + threadIdx.x;
  if (i >= B_BATCH) return;
  midx[b32[i*4 + 2]] = i;
}
// M2f[r][j] = rtab[edge_type[r]] @ W_rel
__global__ void k_m2f(const void* __restrict__ rtab, const void* __restrict__ wrel,
                      const void* __restrict__ et, const int* __restrict__ ifl, float* __restrict__ M2){
  int idx = blockIdx.x*256 + threadIdx.x;
  if (idx >= 200*200) return;
  int fdt = ifl[1];
  int r = idx / 200, j = idx % 200;
  int g = ild(et, r, ifl[0]);
  float s = 0.f;
  for (int k = 0; k < 100; ++k) s += ldf(rtab, (size_t)g*100 + k, fdt) * ldf(wrel, (size_t)k*200 + j, fdt);
  M2[idx] = s;
}

// transpose attention matrices into coalesced-friendly f32 layouts
__global__ void k_trans(const void* __restrict__ ah, const void* __restrict__ aout,
                        const void* __restrict__ a2h, const void* __restrict__ a2o,
                        const int* __restrict__ ifl,
                        float* __restrict__ aTs, float* __restrict__ aoTs,
                        float* __restrict__ a2f, float* __restrict__ a2of){
  int i = blockIdx.x*256 + threadIdx.x;
  int fdt = ifl[1];
  if (i < 20000){ int k=i/200, t=i%200; aTs[i] = ldf(ah,(size_t)t*300+k,fdt); return; }
  i -= 20000;
  if (i < 40000){ int k=i/200, t=i%200; aoTs[i] = ldf(aout,(size_t)t*600+k,fdt); return; }
  i -= 40000;
  if (i < 200){ a2f[i] = ldf(a2h, i, fdt); return; }
  i -= 200;
  if (i < 200){ a2of[i] = ldf(a2o, i, fdt); return; }
}

// fp16 weight tables, PRE-TRANSPOSED + PADDED for linear LDS staging:
// layout [col][k] with row stride 102 halves (51 words, odd -> conflict-free reads)
__global__ void k_w16(const void* __restrict__ went, const void* __restrict__ ah,
                      const void* __restrict__ aout, const int* __restrict__ ifl,
                      __half* __restrict__ W16eT, __half* __restrict__ W16dT, __half* __restrict__ W16d2T){
  int i = blockIdx.x*256 + threadIdx.x;
  int fdt = ifl[1];
  if (i < 20400){
    int c = i/102, k = i%102;
    W16eT[i] = __float2half_rn(k < 100 ? ldf(went, (size_t)k*200+c, fdt) : 0.f);
    return;
  }
  i -= 20400;
  if (i < 20400){
    int c = i/102, k = i%102;
    W16dT[i] = __float2half_rn(k < 100 ? ldf(ah, (size_t)c*300+100+k, fdt) : 0.f);
    return;
  }
  i -= 20400;
  if (i < 40800){
    int p = i/20400, r = i%20400;
    int c = r/102, k = r%102;
    W16d2T[i] = __float2half_rn(k < 100 ? ldf(aout, (size_t)c*600+200+p*100+k, fdt) : 0.f);
  }
}

// f32 copy of entity rows + per-node inverse norms. One wave per row, 4 rows/block.
__global__ __launch_bounds__(256)
void k_cvt_en(const void* __restrict__ ent, const int* __restrict__ ifl,
              float* __restrict__ ENf, float* __restrict__ invn){
  const int w = threadIdx.x >> 6, l = threadIdx.x & 63;
  const int n = blockIdx.x*4 + w;
  const int fdt = ifl[1];
  float x = 0.f, y = 0.f;
  if (l < 50){
    if (fdt == 0){
      float2 v = ((const float2*)ent)[(size_t)n*50 + l];
      x = v.x; y = v.y;
    } else if (fdt == 2){
      __half2 h = ((const __half2*)ent)[(size_t)n*50 + l];
      float2 v = __half22float2(h); x = v.x; y = v.y;
    } else {
      unsigned int u = ((const unsigned int*)ent)[(size_t)n*50 + l];
      x = __builtin_bit_cast(float, u << 16);
      y = __builtin_bit_cast(float, u & 0xFFFF0000u);
    }
    if (fdt != 0) ((float2*)ENf)[(size_t)n*50 + l] = make_float2(x, y);
  }
  float ss = x*x + y*y;
  #pragma unroll
  for (int o = 1; o < 64; o <<= 1) ss += __shfl_xor(ss, o);
  if (l == 0) invn[n] = 1.f / fmaxf(sqrtf(ss), 1e-12f);
}

// R1f[tt][t] = rtab[tt] @ a_rel.T ; sR1[tt][h]
__global__ __launch_bounds__(256)
void k_R1(const void* __restrict__ rtab, const void* __restrict__ ah, const int* __restrict__ ifl,
          const float* __restrict__ a2f, float* __restrict__ R1f, float* __restrict__ sR1){
  __shared__ float rt[100], ml[200];
  const int tt = blockIdx.x, t = threadIdx.x, fdt = ifl[1];
  if (t < 100) rt[t] = ldf(rtab,(size_t)tt*100+t,fdt);
  __syncthreads();
  if (t < 200){
    float R = 0.f;
    for (int k = 0; k < 100; ++k) R += rt[k]*ldf(ah,(size_t)t*300+200+k,fdt);
    R1f[tt*200+t] = R; ml[t] = R*a2f[t];
  }
  __syncthreads();
  if (t < 64){
    float s = 0.f;
    for (int q = t; q < 100; q += 64) s += ml[q];
    for (int o = 1; o < 64; o <<= 1) s += __shfl_xor(s, o);
    if (t == 0) sR1[tt*2] = s;
  } else if (t < 128){
    int l = t - 64;
    float s = 0.f;
    for (int q = 100 + l; q < 200; q += 64) s += ml[q];
    for (int o = 1; o < 64; o <<= 1) s += __shfl_xor(s, o);
    if (l == 0) sR1[tt*2+1] = s;
  }
}

// R2f[tt][t] = M2f[tt] @ a_rel2.T ; sR2[tt]
__global__ __launch_bounds__(256)
void k_R2(const float* __restrict__ M2f, const void* __restrict__ aout, const int* __restrict__ ifl,
          const float* __restrict__ a2of, float* __restrict__ R2f, float* __restrict__ sR2){
  __shared__ float mr[200], ml[200];
  const int tt = blockIdx.x, t = threadIdx.x, fdt = ifl[1];
  if (t < 200) mr[t] = M2f[tt*200+t];
  __syncthreads();
  if (t < 200){
    float R = 0.f;
    for (int k = 0; k < 200; ++k) R += mr[k]*ldf(aout,(size_t)t*600+400+k,fdt);
    R2f[tt*200+t] = R; ml[t] = R*a2of[t];
  }
  __syncthreads();
  if (t < 64){
    float s = 0.f;
    for (int q = t; q < 200; q += 64) s += ml[q];
    for (int o = 1; o < 64; o <<= 1) s += __shfl_xor(s, o);
    if (t == 0) sR2[tt] = s;
  }
}

// ---------------- CSR (packed: dst | type<<16) ----------------
__global__ void k_count(const void* __restrict__ el, const int* __restrict__ ifl, int* __restrict__ cnt){
  int e = blockIdx.x*256 + threadIdx.x;
  if (e >= E_EDGES) return;
  atomicAdd(&cnt[ild(el, e, ifl[0])], 1);
}
__global__ __launch_bounds__(256)
void k_scan(const int* __restrict__ cnt, int* __restrict__ offs){
  __shared__ int bs[256];
  int t = threadIdx.x;
  const int CH = (N_NODES + 255) / 256;
  int lo = t*CH, hi = min(lo+CH, N_NODES);
  int s = 0;
  for (int i = lo; i < hi; ++i) s += cnt[i];
  bs[t] = s;
  __syncthreads();
  for (int o = 1; o < 256; o <<= 1){
    int v = (t >= o) ? bs[t-o] : 0;
    __syncthreads();
    bs[t] += v;
    __syncthreads();
  }
  int base = (t == 0) ? 0 : bs[t-1];
  for (int i = lo; i < hi; ++i){ offs[i] = base; base += cnt[i]; }
  if (t == 255) offs[N_NODES] = bs[255];
}
__global__ void k_scatter(const void* __restrict__ el, const void* __restrict__ et,
                          const int* __restrict__ ifl, const int* __restrict__ offs,
                          int* __restrict__ fill, int* __restrict__ csr){
  int e = blockIdx.x*256 + threadIdx.x;
  if (e >= E_EDGES) return;
  int f = ifl[0];
  int a = ild(el, e, f);
  int pos = offs[a] + atomicAdd(&fill[a], 1);
  csr[pos] = ild(el, (size_t)E_EDGES + e, f) | (ild(et, e, f) << 16);
}

// flag = masked nodes + their neighbors
__global__ void k_flag(const int* __restrict__ b32, const int* __restrict__ offs,
                       const int* __restrict__ csr, int* __restrict__ nflag){
  const int i = blockIdx.x, t = threadIdx.x;
  const int n = b32[i*4 + 2];
  if (t == 0) nflag[n] = 1;
  for (int j = offs[n] + t; j < offs[n+1]; j += 256) nflag[csr[j] & 0xFFFF] = 1;
}
__global__ void k_compact(const int* __restrict__ nflag, int* __restrict__ fcnt, int* __restrict__ flist){
  int i = blockIdx.x*256 + threadIdx.x;
  if (i < N_NODES && nflag[i]) flist[atomicAdd(fcnt, 1)] = i;
}

// ---- 40-node/block matvec (5 groups of 8): D1 (K=100) ----
__global__ __launch_bounds__(256)
void k_D1b(const void* __restrict__ ent, const float* __restrict__ ENf, const int* __restrict__ ifl,
           const __half* __restrict__ W16dT, const float* __restrict__ a2f,
           __half* __restrict__ D1, float* __restrict__ sD)
{
  __shared__ uint4 Wl4[2550];          // 200*102 halves, linear copy
  __shared__ float scr[4*16], outr[16];
  const __half* Wl = (const __half*)Wl4;
  const int t = threadIdx.x;
  const int fdt = ifl[1];
  const uint4* Wg = (const uint4*)W16dT;
  for (int idx = t; idx < 2550; idx += 256) Wl4[idx] = Wg[idx];
  __syncthreads();
  const float* ENp = (fdt == 0) ? (const float*)ent : ENf;
  const int col = (t < 200) ? t : 199;
  const bool act = t < 200;
  const float a2v = act ? a2f[col] : 0.f;
  for (int g = 0; g < 5; ++g){
    const int n0 = blockIdx.x*40 + g*8;
    float acc[8] = {0,0,0,0,0,0,0,0};
    for (int k = 0; k < 100; k += 2){
      __half2 wh = *(const __half2*)&Wl[col*102 + k];
      float2 wf = __half22float2(wh);
      #pragma unroll
      for (int i = 0; i < 8; ++i){
        const float* ep = ENp + (size_t)(n0+i)*100 + k;
        acc[i] += ep[0]*wf.x + ep[1]*wf.y;
      }
    }
    float hv[16];
    #pragma unroll
    for (int i = 0; i < 8; ++i){
      if (act) D1[(size_t)(n0+i)*200 + col] = __float2half_rn(acc[i]);
      float m = acc[i]*a2v;
      hv[i*2]   = (col < 100) ? m : 0.f;
      hv[i*2+1] = (col < 100) ? 0.f : m;
    }
    blockRed<16>(hv, scr, outr);
    if (t < 16) sD[(size_t)(n0 + (t>>1))*2 + (t&1)] = outr[t];
  }
}

// ---- 40-node/block matvec + epilogue: entities_upgraded & final l2norm output ----
__global__ __launch_bounds__(256)
void k_eufb(const void* __restrict__ ent, const float* __restrict__ ENf, const int* __restrict__ ifl,
            const __half* __restrict__ W16eT, const float* __restrict__ invn,
            const int* __restrict__ midx, const float* __restrict__ x2m, char* __restrict__ dout)
{
  __shared__ uint4 Wl4[2550];
  __shared__ float scr[4*8], outr[8];
  const __half* Wl = (const __half*)Wl4;
  const int t = threadIdx.x;
  const int fdt = ifl[1];
  const uint4* Wg = (const uint4*)W16eT;
  for (int idx = t; idx < 2550; idx += 256) Wl4[idx] = Wg[idx];
  __syncthreads();
  const float* ENp = (fdt == 0) ? (const float*)ent : ENf;
  const int col = (t < 200) ? t : 199;
  const bool act = t < 200;
  for (int g = 0; g < 5; ++g){
    const int n0 = blockIdx.x*40 + g*8;
    float acc[8] = {0,0,0,0,0,0,0,0};
    for (int k = 0; k < 100; k += 2){
      __half2 wh = *(const __half2*)&Wl[col*102 + k];
      float2 wf = __half22float2(wh);
      #pragma unroll
      for (int i = 0; i < 8; ++i){
        const float* ep = ENp + (size_t)(n0+i)*100 + k;
        acc[i] += ep[0]*wf.x + ep[1]*wf.y;
      }
    }
    float val[8], ss[8];
    #pragma unroll
    for (int i = 0; i < 8; ++i){
      const int n = n0 + i;
      float v = acc[i]*invn[n];
      const int mi = midx[n];
      if (mi >= 0) v += x2m[(size_t)mi*200 + col];
      val[i] = act ? v : 0.f;
      ss[i] = val[i]*val[i];
    }
    blockRed<8>(ss, scr, outr);
    #pragma unroll
    for (int i = 0; i < 8; ++i){
      if (act){
        float r = 1.f / fmaxf(sqrtf(outr[i]), 1e-12f);
        stf(dout, (size_t)(n0+i)*200 + col, val[i]*r, fdt);
      }
    }
  }
}

// ---- 64-node/block matvec over compacted flagged list: D2 (K=200, both phases staged) ----
__global__ __launch_bounds__(256)
void k_D2b(const __half* __restrict__ x1, const int* __restrict__ flist, const int* __restrict__ fcnt,
           const __half* __restrict__ W16d2T, const float* __restrict__ a2of,
           __half* __restrict__ D2, float* __restrict__ sD2)
{
  extern __shared__ __half Wl[];       // 2*200*102 halves = 81600 B (dynamic)
  __shared__ float scr[4*8], outr[8];
  const int t = threadIdx.x;
  const int cnt = fcnt[0];
  const int base0 = blockIdx.x*64;
  if (base0 >= cnt) return;
  uint4* Wl4 = (uint4*)Wl;
  const uint4* Wg = (const uint4*)W16d2T;
  for (int idx = t; idx < 5100; idx += 256) Wl4[idx] = Wg[idx];
  __syncthreads();
  const int col = (t < 200) ? t : 199;
  const bool act = t < 200;
  const float a2v = act ? a2of[col] : 0.f;
  for (int g = 0; g < 8; ++g){
    const int base = base0 + g*8;
    if (base >= cnt) break;            // cnt uniform -> barrier-safe
    int nd[8];
    #pragma unroll
    for (int i = 0; i < 8; ++i){ int j = base + i; nd[i] = flist[j < cnt ? j : cnt-1]; }
    float acc[8] = {0,0,0,0,0,0,0,0};
    #pragma unroll 1
    for (int p = 0; p < 2; ++p){
      const __half* Wp = Wl + p*20400;
      for (int kp = 0; kp < 100; kp += 2){
        __half2 wh = *(const __half2*)&Wp[col*102 + kp];
        float2 wf = __half22float2(wh);
        const int k = p*100 + kp;
        #pragma unroll
        for (int i = 0; i < 8; ++i){
          unsigned int u = *(const unsigned int*)(x1 + (size_t)nd[i]*200 + k);
          __half2 eh = __builtin_bit_cast(__half2, u);
          float2 ef = __half22float2(eh);
          acc[i] += ef.x*wf.x + ef.y*wf.y;
        }
      }
    }
    float ml[8];
    #pragma unroll
    for (int i = 0; i < 8; ++i){
      if (act) D2[(size_t)nd[i]*200 + col] = __float2half_rn(acc[i]);
      ml[i] = acc[i]*a2v;
    }
    blockRed<8>(ml, scr, outr);
    if (t < 8){
      int j = base + t;
      if (j < cnt) sD2[flist[j]] = outr[t];
    }
  }
}

// layer 1 aggregation, flagged nodes only
__global__ __launch_bounds__(256)
void k_x1(const void* __restrict__ ent, const float* __restrict__ ENf, const int* __restrict__ ifl,
          const int* __restrict__ nflag, const float* __restrict__ aTs, const float* __restrict__ a2f,
          const float* __restrict__ R1f, const float* __restrict__ sR1,
          const __half* __restrict__ D1, const float* __restrict__ sD,
          const int* __restrict__ offs, const int* __restrict__ csr, __half* __restrict__ x1)
{
  __shared__ float ml[200], sS2[2];
  const int n = blockIdx.x, t = threadIdx.x;
  if (!nflag[n]) return;
  const int fdt = ifl[1];
  const float* ENp = (fdt == 0) ? (const float*)ent : ENf;
  float S = 0.f;
  if (t < 200){
    const float* ep = ENp + (size_t)n*100;
    for (int k = 0; k < 100; ++k) S += ep[k]*aTs[k*200+t];
    ml[t] = S*a2f[t];
  }
  __syncthreads();
  if (t < 64){
    float s = 0.f;
    for (int q = t; q < 100; q += 64) s += ml[q];
    for (int o = 1; o < 64; o <<= 1) s += __shfl_xor(s, o);
    if (t == 0) sS2[0] = s;
  } else if (t < 128){
    int l = t - 64;
    float s = 0.f;
    for (int q = 100 + l; q < 200; q += 64) s += ml[q];
    for (int o = 1; o < 64; o <<= 1) s += __shfl_xor(s, o);
    if (l == 0) sS2[1] = s;
  }
  __syncthreads();
  if (t >= 200) return;
  const int h = (t >= 100) ? 1 : 0;
  const float sS = sS2[h];
  float acc = 0.f, W = 0.f;
  const int beg = offs[n], end = offs[n+1];
  for (int j = beg; j < end; ++j){
    int pk = csr[j];
    int v = pk & 0xFFFF, tt = pk >> 16;
    float d = __half2float(D1[(size_t)v*200 + t]);
    float r = R1f[tt*200 + t];
    float p = sS + sD[(size_t)v*2 + h] + sR1[tt*2 + h];
    float lk = p > 0.f ? p : 0.2f*p;
    float w = expf(-lk);
    acc += w*(d + r); W += w;
  }
  float hh = (S*W + acc) / (W + 1e-12f);
  x1[(size_t)n*200 + t] = __float2half_rn(hh > 0.f ? hh : (expf(hh) - 1.f));
}

// layer 2, masked nodes only
__global__ __launch_bounds__(256)
void k_x2m(const int* __restrict__ b32, const __half* __restrict__ x1, const float* __restrict__ aoTs,
           const float* __restrict__ a2of, const float* __restrict__ R2f, const float* __restrict__ sR2,
           const __half* __restrict__ D2, const float* __restrict__ sD2,
           const int* __restrict__ offs, const int* __restrict__ csr, float* __restrict__ x2m)
{
  __shared__ float xn[200], ml[200], sS2[1];
  const int i = blockIdx.x, t = threadIdx.x;
  const int n = b32[i*4 + 2];
  if (t < 200) xn[t] = __half2float(x1[(size_t)n*200 + t]);
  __syncthreads();
  float S = 0.f;
  if (t < 200){
    for (int k = 0; k < 200; ++k) S += xn[k]*aoTs[k*200+t];
    ml[t] = S*a2of[t];
  }
  __syncthreads();
  if (t < 64){
    float s = 0.f;
    for (int q = t; q < 200; q += 64) s += ml[q];
    for (int o = 1; o < 64; o <<= 1) s += __shfl_xor(s, o);
    if (t == 0) sS2[0] = s;
  }
  __syncthreads();
  if (t >= 200) return;
  const float sS = sS2[0];
  float acc = 0.f, W = 0.f;
  const int beg = offs[n], end = offs[n+1];
  for (int j = beg; j < end; ++j){
    int pk = csr[j];
    int v = pk & 0xFFFF, tt = pk >> 16;
    float d = __half2float(D2[(size_t)v*200 + t]);
    float r = R2f[tt*200 + t];
    float p = sS + sD2[v] + sR2[tt];
    float lk = p > 0.f ? p : 0.2f*p;
    float w = expf(-lk);
    acc += w*(d + r); W += w;
  }
  float hh = (S*W + acc) / (W + 1e-12f);
  x2m[(size_t)i*200 + t] = hh > 0.f ? hh : (expf(hh) - 1.f);
}

// ---------------- his_temp: LDS tile + 16B vector stores ----------------
__global__ __launch_bounds__(256)
void k_his(const void* __restrict__ binp, const void* __restrict__ wt, const void* __restrict__ bt,
           const int* __restrict__ ifl, char* __restrict__ dout)
{
  __shared__ float he[100];
  __shared__ uint4 tile[50];
  const int i = blockIdx.x, t = threadIdx.x;
  const int fdt = ifl[1];
  const double t2 = (double)ild(binp, (size_t)i*4 + 3, ifl[0]);
  if (t < 100){
    double a = t2 * (double)ldf(wt, t, fdt) + (double)ldf(bt, t, fdt);
    he[t] = (float)cos(a);
  }
  __syncthreads();
  if (fdt == 0){
    float* tf = (float*)tile;          // 100 floats = 25 uint4, period 100
    if (t < 100) tf[t] = he[t];
    __syncthreads();
    uint4* out4 = (uint4*)(dout + 40000000 + (size_t)i*204800);
    for (int idx = t; idx < 12800; idx += 256) out4[idx] = tile[idx % 25];
  } else {
    unsigned short* th = (unsigned short*)tile;   // 400 halves = 50 uint4, period 400
    for (int j = t; j < 400; j += 256){
      float v = he[j % 100];
      th[j] = (fdt == 2) ? __builtin_bit_cast(unsigned short, __float2half_rn(v)) : f2bf(v);
    }
    __syncthreads();
    uint4* out4 = (uint4*)(dout + 20000000 + (size_t)i*102400);
    for (int idx = t; idx < 6400; idx += 256) out4[idx] = tile[idx % 50];
  }
}

// ---------------- launch ----------------
extern "C" void kernel_launch(void* const* d_in, const int* in_sizes, int n_in,
                              void* d_out, int out_size, void* d_ws, size_t ws_size,
                              hipStream_t stream)
{
  (void)in_sizes; (void)n_in; (void)out_size; (void)ws_size;
  const void* ent  = d_in[0];
  const void* rtab = d_in[1];
  const void* w_t2 = d_in[2];
  const void* b_t2 = d_in[3];
  const void* Went = d_in[4];
  const void* ah   = d_in[5];
  const void* a2h  = d_in[6];
  const void* Wrel = d_in[7];
  const void* aout = d_in[8];
  const void* a2o  = d_in[9];
  const void* elist = d_in[10];
  const void* etype = d_in[11];
  const void* binp  = d_in[12];

  int* ifl = (int*)d_ws;                         // [0]=int64 flag, [1]=float dtype
  int* b32 = (int*)((char*)d_ws + 256);          // 2048 ints

  char* dout = (char*)d_out;
  // ENf at [0,20MB): f32 copy of ent (16-bit dtypes only); per-block read-before-write vs out0.
  float* ENf = (float*)dout;
  // Region A [20MB,40MB): D1 then D2 (fp16).
  __half* D12 = (__half*)(dout + 20000000);
  // Region B [40MB,~66.6MB): consumed by kernels up to k_eufb; inside out1 for all dtypes.
  char* scr = dout + 40000000;
  size_t cur = 0;
  auto alloc = [&](size_t bytes) -> char* {
    char* p = scr + cur;
    cur = (cur + bytes + 255) & ~(size_t)255;
    return p;
  };
  __half* X1     = (__half*)alloc((size_t)N_NODES*200*2);   // 20 MB
  int*   csr     = (int*)alloc((size_t)E_EDGES*4);          // 3.2 MB
  int*   offs    = (int*)alloc((size_t)(N_NODES+1)*4);
  int*   cnt     = (int*)alloc((size_t)N_NODES*4);
  int*   midx    = (int*)alloc((size_t)N_NODES*4);
  int*   nflag   = (int*)alloc((size_t)N_NODES*4);
  int*   flist   = (int*)alloc((size_t)N_NODES*4);
  int*   fcnt    = (int*)alloc(256);
  float* invn    = (float*)alloc((size_t)N_NODES*4);
  float* M2f     = (float*)alloc((size_t)200*200*4);
  float* x2m     = (float*)alloc((size_t)B_BATCH*200*4);
  float* aTs     = (float*)alloc((size_t)100*200*4);
  float* aoTs    = (float*)alloc((size_t)200*200*4);
  float* R1f     = (float*)alloc((size_t)200*200*4);
  float* R2f     = (float*)alloc((size_t)200*200*4);
  float* sD      = (float*)alloc((size_t)N_NODES*2*4);
  float* sD2     = (float*)alloc((size_t)N_NODES*4);
  float* sR1     = (float*)alloc((size_t)200*2*4);
  float* sR2     = (float*)alloc((size_t)200*4);
  float* a2f     = (float*)alloc((size_t)200*4);
  float* a2of    = (float*)alloc((size_t)200*4);
  __half* W16eT  = (__half*)alloc((size_t)200*102*2);       // transposed+padded
  __half* W16dT  = (__half*)alloc((size_t)200*102*2);
  __half* W16d2T = (__half*)alloc((size_t)2*200*102*2);
  // total ~26.6 MB -> ends ~66.6 MB < 72.4 MB (min d_out at esize=2)

  const int EB = (E_EDGES + 255) / 256;
  const int NB = (N_NODES + 255) / 256;

  k_probe<<<dim3(1), dim3(64), 0, stream>>>((const unsigned short*)ent, (const unsigned int*)ent,
                                            (const unsigned int*)elist, ifl);
  k_cvtb <<<dim3(8), dim3(256), 0, stream>>>(binp, ifl, b32);
  k_fillm<<<dim3(NB), dim3(256), 0, stream>>>(midx, -1, N_NODES);
  k_mset <<<dim3(2), dim3(256), 0, stream>>>(b32, midx);
  k_trans<<<dim3(237), dim3(256), 0, stream>>>(ah, aout, a2h, a2o, ifl, aTs, aoTs, a2f, a2of);
  k_w16  <<<dim3(319), dim3(256), 0, stream>>>(Went, ah, aout, ifl, W16eT, W16dT, W16d2T);
  k_cvt_en<<<dim3(N_NODES/4), dim3(256), 0, stream>>>(ent, ifl, ENf, invn);
  k_m2f  <<<dim3(157), dim3(256), 0, stream>>>(rtab, Wrel, etype, ifl, M2f);
  k_R1   <<<dim3(200), dim3(256), 0, stream>>>(rtab, ah, ifl, a2f, R1f, sR1);
  k_R2   <<<dim3(200), dim3(256), 0, stream>>>(M2f, aout, ifl, a2of, R2f, sR2);

  k_fillm<<<dim3(NB), dim3(256), 0, stream>>>(cnt, 0, N_NODES);
  k_count<<<dim3(EB), dim3(256), 0, stream>>>(elist, ifl, cnt);
  k_scan <<<dim3(1), dim3(256), 0, stream>>>(cnt, offs);
  k_fillm<<<dim3(NB), dim3(256), 0, stream>>>(cnt, 0, N_NODES);
  k_scatter<<<dim3(EB), dim3(256), 0, stream>>>(elist, etype, ifl, offs, cnt, csr);

  k_fillm<<<dim3(NB), dim3(256), 0, stream>>>(nflag, 0, N_NODES);
  k_flag <<<dim3(B_BATCH), dim3(256), 0, stream>>>(b32, offs, csr, nflag);
  k_fillm<<<dim3(1), dim3(256), 0, stream>>>(fcnt, 0, 1);
  k_compact<<<dim3(NB), dim3(256), 0, stream>>>(nflag, fcnt, flist);

  k_D1b<<<dim3(N_NODES/40), dim3(256), 0, stream>>>(ent, ENf, ifl, W16dT, a2f, D12, sD);
  k_x1 <<<dim3(N_NODES), dim3(256), 0, stream>>>(ent, ENf, ifl, nflag, aTs, a2f, R1f, sR1, D12, sD, offs, csr, X1);
  k_D2b<<<dim3((N_NODES+63)/64), dim3(256), 81600, stream>>>(X1, flist, fcnt, W16d2T, a2of, D12, sD2);
  k_x2m<<<dim3(B_BATCH), dim3(256), 0, stream>>>(b32, X1, aoTs, a2of, R2f, sR2, D12, sD2, offs, csr, x2m);
  k_eufb<<<dim3(N_NODES/40), dim3(256), 0, stream>>>(ent, ENf, ifl, W16eT, invn, midx, x2m, dout);

  // LAST: overwrites all of out1 (incl. all scratch); reads only inputs + ifl
  k_his<<<dim3(B_BATCH), dim3(256), 0, stream>>>(binp, w_t2, b_t2, ifl, dout);
}

// Round 4
// 798.365 us; speedup vs baseline: 1.4177x; 1.4177x over previous
//
#include <hip/hip_runtime.h>
#include <hip/hip_fp16.h>
#include <stdint.h>

#define N_NODES 50000
#define FIN_D   100
#define E_EDGES 800000
#define NRELS   200
#define B_BATCH 512
#define HDIM    100

typedef _Float16 f16x8 __attribute__((ext_vector_type(8)));
typedef short    s16x8 __attribute__((ext_vector_type(8)));
typedef float    f32x4v __attribute__((ext_vector_type(4)));

__device__ __forceinline__ unsigned short f2bf(float f){
  unsigned int x = __builtin_bit_cast(unsigned int, f);
  unsigned int lsb = (x >> 16) & 1u;
  x += 0x7fffu + lsb;
  return (unsigned short)(x >> 16);
}
// float-tensor load: fdt 2=fp16, 1=bf16, 0=f32
__device__ __forceinline__ float ldf(const void* p, size_t i, int fdt){
  if (fdt == 2) return __half2float(((const __half*)p)[i]);
  if (fdt == 1){ unsigned int x = ((unsigned int)((const unsigned short*)p)[i]) << 16;
                 return __builtin_bit_cast(float, x); }
  return ((const float*)p)[i];
}
// output store, same dtype as inputs
__device__ __forceinline__ void stf(void* p, size_t i, float v, int fdt){
  if (fdt == 2) ((__half*)p)[i] = __float2half_rn(v);
  else if (fdt == 1) ((unsigned short*)p)[i] = f2bf(v);
  else ((float*)p)[i] = v;
}
// integer-tensor load: i64 flag
__device__ __forceinline__ int ild(const void* p, size_t i, int i64){
  return i64 ? (int)((const long long*)p)[i] : ((const int*)p)[i];
}

// ---------------- dtype probes ----------------
__global__ void k_probe(const unsigned short* __restrict__ eh, const unsigned int* __restrict__ ew,
                        const unsigned int* __restrict__ elw, int* __restrict__ ifl){
  int t = threadIdx.x;   // 64 lanes
  int cF = 0, cB = 0, c32 = 0;
  #pragma unroll
  for (int j = 0; j < 4; ++j){
    unsigned short u = eh[4*t + j];
    {
      int e5 = (u >> 10) & 31, m = u & 1023;
      float v = (e5 == 0) ? ldexpf((float)m, -24) : ldexpf(1.f + m/1024.f, e5 - 15);
      if (v >= 0.004f && v <= 0.30f) cF++;
    }
    {
      unsigned int x = ((unsigned int)(u & 0x7FFF)) << 16;
      float v = __builtin_bit_cast(float, x);
      if (v >= 0.004f && v <= 0.30f) cB++;
    }
  }
  #pragma unroll
  for (int j = 0; j < 2; ++j){
    unsigned int w = ew[2*t + j] & 0x7FFFFFFFu;
    float v = __builtin_bit_cast(float, w);
    if (v >= 0.004f && v <= 0.30f) c32++;
  }
  for (int o = 1; o < 64; o <<= 1){
    cF += __shfl_xor(cF, o); cB += __shfl_xor(cB, o); c32 += __shfl_xor(c32, o);
  }
  int z = (elw[2*t + 1] == 0u) ? 1 : 0;
  unsigned long long mb = __ballot(z);
  if (t == 0){
    int fdt;
    if (c32 >= 96) fdt = 0;
    else fdt = (cB > cF) ? 1 : 2;
    ifl[1] = fdt;
    ifl[0] = (__popcll(mb) >= 60) ? 1 : 0;
  }
}

// ---------------- setup ----------------
__global__ void k_fillm(int* __restrict__ p, int v, int n){
  int i = blockIdx.x * blockDim.x + threadIdx.x;
  if (i < n) p[i] = v;
}
__global__ void k_cvtb(const void* __restrict__ binp, const int* __restrict__ ifl, int* __restrict__ b32){
  int i = blockIdx.x*256 + threadIdx.x;
  if (i >= B_BATCH*4) return;
  b32[i] = ild(binp, i, ifl[0]);
}
__global__ void k_mset(const int* __restrict__ b32, int* __restrict__ midx){
  int i = blockIdx.x*256 + threadIdx.x;
  if (i >= B_BATCH) return;
  midx[b32[i*4 + 2]] = i;
}
// M2f[r][j] = rtab[edge_type[r]] @ W_rel
__global__ void k_m2f(const void* __restrict__ rtab, const void* __restrict__ wrel,
                      const void* __restrict__ et, const int* __restrict__ ifl, float* __restrict__ M2){
  int idx = blockIdx.x*256 + threadIdx.x;
  if (idx >= 200*200) return;
  int fdt = ifl[1];
  int r = idx / 200, j = idx % 200;
  int g = ild(et, r, ifl[0]);
  float s = 0.f;
  for (int k = 0; k < 100; ++k) s += ldf(rtab, (size_t)g*100 + k, fdt) * ldf(wrel, (size_t)k*200 + j, fdt);
  M2[idx] = s;
}

// transpose attention matrices into coalesced-friendly f32 layouts
__global__ void k_trans(const void* __restrict__ ah, const void* __restrict__ aout,
                        const void* __restrict__ a2h, const void* __restrict__ a2o,
                        const int* __restrict__ ifl,
                        float* __restrict__ aTs, float* __restrict__ aoTs,
                        float* __restrict__ a2f, float* __restrict__ a2of){
  int i = blockIdx.x*256 + threadIdx.x;
  int fdt = ifl[1];
  if (i < 20000){ int k=i/200, t=i%200; aTs[i] = ldf(ah,(size_t)t*300+k,fdt); return; }
  i -= 20000;
  if (i < 40000){ int k=i/200, t=i%200; aoTs[i] = ldf(aout,(size_t)t*600+k,fdt); return; }
  i -= 40000;
  if (i < 200){ a2f[i] = ldf(a2h, i, fdt); return; }
  i -= 200;
  if (i < 200){ a2of[i] = ldf(a2o, i, fdt); return; }
}

// W table for k_D2b (unchanged layout: [col][k] stride 102)
__global__ void k_w16(const void* __restrict__ aout, const int* __restrict__ ifl,
                      __half* __restrict__ W16d2T){
  int i = blockIdx.x*256 + threadIdx.x;
  if (i >= 40800) return;
  int fdt = ifl[1];
  int p = i/20400, r = i%20400;
  int c = r/102, k = r%102;
  W16d2T[i] = __float2half_rn(k < 100 ? ldf(aout, (size_t)c*600+200+p*100+k, fdt) : 0.f);
}

// MFMA B-operand swizzled weight tables (16-bit; fp16 if fdt==2 else bf16).
// halves layout: [n(13)][ks(4)][lane(64)][j(8)]; element = W[k][col],
// k = ks*32 + (lane>>4)*8 + j, col = n*16 + (lane&15); zero pad k>=100 / col>=200.
__global__ void k_wsw(const void* __restrict__ went, const void* __restrict__ ah,
                      const int* __restrict__ ifl,
                      unsigned short* __restrict__ WswE, unsigned short* __restrict__ WswD){
  int i = blockIdx.x*256 + threadIdx.x;
  if (i >= 2*26624) return;
  int fdt = ifl[1];
  int tbl = i / 26624, r0 = i % 26624;
  int j = r0 & 7, l = (r0>>3) & 63, ks = (r0>>9) & 3, n = r0>>11;
  int k = ks*32 + (l>>4)*8 + j;
  int col = n*16 + (l&15);
  float v = 0.f;
  if (k < 100 && col < 200)
    v = tbl ? ldf(ah, (size_t)col*300 + 100 + k, fdt) : ldf(went, (size_t)k*200 + col, fdt);
  unsigned short h = (fdt == 2) ? __builtin_bit_cast(unsigned short, __float2half_rn(v)) : f2bf(v);
  (tbl ? WswD : WswE)[r0] = h;
}

// f32 copy of entity rows + per-node inverse norms. One wave per row, 4 rows/block.
__global__ __launch_bounds__(256)
void k_cvt_en(const void* __restrict__ ent, const int* __restrict__ ifl,
              float* __restrict__ ENf, float* __restrict__ invn){
  const int w = threadIdx.x >> 6, l = threadIdx.x & 63;
  const int n = blockIdx.x*4 + w;
  const int fdt = ifl[1];
  float x = 0.f, y = 0.f;
  if (l < 50){
    if (fdt == 0){
      float2 v = ((const float2*)ent)[(size_t)n*50 + l];
      x = v.x; y = v.y;
    } else if (fdt == 2){
      __half2 h = ((const __half2*)ent)[(size_t)n*50 + l];
      float2 v = __half22float2(h); x = v.x; y = v.y;
    } else {
      unsigned int u = ((const unsigned int*)ent)[(size_t)n*50 + l];
      x = __builtin_bit_cast(float, u << 16);
      y = __builtin_bit_cast(float, u & 0xFFFF0000u);
    }
    if (fdt != 0) ((float2*)ENf)[(size_t)n*50 + l] = make_float2(x, y);
  }
  float ss = x*x + y*y;
  #pragma unroll
  for (int o = 1; o < 64; o <<= 1) ss += __shfl_xor(ss, o);
  if (l == 0) invn[n] = 1.f / fmaxf(sqrtf(ss), 1e-12f);
}

// R1f[tt][t] = rtab[tt] @ a_rel.T ; sR1[tt][h]
__global__ __launch_bounds__(256)
void k_R1(const void* __restrict__ rtab, const void* __restrict__ ah, const int* __restrict__ ifl,
          const float* __restrict__ a2f, float* __restrict__ R1f, float* __restrict__ sR1){
  __shared__ float rt[100], ml[200];
  const int tt = blockIdx.x, t = threadIdx.x, fdt = ifl[1];
  if (t < 100) rt[t] = ldf(rtab,(size_t)tt*100+t,fdt);
  __syncthreads();
  if (t < 200){
    float R = 0.f;
    for (int k = 0; k < 100; ++k) R += rt[k]*ldf(ah,(size_t)t*300+200+k,fdt);
    R1f[tt*200+t] = R; ml[t] = R*a2f[t];
  }
  __syncthreads();
  if (t < 64){
    float s = 0.f;
    for (int q = t; q < 100; q += 64) s += ml[q];
    for (int o = 1; o < 64; o <<= 1) s += __shfl_xor(s, o);
    if (t == 0) sR1[tt*2] = s;
  } else if (t < 128){
    int l = t - 64;
    float s = 0.f;
    for (int q = 100 + l; q < 200; q += 64) s += ml[q];
    for (int o = 1; o < 64; o <<= 1) s += __shfl_xor(s, o);
    if (l == 0) sR1[tt*2+1] = s;
  }
}

// R2f[tt][t] = M2f[tt] @ a_rel2.T ; sR2[tt]
__global__ __launch_bounds__(256)
void k_R2(const float* __restrict__ M2f, const void* __restrict__ aout, const int* __restrict__ ifl,
          const float* __restrict__ a2of, float* __restrict__ R2f, float* __restrict__ sR2){
  __shared__ float mr[200], ml[200];
  const int tt = blockIdx.x, t = threadIdx.x, fdt = ifl[1];
  if (t < 200) mr[t] = M2f[tt*200+t];
  __syncthreads();
  if (t < 200){
    float R = 0.f;
    for (int k = 0; k < 200; ++k) R += mr[k]*ldf(aout,(size_t)t*600+400+k,fdt);
    R2f[tt*200+t] = R; ml[t] = R*a2of[t];
  }
  __syncthreads();
  if (t < 64){
    float s = 0.f;
    for (int q = t; q < 200; q += 64) s += ml[q];
    for (int o = 1; o < 64; o <<= 1) s += __shfl_xor(s, o);
    if (t == 0) sR2[tt] = s;
  }
}

// ---------------- CSR (packed: dst | type<<16) ----------------
__global__ void k_count(const void* __restrict__ el, const int* __restrict__ ifl, int* __restrict__ cnt){
  int e = blockIdx.x*256 + threadIdx.x;
  if (e >= E_EDGES) return;
  atomicAdd(&cnt[ild(el, e, ifl[0])], 1);
}
__global__ __launch_bounds__(256)
void k_scan(const int* __restrict__ cnt, int* __restrict__ offs){
  __shared__ int bs[256];
  int t = threadIdx.x;
  const int CH = (N_NODES + 255) / 256;
  int lo = t*CH, hi = min(lo+CH, N_NODES);
  int s = 0;
  for (int i = lo; i < hi; ++i) s += cnt[i];
  bs[t] = s;
  __syncthreads();
  for (int o = 1; o < 256; o <<= 1){
    int v = (t >= o) ? bs[t-o] : 0;
    __syncthreads();
    bs[t] += v;
    __syncthreads();
  }
  int base = (t == 0) ? 0 : bs[t-1];
  for (int i = lo; i < hi; ++i){ offs[i] = base; base += cnt[i]; }
  if (t == 255) offs[N_NODES] = bs[255];
}
__global__ void k_scatter(const void* __restrict__ el, const void* __restrict__ et,
                          const int* __restrict__ ifl, const int* __restrict__ offs,
                          int* __restrict__ fill, int* __restrict__ csr){
  int e = blockIdx.x*256 + threadIdx.x;
  if (e >= E_EDGES) return;
  int f = ifl[0];
  int a = ild(el, e, f);
  int pos = offs[a] + atomicAdd(&fill[a], 1);
  csr[pos] = ild(el, (size_t)E_EDGES + e, f) | (ild(et, e, f) << 16);
}

// flag = masked nodes + their neighbors
__global__ void k_flag(const int* __restrict__ b32, const int* __restrict__ offs,
                       const int* __restrict__ csr, int* __restrict__ nflag){
  const int i = blockIdx.x, t = threadIdx.x;
  const int n = b32[i*4 + 2];
  if (t == 0) nflag[n] = 1;
  for (int j = offs[n] + t; j < offs[n+1]; j += 256) nflag[csr[j] & 0xFFFF] = 1;
}
__global__ void k_compact(const int* __restrict__ nflag, int* __restrict__ fcnt, int* __restrict__ flist){
  int i = blockIdx.x*256 + threadIdx.x;
  if (i < N_NODES && nflag[i]) flist[atomicAdd(fcnt, 1)] = i;
}

// ---- A-fragment gather for EN GEMMs (K=100 padded to 128; tail zeroed in regs) ----
__device__ __forceinline__ void loadA(const void* ent, int fdt, int arow, int koff, uint4* a){
  if (fdt != 0){
    const unsigned short* E = (const unsigned short*)ent;
    #pragma unroll
    for (int ks = 0; ks < 3; ++ks){
      const uint2* p = (const uint2*)(E + (size_t)arow*100 + ks*32 + koff);
      uint2 u0 = p[0], u1 = p[1];
      a[ks] = make_uint4(u0.x, u0.y, u1.x, u1.y);
    }
    if (koff == 0){
      const uint2* p = (const uint2*)(E + (size_t)arow*100 + 96);
      uint2 u0 = p[0];
      a[3] = make_uint4(u0.x, u0.y, 0, 0);        // k=96..99 valid, 100..103 zeroed
    } else a[3] = make_uint4(0,0,0,0);
  } else {
    const float* E = (const float*)ent;
    #pragma unroll
    for (int ks = 0; ks < 3; ++ks){
      const uint4* p = (const uint4*)(E + (size_t)arow*100 + ks*32 + koff);
      uint4 lo = p[0], hi = p[1];
      a[ks].x = (lo.x>>16) | (lo.y & 0xFFFF0000u);
      a[ks].y = (lo.z>>16) | (lo.w & 0xFFFF0000u);
      a[ks].z = (hi.x>>16) | (hi.y & 0xFFFF0000u);
      a[ks].w = (hi.z>>16) | (hi.w & 0xFFFF0000u);
    }
    if (koff == 0){
      const uint4* p = (const uint4*)(E + (size_t)arow*100 + 96);
      uint4 lo = p[0];
      a[3] = make_uint4((lo.x>>16)|(lo.y&0xFFFF0000u), (lo.z>>16)|(lo.w&0xFFFF0000u), 0, 0);
    } else a[3] = make_uint4(0,0,0,0);
  }
}

// ---- MFMA GEMM: D1 = EN @ a_dst.T  (+ sD head sums) ----
__global__ __launch_bounds__(256)
void k_gemmD1(const void* __restrict__ ent, const int* __restrict__ ifl,
              const unsigned short* __restrict__ WswD, const float* __restrict__ a2f,
              __half* __restrict__ D1, float* __restrict__ sD)
{
  const int wid = threadIdx.x >> 6, l = threadIdx.x & 63;
  const int mt = blockIdx.x*4 + wid;
  if (mt >= 3125) return;
  const int fdt = ifl[1];
  const int arow = mt*16 + (l & 15);
  const int koff = (l >> 4)*8;
  uint4 a[4];
  loadA(ent, fdt, arow, koff, a);
  const int c15 = l & 15;
  const int rbase = mt*16 + (l >> 4)*4;
  float sh0[4] = {0,0,0,0}, sh1[4] = {0,0,0,0};
  const uint4* W4 = (const uint4*)WswD;
  #pragma unroll
  for (int n = 0; n < 13; ++n){
    const int col = n*16 + c15;
    f32x4v acc = {0.f, 0.f, 0.f, 0.f};
    if (fdt == 2){
      #pragma unroll
      for (int ks = 0; ks < 4; ++ks){
        uint4 w = W4[(n*4 + ks)*64 + l];
        acc = __builtin_amdgcn_mfma_f32_16x16x32_f16(
            __builtin_bit_cast(f16x8, a[ks]), __builtin_bit_cast(f16x8, w), acc, 0, 0, 0);
      }
    } else {
      #pragma unroll
      for (int ks = 0; ks < 4; ++ks){
        uint4 w = W4[(n*4 + ks)*64 + l];
        acc = __builtin_amdgcn_mfma_f32_16x16x32_bf16(
            __builtin_bit_cast(s16x8, a[ks]), __builtin_bit_cast(s16x8, w), acc, 0, 0, 0);
      }
    }
    const float a2v = (col < 200) ? a2f[col] : 0.f;
    #pragma unroll
    for (int r = 0; r < 4; ++r){
      float v = acc[r];
      if (col < 200) D1[(size_t)(rbase + r)*200 + col] = __float2half_rn(v);
      float m = v*a2v;
      if (col < 100) sh0[r] += m; else sh1[r] += m;
    }
  }
  #pragma unroll
  for (int o = 1; o < 16; o <<= 1){
    #pragma unroll
    for (int r = 0; r < 4; ++r){
      sh0[r] += __shfl_xor(sh0[r], o);
      sh1[r] += __shfl_xor(sh1[r], o);
    }
  }
  if (c15 == 0){
    #pragma unroll
    for (int r = 0; r < 4; ++r){
      sD[(size_t)(rbase + r)*2]     = sh0[r];
      sD[(size_t)(rbase + r)*2 + 1] = sh1[r];
    }
  }
}

// ---- MFMA GEMM + epilogue: out0 = l2norm(EN@Went * invn + mask*x2m) ----
__global__ __launch_bounds__(256)
void k_gemmEuf(const void* __restrict__ ent, const int* __restrict__ ifl,
               const unsigned short* __restrict__ WswE, const float* __restrict__ invn,
               const int* __restrict__ midx, const float* __restrict__ x2m, char* __restrict__ dout)
{
  const int wid = threadIdx.x >> 6, l = threadIdx.x & 63;
  const int mt = blockIdx.x*4 + wid;
  if (mt >= 3125) return;
  const int fdt = ifl[1];
  const int arow = mt*16 + (l & 15);
  const int koff = (l >> 4)*8;
  uint4 a[4];
  loadA(ent, fdt, arow, koff, a);
  const int c15 = l & 15;
  const int rbase = mt*16 + (l >> 4)*4;
  f32x4v acc[13];
  const uint4* W4 = (const uint4*)WswE;
  #pragma unroll
  for (int n = 0; n < 13; ++n){
    f32x4v c = {0.f, 0.f, 0.f, 0.f};
    if (fdt == 2){
      #pragma unroll
      for (int ks = 0; ks < 4; ++ks){
        uint4 w = W4[(n*4 + ks)*64 + l];
        c = __builtin_amdgcn_mfma_f32_16x16x32_f16(
            __builtin_bit_cast(f16x8, a[ks]), __builtin_bit_cast(f16x8, w), c, 0, 0, 0);
      }
    } else {
      #pragma unroll
      for (int ks = 0; ks < 4; ++ks){
        uint4 w = W4[(n*4 + ks)*64 + l];
        c = __builtin_amdgcn_mfma_f32_16x16x32_bf16(
            __builtin_bit_cast(s16x8, a[ks]), __builtin_bit_cast(s16x8, w), c, 0, 0, 0);
      }
    }
    acc[n] = c;
  }
  float iv[4]; int mi[4];
  #pragma unroll
  for (int r = 0; r < 4; ++r){ iv[r] = invn[rbase + r]; mi[r] = midx[rbase + r]; }
  float ssv[4] = {0,0,0,0};
  #pragma unroll
  for (int n = 0; n < 13; ++n){
    const int col = n*16 + c15;
    if (col < 200){
      #pragma unroll
      for (int r = 0; r < 4; ++r){
        float v = acc[n][r]*iv[r];
        if (mi[r] >= 0) v += x2m[(size_t)mi[r]*200 + col];
        acc[n][r] = v;
        ssv[r] += v*v;
      }
    }
  }
  #pragma unroll
  for (int o = 1; o < 16; o <<= 1){
    #pragma unroll
    for (int r = 0; r < 4; ++r) ssv[r] += __shfl_xor(ssv[r], o);
  }
  float rn[4];
  #pragma unroll
  for (int r = 0; r < 4; ++r) rn[r] = 1.f / fmaxf(sqrtf(ssv[r]), 1e-12f);
  #pragma unroll
  for (int n = 0; n < 13; ++n){
    const int col = n*16 + c15;
    if (col < 200){
      #pragma unroll
      for (int r = 0; r < 4; ++r)
        stf(dout, (size_t)(rbase + r)*200 + col, acc[n][r]*rn[r], fdt);
    }
  }
}

// ---- 64-node/block matvec over compacted flagged list: D2 (K=200, both phases staged) ----
__global__ __launch_bounds__(256)
void k_D2b(const __half* __restrict__ x1, const int* __restrict__ flist, const int* __restrict__ fcnt,
           const __half* __restrict__ W16d2T, const float* __restrict__ a2of,
           __half* __restrict__ D2, float* __restrict__ sD2)
{
  extern __shared__ __half Wl[];       // 2*200*102 halves = 81600 B (dynamic)
  __shared__ float scr[4*8], outr[8];
  const int t = threadIdx.x;
  const int cnt = fcnt[0];
  const int base0 = blockIdx.x*64;
  if (base0 >= cnt) return;
  uint4* Wl4 = (uint4*)Wl;
  const uint4* Wg = (const uint4*)W16d2T;
  for (int idx = t; idx < 5100; idx += 256) Wl4[idx] = Wg[idx];
  __syncthreads();
  const int col = (t < 200) ? t : 199;
  const bool act = t < 200;
  const float a2v = act ? a2of[col] : 0.f;
  for (int g = 0; g < 8; ++g){
    const int base = base0 + g*8;
    if (base >= cnt) break;            // cnt uniform -> barrier-safe
    int nd[8];
    #pragma unroll
    for (int i = 0; i < 8; ++i){ int j = base + i; nd[i] = flist[j < cnt ? j : cnt-1]; }
    float acc[8] = {0,0,0,0,0,0,0,0};
    #pragma unroll 1
    for (int p = 0; p < 2; ++p){
      const __half* Wp = Wl + p*20400;
      for (int kp = 0; kp < 100; kp += 2){
        __half2 wh = *(const __half2*)&Wp[col*102 + kp];
        float2 wf = __half22float2(wh);
        const int k = p*100 + kp;
        #pragma unroll
        for (int i = 0; i < 8; ++i){
          unsigned int u = *(const unsigned int*)(x1 + (size_t)nd[i]*200 + k);
          __half2 eh = __builtin_bit_cast(__half2, u);
          float2 ef = __half22float2(eh);
          acc[i] += ef.x*wf.x + ef.y*wf.y;
        }
      }
    }
    float ml[8];
    #pragma unroll
    for (int i = 0; i < 8; ++i){
      if (act) D2[(size_t)nd[i]*200 + col] = __float2half_rn(acc[i]);
      ml[i] = acc[i]*a2v;
    }
    #pragma unroll
    for (int i = 0; i < 8; ++i){
      #pragma unroll
      for (int o = 1; o < 64; o <<= 1) ml[i] += __shfl_xor(ml[i], o);
    }
    {
      const int w = threadIdx.x >> 6, ll = threadIdx.x & 63;
      if (ll == 0){
        #pragma unroll
        for (int i = 0; i < 8; ++i) scr[w*8 + i] = ml[i];
      }
      __syncthreads();
      if (t < 8) outr[t] = scr[t] + scr[8+t] + scr[16+t] + scr[24+t];
      __syncthreads();
    }
    if (t < 8){
      int j = base + t;
      if (j < cnt) sD2[flist[j]] = outr[t];
    }
  }
}

// layer 1 aggregation, flagged nodes only
__global__ __launch_bounds__(256)
void k_x1(const void* __restrict__ ent, const float* __restrict__ ENf, const int* __restrict__ ifl,
          const int* __restrict__ nflag, const float* __restrict__ aTs, const float* __restrict__ a2f,
          const float* __restrict__ R1f, const float* __restrict__ sR1,
          const __half* __restrict__ D1, const float* __restrict__ sD,
          const int* __restrict__ offs, const int* __restrict__ csr, __half* __restrict__ x1)
{
  __shared__ float ml[200], sS2[2];
  const int n = blockIdx.x, t = threadIdx.x;
  if (!nflag[n]) return;
  const int fdt = ifl[1];
  const float* ENp = (fdt == 0) ? (const float*)ent : ENf;
  float S = 0.f;
  if (t < 200){
    const float* ep = ENp + (size_t)n*100;
    for (int k = 0; k < 100; ++k) S += ep[k]*aTs[k*200+t];
    ml[t] = S*a2f[t];
  }
  __syncthreads();
  if (t < 64){
    float s = 0.f;
    for (int q = t; q < 100; q += 64) s += ml[q];
    for (int o = 1; o < 64; o <<= 1) s += __shfl_xor(s, o);
    if (t == 0) sS2[0] = s;
  } else if (t < 128){
    int l = t - 64;
    float s = 0.f;
    for (int q = 100 + l; q < 200; q += 64) s += ml[q];
    for (int o = 1; o < 64; o <<= 1) s += __shfl_xor(s, o);
    if (l == 0) sS2[1] = s;
  }
  __syncthreads();
  if (t >= 200) return;
  const int h = (t >= 100) ? 1 : 0;
  const float sS = sS2[h];
  float acc = 0.f, W = 0.f;
  const int beg = offs[n], end = offs[n+1];
  for (int j = beg; j < end; ++j){
    int pk = csr[j];
    int v = pk & 0xFFFF, tt = pk >> 16;
    float d = __half2float(D1[(size_t)v*200 + t]);
    float r = R1f[tt*200 + t];
    float p = sS + sD[(size_t)v*2 + h] + sR1[tt*2 + h];
    float lk = p > 0.f ? p : 0.2f*p;
    float w = expf(-lk);
    acc += w*(d + r); W += w;
  }
  float hh = (S*W + acc) / (W + 1e-12f);
  x1[(size_t)n*200 + t] = __float2half_rn(hh > 0.f ? hh : (expf(hh) - 1.f));
}

// layer 2, masked nodes only
__global__ __launch_bounds__(256)
void k_x2m(const int* __restrict__ b32, const __half* __restrict__ x1, const float* __restrict__ aoTs,
           const float* __restrict__ a2of, const float* __restrict__ R2f, const float* __restrict__ sR2,
           const __half* __restrict__ D2, const float* __restrict__ sD2,
           const int* __restrict__ offs, const int* __restrict__ csr, float* __restrict__ x2m)
{
  __shared__ float xn[200], ml[200], sS2[1];
  const int i = blockIdx.x, t = threadIdx.x;
  const int n = b32[i*4 + 2];
  if (t < 200) xn[t] = __half2float(x1[(size_t)n*200 + t]);
  __syncthreads();
  float S = 0.f;
  if (t < 200){
    for (int k = 0; k < 200; ++k) S += xn[k]*aoTs[k*200+t];
    ml[t] = S*a2of[t];
  }
  __syncthreads();
  if (t < 64){
    float s = 0.f;
    for (int q = t; q < 200; q += 64) s += ml[q];
    for (int o = 1; o < 64; o <<= 1) s += __shfl_xor(s, o);
    if (t == 0) sS2[0] = s;
  }
  __syncthreads();
  if (t >= 200) return;
  const float sS = sS2[0];
  float acc = 0.f, W = 0.f;
  const int beg = offs[n], end = offs[n+1];
  for (int j = beg; j < end; ++j){
    int pk = csr[j];
    int v = pk & 0xFFFF, tt = pk >> 16;
    float d = __half2float(D2[(size_t)v*200 + t]);
    float r = R2f[tt*200 + t];
    float p = sS + sD2[v] + sR2[tt];
    float lk = p > 0.f ? p : 0.2f*p;
    float w = expf(-lk);
    acc += w*(d + r); W += w;
  }
  float hh = (S*W + acc) / (W + 1e-12f);
  x2m[(size_t)i*200 + t] = hh > 0.f ? hh : (expf(hh) - 1.f);
}

// ---------------- his_temp: LDS tile + 16B vector stores ----------------
__global__ __launch_bounds__(256)
void k_his(const void* __restrict__ binp, const void* __restrict__ wt, const void* __restrict__ bt,
           const int* __restrict__ ifl, char* __restrict__ dout)
{
  __shared__ float he[100];
  __shared__ uint4 tile[50];
  const int i = blockIdx.x, t = threadIdx.x;
  const int fdt = ifl[1];
  const double t2 = (double)ild(binp, (size_t)i*4 + 3, ifl[0]);
  if (t < 100){
    double a = t2 * (double)ldf(wt, t, fdt) + (double)ldf(bt, t, fdt);
    he[t] = (float)cos(a);
  }
  __syncthreads();
  if (fdt == 0){
    float* tf = (float*)tile;          // 100 floats = 25 uint4, period 100
    if (t < 100) tf[t] = he[t];
    __syncthreads();
    uint4* out4 = (uint4*)(dout + 40000000 + (size_t)i*204800);
    for (int idx = t; idx < 12800; idx += 256) out4[idx] = tile[idx % 25];
  } else {
    unsigned short* th = (unsigned short*)tile;   // 400 halves = 50 uint4, period 400
    for (int j = t; j < 400; j += 256){
      float v = he[j % 100];
      th[j] = (fdt == 2) ? __builtin_bit_cast(unsigned short, __float2half_rn(v)) : f2bf(v);
    }
    __syncthreads();
    uint4* out4 = (uint4*)(dout + 20000000 + (size_t)i*102400);
    for (int idx = t; idx < 6400; idx += 256) out4[idx] = tile[idx % 50];
  }
}

// ---------------- launch ----------------
extern "C" void kernel_launch(void* const* d_in, const int* in_sizes, int n_in,
                              void* d_out, int out_size, void* d_ws, size_t ws_size,
                              hipStream_t stream)
{
  (void)in_sizes; (void)n_in; (void)out_size; (void)ws_size;
  const void* ent  = d_in[0];
  const void* rtab = d_in[1];
  const void* w_t2 = d_in[2];
  const void* b_t2 = d_in[3];
  const void* Went = d_in[4];
  const void* ah   = d_in[5];
  const void* a2h  = d_in[6];
  const void* Wrel = d_in[7];
  const void* aout = d_in[8];
  const void* a2o  = d_in[9];
  const void* elist = d_in[10];
  const void* etype = d_in[11];
  const void* binp  = d_in[12];

  int* ifl = (int*)d_ws;                         // [0]=int64 flag, [1]=float dtype
  int* b32 = (int*)((char*)d_ws + 256);          // 2048 ints

  char* dout = (char*)d_out;
  // ENf at [0,20MB): f32 copy of ent (16-bit dtypes only); consumed by k_x1, then
  // overwritten by k_gemmEuf's out0 stores. In f32 mode ENf unused (ent read directly).
  float* ENf = (float*)dout;
  // Region A [20MB,40MB): D1 then D2 (fp16).
  __half* D12 = (__half*)(dout + 20000000);
  // Region B [40MB,~66.7MB): consumed by kernels up to k_gemmEuf; inside out1 for all dtypes.
  char* scr = dout + 40000000;
  size_t cur = 0;
  auto alloc = [&](size_t bytes) -> char* {
    char* p = scr + cur;
    cur = (cur + bytes + 255) & ~(size_t)255;
    return p;
  };
  __half* X1     = (__half*)alloc((size_t)N_NODES*200*2);   // 20 MB
  int*   csr     = (int*)alloc((size_t)E_EDGES*4);          // 3.2 MB
  int*   offs    = (int*)alloc((size_t)(N_NODES+1)*4);
  int*   cnt     = (int*)alloc((size_t)N_NODES*4);
  int*   midx    = (int*)alloc((size_t)N_NODES*4);
  int*   nflag   = (int*)alloc((size_t)N_NODES*4);
  int*   flist   = (int*)alloc((size_t)N_NODES*4);
  int*   fcnt    = (int*)alloc(256);
  float* invn    = (float*)alloc((size_t)N_NODES*4);
  float* M2f     = (float*)alloc((size_t)200*200*4);
  float* x2m     = (float*)alloc((size_t)B_BATCH*200*4);
  float* aTs     = (float*)alloc((size_t)100*200*4);
  float* aoTs    = (float*)alloc((size_t)200*200*4);
  float* R1f     = (float*)alloc((size_t)200*200*4);
  float* R2f     = (float*)alloc((size_t)200*200*4);
  float* sD      = (float*)alloc((size_t)N_NODES*2*4);
  float* sD2     = (float*)alloc((size_t)N_NODES*4);
  float* sR1     = (float*)alloc((size_t)200*2*4);
  float* sR2     = (float*)alloc((size_t)200*4);
  float* a2f     = (float*)alloc((size_t)200*4);
  float* a2of    = (float*)alloc((size_t)200*4);
  unsigned short* WswE = (unsigned short*)alloc((size_t)26624*2);   // MFMA B-frag tables
  unsigned short* WswD = (unsigned short*)alloc((size_t)26624*2);
  __half* W16d2T = (__half*)alloc((size_t)2*200*102*2);
  // total ~26.7 MB -> ends ~66.7 MB < 72.4 MB (min d_out at esize=2)

  const int EB = (E_EDGES + 255) / 256;
  const int NB = (N_NODES + 255) / 256;

  k_probe<<<dim3(1), dim3(64), 0, stream>>>((const unsigned short*)ent, (const unsigned int*)ent,
                                            (const unsigned int*)elist, ifl);
  k_cvtb <<<dim3(8), dim3(256), 0, stream>>>(binp, ifl, b32);
  k_fillm<<<dim3(NB), dim3(256), 0, stream>>>(midx, -1, N_NODES);
  k_mset <<<dim3(2), dim3(256), 0, stream>>>(b32, midx);
  k_trans<<<dim3(237), dim3(256), 0, stream>>>(ah, aout, a2h, a2o, ifl, aTs, aoTs, a2f, a2of);
  k_w16  <<<dim3(160), dim3(256), 0, stream>>>(aout, ifl, W16d2T);
  k_wsw  <<<dim3(208), dim3(256), 0, stream>>>(Went, ah, ifl, WswE, WswD);
  k_cvt_en<<<dim3(N_NODES/4), dim3(256), 0, stream>>>(ent, ifl, ENf, invn);
  k_m2f  <<<dim3(157), dim3(256), 0, stream>>>(rtab, Wrel, etype, ifl, M2f);
  k_R1   <<<dim3(200), dim3(256), 0, stream>>>(rtab, ah, ifl, a2f, R1f, sR1);
  k_R2   <<<dim3(200), dim3(256), 0, stream>>>(M2f, aout, ifl, a2of, R2f, sR2);

  k_fillm<<<dim3(NB), dim3(256), 0, stream>>>(cnt, 0, N_NODES);
  k_count<<<dim3(EB), dim3(256), 0, stream>>>(elist, ifl, cnt);
  k_scan <<<dim3(1), dim3(256), 0, stream>>>(cnt, offs);
  k_fillm<<<dim3(NB), dim3(256), 0, stream>>>(cnt, 0, N_NODES);
  k_scatter<<<dim3(EB), dim3(256), 0, stream>>>(elist, etype, ifl, offs, cnt, csr);

  k_fillm<<<dim3(NB), dim3(256), 0, stream>>>(nflag, 0, N_NODES);
  k_flag <<<dim3(B_BATCH), dim3(256), 0, stream>>>(b32, offs, csr, nflag);
  k_fillm<<<dim3(1), dim3(256), 0, stream>>>(fcnt, 0, 1);
  k_compact<<<dim3(NB), dim3(256), 0, stream>>>(nflag, fcnt, flist);

  k_gemmD1<<<dim3(782), dim3(256), 0, stream>>>(ent, ifl, WswD, a2f, D12, sD);
  k_x1 <<<dim3(N_NODES), dim3(256), 0, stream>>>(ent, ENf, ifl, nflag, aTs, a2f, R1f, sR1, D12, sD, offs, csr, X1);
  k_D2b<<<dim3((N_NODES+63)/64), dim3(256), 81600, stream>>>(X1, flist, fcnt, W16d2T, a2of, D12, sD2);
  k_x2m<<<dim3(B_BATCH), dim3(256), 0, stream>>>(b32, X1, aoTs, a2of, R2f, sR2, D12, sD2, offs, csr, x2m);
  k_gemmEuf<<<dim3(782), dim3(256), 0, stream>>>(ent, ifl, WswE, invn, midx, x2m, dout);

  // LAST: overwrites all of out1 (incl. all scratch); reads only inputs + ifl
  k_his<<<dim3(B_BATCH), dim3(256), 0, stream>>>(binp, w_t2, b_t2, ifl, dout);
}

// Round 5
// 616.243 us; speedup vs baseline: 1.8366x; 1.2955x over previous
//
#include <hip/hip_runtime.h>
#include <hip/hip_fp16.h>
#include <stdint.h>

#define N_NODES 50000
#define FIN_D   100
#define E_EDGES 800000
#define NRELS   200
#define B_BATCH 512
#define HDIM    100

typedef _Float16 f16x8 __attribute__((ext_vector_type(8)));
typedef short    s16x8 __attribute__((ext_vector_type(8)));
typedef float    f32x4v __attribute__((ext_vector_type(4)));

__device__ __forceinline__ unsigned short f2bf(float f){
  unsigned int x = __builtin_bit_cast(unsigned int, f);
  unsigned int lsb = (x >> 16) & 1u;
  x += 0x7fffu + lsb;
  return (unsigned short)(x >> 16);
}
// float-tensor load: fdt 2=fp16, 1=bf16, 0=f32
__device__ __forceinline__ float ldf(const void* p, size_t i, int fdt){
  if (fdt == 2) return __half2float(((const __half*)p)[i]);
  if (fdt == 1){ unsigned int x = ((unsigned int)((const unsigned short*)p)[i]) << 16;
                 return __builtin_bit_cast(float, x); }
  return ((const float*)p)[i];
}
// output store, same dtype as inputs
__device__ __forceinline__ void stf(void* p, size_t i, float v, int fdt){
  if (fdt == 2) ((__half*)p)[i] = __float2half_rn(v);
  else if (fdt == 1) ((unsigned short*)p)[i] = f2bf(v);
  else ((float*)p)[i] = v;
}
// integer-tensor load: i64 flag
__device__ __forceinline__ int ild(const void* p, size_t i, int i64){
  return i64 ? (int)((const long long*)p)[i] : ((const int*)p)[i];
}

// ---------------- dtype probes ----------------
__global__ void k_probe(const unsigned short* __restrict__ eh, const unsigned int* __restrict__ ew,
                        const unsigned int* __restrict__ elw, int* __restrict__ ifl){
  int t = threadIdx.x;   // 64 lanes
  int cF = 0, cB = 0, c32 = 0;
  #pragma unroll
  for (int j = 0; j < 4; ++j){
    unsigned short u = eh[4*t + j];
    {
      int e5 = (u >> 10) & 31, m = u & 1023;
      float v = (e5 == 0) ? ldexpf((float)m, -24) : ldexpf(1.f + m/1024.f, e5 - 15);
      if (v >= 0.004f && v <= 0.30f) cF++;
    }
    {
      unsigned int x = ((unsigned int)(u & 0x7FFF)) << 16;
      float v = __builtin_bit_cast(float, x);
      if (v >= 0.004f && v <= 0.30f) cB++;
    }
  }
  #pragma unroll
  for (int j = 0; j < 2; ++j){
    unsigned int w = ew[2*t + j] & 0x7FFFFFFFu;
    float v = __builtin_bit_cast(float, w);
    if (v >= 0.004f && v <= 0.30f) c32++;
  }
  for (int o = 1; o < 64; o <<= 1){
    cF += __shfl_xor(cF, o); cB += __shfl_xor(cB, o); c32 += __shfl_xor(c32, o);
  }
  int z = (elw[2*t + 1] == 0u) ? 1 : 0;
  unsigned long long mb = __ballot(z);
  if (t == 0){
    int fdt;
    if (c32 >= 96) fdt = 0;
    else fdt = (cB > cF) ? 1 : 2;
    ifl[1] = fdt;
    ifl[0] = (__popcll(mb) >= 60) ? 1 : 0;
  }
}

// ---------------- setup ----------------
__global__ void k_fillm(int* __restrict__ p, int v, int n){
  int i = blockIdx.x * blockDim.x + threadIdx.x;
  if (i < n) p[i] = v;
}
__global__ void k_cvtb(const void* __restrict__ binp, const int* __restrict__ ifl, int* __restrict__ b32){
  int i = blockIdx.x*256 + threadIdx.x;
  if (i >= B_BATCH*4) return;
  b32[i] = ild(binp, i, ifl[0]);
}
__global__ void k_mset(const int* __restrict__ b32, int* __restrict__ midx){
  int i = blockIdx.x*256 + threadIdx.x;
  if (i >= B_BATCH) return;
  midx[b32[i*4 + 2]] = i;
}
// M2f[r][j] = rtab[edge_type[r]] @ W_rel
__global__ void k_m2f(const void* __restrict__ rtab, const void* __restrict__ wrel,
                      const void* __restrict__ et, const int* __restrict__ ifl, float* __restrict__ M2){
  int idx = blockIdx.x*256 + threadIdx.x;
  if (idx >= 200*200) return;
  int fdt = ifl[1];
  int r = idx / 200, j = idx % 200;
  int g = ild(et, r, ifl[0]);
  float s = 0.f;
  for (int k = 0; k < 100; ++k) s += ldf(rtab, (size_t)g*100 + k, fdt) * ldf(wrel, (size_t)k*200 + j, fdt);
  M2[idx] = s;
}

// transpose attention matrices into coalesced-friendly f32 layouts
__global__ void k_trans(const void* __restrict__ ah, const void* __restrict__ aout,
                        const void* __restrict__ a2h, const void* __restrict__ a2o,
                        const int* __restrict__ ifl,
                        float* __restrict__ aTs, float* __restrict__ aoTs,
                        float* __restrict__ a2f, float* __restrict__ a2of){
  int i = blockIdx.x*256 + threadIdx.x;
  int fdt = ifl[1];
  if (i < 20000){ int k=i/200, t=i%200; aTs[i] = ldf(ah,(size_t)t*300+k,fdt); return; }
  i -= 20000;
  if (i < 40000){ int k=i/200, t=i%200; aoTs[i] = ldf(aout,(size_t)t*600+k,fdt); return; }
  i -= 40000;
  if (i < 200){ a2f[i] = ldf(a2h, i, fdt); return; }
  i -= 200;
  if (i < 200){ a2of[i] = ldf(a2o, i, fdt); return; }
}

// MFMA B-operand swizzled weight tables (16-bit; fp16 if fdt==2 else bf16).
// halves layout: [n(13)][ks(4)][lane(64)][j(8)]; element = W[k][col],
// k = ks*32 + (lane>>4)*8 + j, col = n*16 + (lane&15); zero pad k>=100 / col>=200.
__global__ void k_wsw(const void* __restrict__ went, const void* __restrict__ ah,
                      const int* __restrict__ ifl,
                      unsigned short* __restrict__ WswE, unsigned short* __restrict__ WswD){
  int i = blockIdx.x*256 + threadIdx.x;
  if (i >= 2*26624) return;
  int fdt = ifl[1];
  int tbl = i / 26624, r0 = i % 26624;
  int j = r0 & 7, l = (r0>>3) & 63, ks = (r0>>9) & 3, n = r0>>11;
  int k = ks*32 + (l>>4)*8 + j;
  int col = n*16 + (l&15);
  float v = 0.f;
  if (k < 100 && col < 200)
    v = tbl ? ldf(ah, (size_t)col*300 + 100 + k, fdt) : ldf(went, (size_t)k*200 + col, fdt);
  unsigned short h = (fdt == 2) ? __builtin_bit_cast(unsigned short, __float2half_rn(v)) : f2bf(v);
  (tbl ? WswD : WswE)[r0] = h;
}

// MFMA B-table for D2 GEMM (ALWAYS fp16: A comes from X1 which is fp16).
// halves layout: [n(13)][ks(7)][lane(64)][j(8)]; element = aout[col][200+k],
// k = ks*32 + (lane>>4)*8 + j (K=200 pad 224), col = n*16 + (lane&15).
__global__ void k_wsw2(const void* __restrict__ aout, const int* __restrict__ ifl,
                       unsigned short* __restrict__ WswD2){
  int i = blockIdx.x*256 + threadIdx.x;
  if (i >= 46592) return;
  int fdt = ifl[1];
  int j = i & 7, l = (i>>3) & 63, r = i >> 9;   // r = n*7 + ks
  int ks = r % 7, n = r / 7;
  int k = ks*32 + (l>>4)*8 + j;
  int col = n*16 + (l&15);
  float v = (k < 200 && col < 200) ? ldf(aout, (size_t)col*600 + 200 + k, fdt) : 0.f;
  WswD2[i] = __builtin_bit_cast(unsigned short, __float2half_rn(v));
}

// f32 copy of entity rows + per-node inverse norms. One wave per row, 4 rows/block.
__global__ __launch_bounds__(256)
void k_cvt_en(const void* __restrict__ ent, const int* __restrict__ ifl,
              float* __restrict__ ENf, float* __restrict__ invn){
  const int w = threadIdx.x >> 6, l = threadIdx.x & 63;
  const int n = blockIdx.x*4 + w;
  const int fdt = ifl[1];
  float x = 0.f, y = 0.f;
  if (l < 50){
    if (fdt == 0){
      float2 v = ((const float2*)ent)[(size_t)n*50 + l];
      x = v.x; y = v.y;
    } else if (fdt == 2){
      __half2 h = ((const __half2*)ent)[(size_t)n*50 + l];
      float2 v = __half22float2(h); x = v.x; y = v.y;
    } else {
      unsigned int u = ((const unsigned int*)ent)[(size_t)n*50 + l];
      x = __builtin_bit_cast(float, u << 16);
      y = __builtin_bit_cast(float, u & 0xFFFF0000u);
    }
    if (fdt != 0) ((float2*)ENf)[(size_t)n*50 + l] = make_float2(x, y);
  }
  float ss = x*x + y*y;
  #pragma unroll
  for (int o = 1; o < 64; o <<= 1) ss += __shfl_xor(ss, o);
  if (l == 0) invn[n] = 1.f / fmaxf(sqrtf(ss), 1e-12f);
}

// R1f[tt][t] = rtab[tt] @ a_rel.T ; sR1[tt][h]
__global__ __launch_bounds__(256)
void k_R1(const void* __restrict__ rtab, const void* __restrict__ ah, const int* __restrict__ ifl,
          const float* __restrict__ a2f, float* __restrict__ R1f, float* __restrict__ sR1){
  __shared__ float rt[100], ml[200];
  const int tt = blockIdx.x, t = threadIdx.x, fdt = ifl[1];
  if (t < 100) rt[t] = ldf(rtab,(size_t)tt*100+t,fdt);
  __syncthreads();
  if (t < 200){
    float R = 0.f;
    for (int k = 0; k < 100; ++k) R += rt[k]*ldf(ah,(size_t)t*300+200+k,fdt);
    R1f[tt*200+t] = R; ml[t] = R*a2f[t];
  }
  __syncthreads();
  if (t < 64){
    float s = 0.f;
    for (int q = t; q < 100; q += 64) s += ml[q];
    for (int o = 1; o < 64; o <<= 1) s += __shfl_xor(s, o);
    if (t == 0) sR1[tt*2] = s;
  } else if (t < 128){
    int l = t - 64;
    float s = 0.f;
    for (int q = 100 + l; q < 200; q += 64) s += ml[q];
    for (int o = 1; o < 64; o <<= 1) s += __shfl_xor(s, o);
    if (l == 0) sR1[tt*2+1] = s;
  }
}

// R2f[tt][t] = M2f[tt] @ a_rel2.T ; sR2[tt]
__global__ __launch_bounds__(256)
void k_R2(const float* __restrict__ M2f, const void* __restrict__ aout, const int* __restrict__ ifl,
          const float* __restrict__ a2of, float* __restrict__ R2f, float* __restrict__ sR2){
  __shared__ float mr[200], ml[200];
  const int tt = blockIdx.x, t = threadIdx.x, fdt = ifl[1];
  if (t < 200) mr[t] = M2f[tt*200+t];
  __syncthreads();
  if (t < 200){
    float R = 0.f;
    for (int k = 0; k < 200; ++k) R += mr[k]*ldf(aout,(size_t)t*600+400+k,fdt);
    R2f[tt*200+t] = R; ml[t] = R*a2of[t];
  }
  __syncthreads();
  if (t < 64){
    float s = 0.f;
    for (int q = t; q < 200; q += 64) s += ml[q];
    for (int o = 1; o < 64; o <<= 1) s += __shfl_xor(s, o);
    if (t == 0) sR2[tt] = s;
  }
}

// ---------------- CSR (packed: dst | type<<16) ----------------
__global__ void k_count(const void* __restrict__ el, const int* __restrict__ ifl, int* __restrict__ cnt){
  int e = blockIdx.x*256 + threadIdx.x;
  if (e >= E_EDGES) return;
  atomicAdd(&cnt[ild(el, e, ifl[0])], 1);
}
__global__ __launch_bounds__(256)
void k_scan(const int* __restrict__ cnt, int* __restrict__ offs){
  __shared__ int bs[256];
  int t = threadIdx.x;
  const int CH = (N_NODES + 255) / 256;
  int lo = t*CH, hi = min(lo+CH, N_NODES);
  int s = 0;
  for (int i = lo; i < hi; ++i) s += cnt[i];
  bs[t] = s;
  __syncthreads();
  for (int o = 1; o < 256; o <<= 1){
    int v = (t >= o) ? bs[t-o] : 0;
    __syncthreads();
    bs[t] += v;
    __syncthreads();
  }
  int base = (t == 0) ? 0 : bs[t-1];
  for (int i = lo; i < hi; ++i){ offs[i] = base; base += cnt[i]; }
  if (t == 255) offs[N_NODES] = bs[255];
}
__global__ void k_scatter(const void* __restrict__ el, const void* __restrict__ et,
                          const int* __restrict__ ifl, const int* __restrict__ offs,
                          int* __restrict__ fill, int* __restrict__ csr){
  int e = blockIdx.x*256 + threadIdx.x;
  if (e >= E_EDGES) return;
  int f = ifl[0];
  int a = ild(el, e, f);
  int pos = offs[a] + atomicAdd(&fill[a], 1);
  csr[pos] = ild(el, (size_t)E_EDGES + e, f) | (ild(et, e, f) << 16);
}

// flag = masked nodes + their neighbors
__global__ void k_flag(const int* __restrict__ b32, const int* __restrict__ offs,
                       const int* __restrict__ csr, int* __restrict__ nflag){
  const int i = blockIdx.x, t = threadIdx.x;
  const int n = b32[i*4 + 2];
  if (t == 0) nflag[n] = 1;
  for (int j = offs[n] + t; j < offs[n+1]; j += 256) nflag[csr[j] & 0xFFFF] = 1;
}
__global__ void k_compact(const int* __restrict__ nflag, int* __restrict__ fcnt, int* __restrict__ flist){
  int i = blockIdx.x*256 + threadIdx.x;
  if (i < N_NODES && nflag[i]) flist[atomicAdd(fcnt, 1)] = i;
}

// ---- A-fragment gather for EN GEMMs (K=100 padded to 128; tail zeroed in regs) ----
__device__ __forceinline__ void loadA(const void* ent, int fdt, int arow, int koff, uint4* a){
  if (fdt != 0){
    const unsigned short* E = (const unsigned short*)ent;
    #pragma unroll
    for (int ks = 0; ks < 3; ++ks){
      const uint2* p = (const uint2*)(E + (size_t)arow*100 + ks*32 + koff);
      uint2 u0 = p[0], u1 = p[1];
      a[ks] = make_uint4(u0.x, u0.y, u1.x, u1.y);
    }
    if (koff == 0){
      const uint2* p = (const uint2*)(E + (size_t)arow*100 + 96);
      uint2 u0 = p[0];
      a[3] = make_uint4(u0.x, u0.y, 0, 0);        // k=96..99 valid, 100..103 zeroed
    } else a[3] = make_uint4(0,0,0,0);
  } else {
    const float* E = (const float*)ent;
    #pragma unroll
    for (int ks = 0; ks < 3; ++ks){
      const uint4* p = (const uint4*)(E + (size_t)arow*100 + ks*32 + koff);
      uint4 lo = p[0], hi = p[1];
      a[ks].x = (lo.x>>16) | (lo.y & 0xFFFF0000u);
      a[ks].y = (lo.z>>16) | (lo.w & 0xFFFF0000u);
      a[ks].z = (hi.x>>16) | (hi.y & 0xFFFF0000u);
      a[ks].w = (hi.z>>16) | (hi.w & 0xFFFF0000u);
    }
    if (koff == 0){
      const uint4* p = (const uint4*)(E + (size_t)arow*100 + 96);
      uint4 lo = p[0];
      a[3] = make_uint4((lo.x>>16)|(lo.y&0xFFFF0000u), (lo.z>>16)|(lo.w&0xFFFF0000u), 0, 0);
    } else a[3] = make_uint4(0,0,0,0);
  }
}

// ---- MFMA GEMM: D1 = EN @ a_dst.T  (+ sD head sums) ----
__global__ __launch_bounds__(256)
void k_gemmD1(const void* __restrict__ ent, const int* __restrict__ ifl,
              const unsigned short* __restrict__ WswD, const float* __restrict__ a2f,
              __half* __restrict__ D1, float* __restrict__ sD)
{
  const int wid = threadIdx.x >> 6, l = threadIdx.x & 63;
  const int mt = blockIdx.x*4 + wid;
  if (mt >= 3125) return;
  const int fdt = ifl[1];
  const int arow = mt*16 + (l & 15);
  const int koff = (l >> 4)*8;
  uint4 a[4];
  loadA(ent, fdt, arow, koff, a);
  const int c15 = l & 15;
  const int rbase = mt*16 + (l >> 4)*4;
  float sh0[4] = {0,0,0,0}, sh1[4] = {0,0,0,0};
  const uint4* W4 = (const uint4*)WswD;
  #pragma unroll
  for (int n = 0; n < 13; ++n){
    const int col = n*16 + c15;
    f32x4v acc = {0.f, 0.f, 0.f, 0.f};
    if (fdt == 2){
      #pragma unroll
      for (int ks = 0; ks < 4; ++ks){
        uint4 w = W4[(n*4 + ks)*64 + l];
        acc = __builtin_amdgcn_mfma_f32_16x16x32_f16(
            __builtin_bit_cast(f16x8, a[ks]), __builtin_bit_cast(f16x8, w), acc, 0, 0, 0);
      }
    } else {
      #pragma unroll
      for (int ks = 0; ks < 4; ++ks){
        uint4 w = W4[(n*4 + ks)*64 + l];
        acc = __builtin_amdgcn_mfma_f32_16x16x32_bf16(
            __builtin_bit_cast(s16x8, a[ks]), __builtin_bit_cast(s16x8, w), acc, 0, 0, 0);
      }
    }
    const float a2v = (col < 200) ? a2f[col] : 0.f;
    #pragma unroll
    for (int r = 0; r < 4; ++r){
      float v = acc[r];
      if (col < 200) D1[(size_t)(rbase + r)*200 + col] = __float2half_rn(v);
      float m = v*a2v;
      if (col < 100) sh0[r] += m; else sh1[r] += m;
    }
  }
  #pragma unroll
  for (int o = 1; o < 16; o <<= 1){
    #pragma unroll
    for (int r = 0; r < 4; ++r){
      sh0[r] += __shfl_xor(sh0[r], o);
      sh1[r] += __shfl_xor(sh1[r], o);
    }
  }
  if (c15 == 0){
    #pragma unroll
    for (int r = 0; r < 4; ++r){
      sD[(size_t)(rbase + r)*2]     = sh0[r];
      sD[(size_t)(rbase + r)*2 + 1] = sh1[r];
    }
  }
}

// ---- MFMA GEMM + epilogue: out0 = l2norm(EN@Went * invn + mask*x2m) ----
__global__ __launch_bounds__(256)
void k_gemmEuf(const void* __restrict__ ent, const int* __restrict__ ifl,
               const unsigned short* __restrict__ WswE, const float* __restrict__ invn,
               const int* __restrict__ midx, const float* __restrict__ x2m, char* __restrict__ dout)
{
  const int wid = threadIdx.x >> 6, l = threadIdx.x & 63;
  const int mt = blockIdx.x*4 + wid;
  if (mt >= 3125) return;
  const int fdt = ifl[1];
  const int arow = mt*16 + (l & 15);
  const int koff = (l >> 4)*8;
  uint4 a[4];
  loadA(ent, fdt, arow, koff, a);
  const int c15 = l & 15;
  const int rbase = mt*16 + (l >> 4)*4;
  f32x4v acc[13];
  const uint4* W4 = (const uint4*)WswE;
  #pragma unroll
  for (int n = 0; n < 13; ++n){
    f32x4v c = {0.f, 0.f, 0.f, 0.f};
    if (fdt == 2){
      #pragma unroll
      for (int ks = 0; ks < 4; ++ks){
        uint4 w = W4[(n*4 + ks)*64 + l];
        c = __builtin_amdgcn_mfma_f32_16x16x32_f16(
            __builtin_bit_cast(f16x8, a[ks]), __builtin_bit_cast(f16x8, w), c, 0, 0, 0);
      }
    } else {
      #pragma unroll
      for (int ks = 0; ks < 4; ++ks){
        uint4 w = W4[(n*4 + ks)*64 + l];
        c = __builtin_amdgcn_mfma_f32_16x16x32_bf16(
            __builtin_bit_cast(s16x8, a[ks]), __builtin_bit_cast(s16x8, w), c, 0, 0, 0);
      }
    }
    acc[n] = c;
  }
  float iv[4]; int mi[4];
  #pragma unroll
  for (int r = 0; r < 4; ++r){ iv[r] = invn[rbase + r]; mi[r] = midx[rbase + r]; }
  float ssv[4] = {0,0,0,0};
  #pragma unroll
  for (int n = 0; n < 13; ++n){
    const int col = n*16 + c15;
    if (col < 200){
      #pragma unroll
      for (int r = 0; r < 4; ++r){
        float v = acc[n][r]*iv[r];
        if (mi[r] >= 0) v += x2m[(size_t)mi[r]*200 + col];
        acc[n][r] = v;
        ssv[r] += v*v;
      }
    }
  }
  #pragma unroll
  for (int o = 1; o < 16; o <<= 1){
    #pragma unroll
    for (int r = 0; r < 4; ++r) ssv[r] += __shfl_xor(ssv[r], o);
  }
  float rn[4];
  #pragma unroll
  for (int r = 0; r < 4; ++r) rn[r] = 1.f / fmaxf(sqrtf(ssv[r]), 1e-12f);
  #pragma unroll
  for (int n = 0; n < 13; ++n){
    const int col = n*16 + c15;
    if (col < 200){
      #pragma unroll
      for (int r = 0; r < 4; ++r)
        stf(dout, (size_t)(rbase + r)*200 + col, acc[n][r]*rn[r], fdt);
    }
  }
}

// ---- MFMA GEMM over compacted flagged list: D2 = X1[flist] @ a_dst2.T (+ sD2) ----
// A is X1 (always fp16) -> f16 MFMA unconditionally. K=200 padded to 224.
__global__ __launch_bounds__(256)
void k_D2g(const __half* __restrict__ x1, const int* __restrict__ flist, const int* __restrict__ fcnt,
           const unsigned short* __restrict__ WswD2, const float* __restrict__ a2of,
           __half* __restrict__ D2, float* __restrict__ sD2)
{
  const int wid = threadIdx.x >> 6, l = threadIdx.x & 63;
  const int mt = blockIdx.x*4 + wid;
  const int cnt = fcnt[0];
  if (mt*16 >= cnt) return;
  const int c15 = l & 15;
  const int koff = (l >> 4)*8;
  int ar = mt*16 + c15; if (ar >= cnt) ar = cnt - 1;
  const __half* xr = x1 + (size_t)flist[ar]*200;
  uint4 a[7];
  #pragma unroll
  for (int ks = 0; ks < 6; ++ks)
    a[ks] = *(const uint4*)(xr + ks*32 + koff);
  a[6] = (koff == 0) ? *(const uint4*)(xr + 192) : make_uint4(0,0,0,0);
  const int rbase = mt*16 + (l >> 4)*4;
  int ndR[4]; bool okR[4];
  #pragma unroll
  for (int r = 0; r < 4; ++r){
    int rr = rbase + r;
    okR[r] = rr < cnt;
    ndR[r] = flist[okR[r] ? rr : cnt - 1];
  }
  float sh[4] = {0,0,0,0};
  const uint4* W4 = (const uint4*)WswD2;
  #pragma unroll
  for (int n = 0; n < 13; ++n){
    const int col = n*16 + c15;
    f32x4v acc = {0.f, 0.f, 0.f, 0.f};
    #pragma unroll
    for (int ks = 0; ks < 7; ++ks){
      uint4 w = W4[(n*7 + ks)*64 + l];
      acc = __builtin_amdgcn_mfma_f32_16x16x32_f16(
          __builtin_bit_cast(f16x8, a[ks]), __builtin_bit_cast(f16x8, w), acc, 0, 0, 0);
    }
    const float a2v = (col < 200) ? a2of[col] : 0.f;
    #pragma unroll
    for (int r = 0; r < 4; ++r){
      float v = acc[r];
      if (col < 200 && okR[r]) D2[(size_t)ndR[r]*200 + col] = __float2half_rn(v);
      sh[r] += v*a2v;
    }
  }
  #pragma unroll
  for (int o = 1; o < 16; o <<= 1){
    #pragma unroll
    for (int r = 0; r < 4; ++r) sh[r] += __shfl_xor(sh[r], o);
  }
  if (c15 == 0){
    #pragma unroll
    for (int r = 0; r < 4; ++r)
      if (okR[r]) sD2[ndR[r]] = sh[r];
  }
}

// layer 1 aggregation, over compacted flagged list (contiguous active blocks)
__global__ __launch_bounds__(256)
void k_x1(const void* __restrict__ ent, const float* __restrict__ ENf, const int* __restrict__ ifl,
          const int* __restrict__ flist, const int* __restrict__ fcnt,
          const float* __restrict__ aTs, const float* __restrict__ a2f,
          const float* __restrict__ R1f, const float* __restrict__ sR1,
          const __half* __restrict__ D1, const float* __restrict__ sD,
          const int* __restrict__ offs, const int* __restrict__ csr, __half* __restrict__ x1)
{
  __shared__ float ml[200], sS2[2];
  const int bi = blockIdx.x, t = threadIdx.x;
  if (bi >= fcnt[0]) return;
  const int n = flist[bi];
  const int fdt = ifl[1];
  const float* ENp = (fdt == 0) ? (const float*)ent : ENf;
  float S = 0.f;
  if (t < 200){
    const float* ep = ENp + (size_t)n*100;
    for (int k = 0; k < 100; ++k) S += ep[k]*aTs[k*200+t];
    ml[t] = S*a2f[t];
  }
  __syncthreads();
  if (t < 64){
    float s = 0.f;
    for (int q = t; q < 100; q += 64) s += ml[q];
    for (int o = 1; o < 64; o <<= 1) s += __shfl_xor(s, o);
    if (t == 0) sS2[0] = s;
  } else if (t < 128){
    int l = t - 64;
    float s = 0.f;
    for (int q = 100 + l; q < 200; q += 64) s += ml[q];
    for (int o = 1; o < 64; o <<= 1) s += __shfl_xor(s, o);
    if (l == 0) sS2[1] = s;
  }
  __syncthreads();
  if (t >= 200) return;
  const int h = (t >= 100) ? 1 : 0;
  const float sS = sS2[h];
  float acc = 0.f, W = 0.f;
  const int beg = offs[n], end = offs[n+1];
  for (int j = beg; j < end; ++j){
    int pk = csr[j];
    int v = pk & 0xFFFF, tt = pk >> 16;
    float d = __half2float(D1[(size_t)v*200 + t]);
    float r = R1f[tt*200 + t];
    float p = sS + sD[(size_t)v*2 + h] + sR1[tt*2 + h];
    float lk = p > 0.f ? p : 0.2f*p;
    float w = expf(-lk);
    acc += w*(d + r); W += w;
  }
  float hh = (S*W + acc) / (W + 1e-12f);
  x1[(size_t)n*200 + t] = __float2half_rn(hh > 0.f ? hh : (expf(hh) - 1.f));
}

// layer 2, masked nodes only
__global__ __launch_bounds__(256)
void k_x2m(const int* __restrict__ b32, const __half* __restrict__ x1, const float* __restrict__ aoTs,
           const float* __restrict__ a2of, const float* __restrict__ R2f, const float* __restrict__ sR2,
           const __half* __restrict__ D2, const float* __restrict__ sD2,
           const int* __restrict__ offs, const int* __restrict__ csr, float* __restrict__ x2m)
{
  __shared__ float xn[200], ml[200], sS2[1];
  const int i = blockIdx.x, t = threadIdx.x;
  const int n = b32[i*4 + 2];
  if (t < 200) xn[t] = __half2float(x1[(size_t)n*200 + t]);
  __syncthreads();
  float S = 0.f;
  if (t < 200){
    for (int k = 0; k < 200; ++k) S += xn[k]*aoTs[k*200+t];
    ml[t] = S*a2of[t];
  }
  __syncthreads();
  if (t < 64){
    float s = 0.f;
    for (int q = t; q < 200; q += 64) s += ml[q];
    for (int o = 1; o < 64; o <<= 1) s += __shfl_xor(s, o);
    if (t == 0) sS2[0] = s;
  }
  __syncthreads();
  if (t >= 200) return;
  const float sS = sS2[0];
  float acc = 0.f, W = 0.f;
  const int beg = offs[n], end = offs[n+1];
  for (int j = beg; j < end; ++j){
    int pk = csr[j];
    int v = pk & 0xFFFF, tt = pk >> 16;
    float d = __half2float(D2[(size_t)v*200 + t]);
    float r = R2f[tt*200 + t];
    float p = sS + sD2[v] + sR2[tt];
    float lk = p > 0.f ? p : 0.2f*p;
    float w = expf(-lk);
    acc += w*(d + r); W += w;
  }
  float hh = (S*W + acc) / (W + 1e-12f);
  x2m[(size_t)i*200 + t] = hh > 0.f ? hh : (expf(hh) - 1.f);
}

// ---------------- his_temp: LDS tile + 16B vector stores ----------------
__global__ __launch_bounds__(256)
void k_his(const void* __restrict__ binp, const void* __restrict__ wt, const void* __restrict__ bt,
           const int* __restrict__ ifl, char* __restrict__ dout)
{
  __shared__ float he[100];
  __shared__ uint4 tile[50];
  const int i = blockIdx.x, t = threadIdx.x;
  const int fdt = ifl[1];
  const double t2 = (double)ild(binp, (size_t)i*4 + 3, ifl[0]);
  if (t < 100){
    double a = t2 * (double)ldf(wt, t, fdt) + (double)ldf(bt, t, fdt);
    he[t] = (float)cos(a);
  }
  __syncthreads();
  if (fdt == 0){
    float* tf = (float*)tile;          // 100 floats = 25 uint4, period 100
    if (t < 100) tf[t] = he[t];
    __syncthreads();
    uint4* out4 = (uint4*)(dout + 40000000 + (size_t)i*204800);
    for (int idx = t; idx < 12800; idx += 256) out4[idx] = tile[idx % 25];
  } else {
    unsigned short* th = (unsigned short*)tile;   // 400 halves = 50 uint4, period 400
    for (int j = t; j < 400; j += 256){
      float v = he[j % 100];
      th[j] = (fdt == 2) ? __builtin_bit_cast(unsigned short, __float2half_rn(v)) : f2bf(v);
    }
    __syncthreads();
    uint4* out4 = (uint4*)(dout + 20000000 + (size_t)i*102400);
    for (int idx = t; idx < 6400; idx += 256) out4[idx] = tile[idx % 50];
  }
}

// ---------------- launch ----------------
extern "C" void kernel_launch(void* const* d_in, const int* in_sizes, int n_in,
                              void* d_out, int out_size, void* d_ws, size_t ws_size,
                              hipStream_t stream)
{
  (void)in_sizes; (void)n_in; (void)out_size; (void)ws_size;
  const void* ent  = d_in[0];
  const void* rtab = d_in[1];
  const void* w_t2 = d_in[2];
  const void* b_t2 = d_in[3];
  const void* Went = d_in[4];
  const void* ah   = d_in[5];
  const void* a2h  = d_in[6];
  const void* Wrel = d_in[7];
  const void* aout = d_in[8];
  const void* a2o  = d_in[9];
  const void* elist = d_in[10];
  const void* etype = d_in[11];
  const void* binp  = d_in[12];

  int* ifl = (int*)d_ws;                         // [0]=int64 flag, [1]=float dtype
  int* b32 = (int*)((char*)d_ws + 256);          // 2048 ints

  char* dout = (char*)d_out;
  // ENf at [0,20MB): f32 copy of ent (16-bit dtypes only); consumed by k_x1, then
  // overwritten by k_gemmEuf's out0 stores. In f32 mode ENf unused (ent read directly).
  float* ENf = (float*)dout;
  // Region A [20MB,40MB): D1 then D2 (fp16).
  __half* D12 = (__half*)(dout + 20000000);
  // Region B [40MB,~66.7MB): consumed by kernels up to k_gemmEuf; inside out1 for all dtypes.
  char* scr = dout + 40000000;
  size_t cur = 0;
  auto alloc = [&](size_t bytes) -> char* {
    char* p = scr + cur;
    cur = (cur + bytes + 255) & ~(size_t)255;
    return p;
  };
  __half* X1     = (__half*)alloc((size_t)N_NODES*200*2);   // 20 MB
  int*   csr     = (int*)alloc((size_t)E_EDGES*4);          // 3.2 MB
  int*   offs    = (int*)alloc((size_t)(N_NODES+1)*4);
  int*   cnt     = (int*)alloc((size_t)N_NODES*4);
  int*   midx    = (int*)alloc((size_t)N_NODES*4);
  int*   nflag   = (int*)alloc((size_t)N_NODES*4);
  int*   flist   = (int*)alloc((size_t)N_NODES*4);
  int*   fcnt    = (int*)alloc(256);
  float* invn    = (float*)alloc((size_t)N_NODES*4);
  float* M2f     = (float*)alloc((size_t)200*200*4);
  float* x2m     = (float*)alloc((size_t)B_BATCH*200*4);
  float* aTs     = (float*)alloc((size_t)100*200*4);
  float* aoTs    = (float*)alloc((size_t)200*200*4);
  float* R1f     = (float*)alloc((size_t)200*200*4);
  float* R2f     = (float*)alloc((size_t)200*200*4);
  float* sD      = (float*)alloc((size_t)N_NODES*2*4);
  float* sD2     = (float*)alloc((size_t)N_NODES*4);
  float* sR1     = (float*)alloc((size_t)200*2*4);
  float* sR2     = (float*)alloc((size_t)200*4);
  float* a2f     = (float*)alloc((size_t)200*4);
  float* a2of    = (float*)alloc((size_t)200*4);
  unsigned short* WswE  = (unsigned short*)alloc((size_t)26624*2);  // MFMA B-frag tables
  unsigned short* WswD  = (unsigned short*)alloc((size_t)26624*2);
  unsigned short* WswD2 = (unsigned short*)alloc((size_t)46592*2);
  // total ~26.7 MB -> ends ~66.7 MB < 72.4 MB (min d_out at esize=2)

  const int EB = (E_EDGES + 255) / 256;
  const int NB = (N_NODES + 255) / 256;

  k_probe<<<dim3(1), dim3(64), 0, stream>>>((const unsigned short*)ent, (const unsigned int*)ent,
                                            (const unsigned int*)elist, ifl);
  k_cvtb <<<dim3(8), dim3(256), 0, stream>>>(binp, ifl, b32);
  k_fillm<<<dim3(NB), dim3(256), 0, stream>>>(midx, -1, N_NODES);
  k_mset <<<dim3(2), dim3(256), 0, stream>>>(b32, midx);
  k_trans<<<dim3(237), dim3(256), 0, stream>>>(ah, aout, a2h, a2o, ifl, aTs, aoTs, a2f, a2of);
  k_wsw  <<<dim3(208), dim3(256), 0, stream>>>(Went, ah, ifl, WswE, WswD);
  k_wsw2 <<<dim3(182), dim3(256), 0, stream>>>(aout, ifl, WswD2);
  k_cvt_en<<<dim3(N_NODES/4), dim3(256), 0, stream>>>(ent, ifl, ENf, invn);
  k_m2f  <<<dim3(157), dim3(256), 0, stream>>>(rtab, Wrel, etype, ifl, M2f);
  k_R1   <<<dim3(200), dim3(256), 0, stream>>>(rtab, ah, ifl, a2f, R1f, sR1);
  k_R2   <<<dim3(200), dim3(256), 0, stream>>>(M2f, aout, ifl, a2of, R2f, sR2);

  k_fillm<<<dim3(NB), dim3(256), 0, stream>>>(cnt, 0, N_NODES);
  k_count<<<dim3(EB), dim3(256), 0, stream>>>(elist, ifl, cnt);
  k_scan <<<dim3(1), dim3(256), 0, stream>>>(cnt, offs);
  k_fillm<<<dim3(NB), dim3(256), 0, stream>>>(cnt, 0, N_NODES);
  k_scatter<<<dim3(EB), dim3(256), 0, stream>>>(elist, etype, ifl, offs, cnt, csr);

  k_fillm<<<dim3(NB), dim3(256), 0, stream>>>(nflag, 0, N_NODES);
  k_flag <<<dim3(B_BATCH), dim3(256), 0, stream>>>(b32, offs, csr, nflag);
  k_fillm<<<dim3(1), dim3(256), 0, stream>>>(fcnt, 0, 1);
  k_compact<<<dim3(NB), dim3(256), 0, stream>>>(nflag, fcnt, flist);

  k_gemmD1<<<dim3(782), dim3(256), 0, stream>>>(ent, ifl, WswD, a2f, D12, sD);
  k_x1 <<<dim3(N_NODES), dim3(256), 0, stream>>>(ent, ENf, ifl, flist, fcnt, aTs, a2f, R1f, sR1, D12, sD, offs, csr, X1);
  k_D2g<<<dim3(782), dim3(256), 0, stream>>>(X1, flist, fcnt, WswD2, a2of, D12, sD2);
  k_x2m<<<dim3(B_BATCH), dim3(256), 0, stream>>>(b32, X1, aoTs, a2of, R2f, sR2, D12, sD2, offs, csr, x2m);
  k_gemmEuf<<<dim3(782), dim3(256), 0, stream>>>(ent, ifl, WswE, invn, midx, x2m, dout);

  // LAST: overwrites all of out1 (incl. all scratch); reads only inputs + ifl
  k_his<<<dim3(B_BATCH), dim3(256), 0, stream>>>(binp, w_t2, b_t2, ifl, dout);
}

// Round 6
// 491.152 us; speedup vs baseline: 2.3044x; 1.2547x over previous
//
#include <hip/hip_runtime.h>
#include <hip/hip_fp16.h>
#include <stdint.h>

#define N_NODES 50000
#define FIN_D   100
#define E_EDGES 800000
#define NRELS   200
#define B_BATCH 512
#define HDIM    100

typedef _Float16 f16x8 __attribute__((ext_vector_type(8)));
typedef short    s16x8 __attribute__((ext_vector_type(8)));
typedef float    f32x4v __attribute__((ext_vector_type(4)));

__device__ __forceinline__ unsigned short f2bf(float f){
  unsigned int x = __builtin_bit_cast(unsigned int, f);
  unsigned int lsb = (x >> 16) & 1u;
  x += 0x7fffu + lsb;
  return (unsigned short)(x >> 16);
}
// float-tensor load: fdt 2=fp16, 1=bf16, 0=f32
__device__ __forceinline__ float ldf(const void* p, size_t i, int fdt){
  if (fdt == 2) return __half2float(((const __half*)p)[i]);
  if (fdt == 1){ unsigned int x = ((unsigned int)((const unsigned short*)p)[i]) << 16;
                 return __builtin_bit_cast(float, x); }
  return ((const float*)p)[i];
}
// output store, same dtype as inputs
__device__ __forceinline__ void stf(void* p, size_t i, float v, int fdt){
  if (fdt == 2) ((__half*)p)[i] = __float2half_rn(v);
  else if (fdt == 1) ((unsigned short*)p)[i] = f2bf(v);
  else ((float*)p)[i] = v;
}
// integer-tensor load: i64 flag
__device__ __forceinline__ int ild(const void* p, size_t i, int i64){
  return i64 ? (int)((const long long*)p)[i] : ((const int*)p)[i];
}

// ---------------- dtype probes ----------------
__global__ void k_probe(const unsigned short* __restrict__ eh, const unsigned int* __restrict__ ew,
                        const unsigned int* __restrict__ elw, int* __restrict__ ifl){
  int t = threadIdx.x;   // 64 lanes
  int cF = 0, cB = 0, c32 = 0;
  #pragma unroll
  for (int j = 0; j < 4; ++j){
    unsigned short u = eh[4*t + j];
    {
      int e5 = (u >> 10) & 31, m = u & 1023;
      float v = (e5 == 0) ? ldexpf((float)m, -24) : ldexpf(1.f + m/1024.f, e5 - 15);
      if (v >= 0.004f && v <= 0.30f) cF++;
    }
    {
      unsigned int x = ((unsigned int)(u & 0x7FFF)) << 16;
      float v = __builtin_bit_cast(float, x);
      if (v >= 0.004f && v <= 0.30f) cB++;
    }
  }
  #pragma unroll
  for (int j = 0; j < 2; ++j){
    unsigned int w = ew[2*t + j] & 0x7FFFFFFFu;
    float v = __builtin_bit_cast(float, w);
    if (v >= 0.004f && v <= 0.30f) c32++;
  }
  for (int o = 1; o < 64; o <<= 1){
    cF += __shfl_xor(cF, o); cB += __shfl_xor(cB, o); c32 += __shfl_xor(c32, o);
  }
  int z = (elw[2*t + 1] == 0u) ? 1 : 0;
  unsigned long long mb = __ballot(z);
  if (t == 0){
    int fdt;
    if (c32 >= 96) fdt = 0;
    else fdt = (cB > cF) ? 1 : 2;
    ifl[1] = fdt;
    ifl[0] = (__popcll(mb) >= 60) ? 1 : 0;
  }
}

// ---------------- init: all fills in one kernel ----------------
__global__ void k_init(int* __restrict__ midx, int* __restrict__ cnt,
                       int* __restrict__ nflag, int* __restrict__ fcnt){
  int i = blockIdx.x*256 + threadIdx.x;
  if (i < N_NODES){ midx[i] = -1; cnt[i] = 0; nflag[i] = 0; }
  if (i == 0) fcnt[0] = 0;
}
__global__ void k_mset(const void* __restrict__ binp, const int* __restrict__ ifl,
                       int* __restrict__ midx){
  int i = blockIdx.x*256 + threadIdx.x;
  if (i >= B_BATCH) return;
  midx[ild(binp, (size_t)i*4 + 2, ifl[0])] = i;
}

// ---------------- all weight-table builds in one kernel ----------------
// ranges: [0,20000) aTs ; [20000,60000) aoTs ; [..,+200) a2f ; [..,+200) a2of ;
//         [..,+53248) WswE/WswD ; [..,+46592) WswD2
__global__ void k_tables(const void* __restrict__ ah, const void* __restrict__ aout,
                         const void* __restrict__ a2h, const void* __restrict__ a2o,
                         const void* __restrict__ went, const int* __restrict__ ifl,
                         float* __restrict__ aTs, float* __restrict__ aoTs,
                         float* __restrict__ a2f, float* __restrict__ a2of,
                         unsigned short* __restrict__ WswE, unsigned short* __restrict__ WswD,
                         unsigned short* __restrict__ WswD2){
  int i = blockIdx.x*256 + threadIdx.x;
  int fdt = ifl[1];
  if (i < 20000){ int k=i/200, t=i%200; aTs[i] = ldf(ah,(size_t)t*300+k,fdt); return; }
  i -= 20000;
  if (i < 40000){ int k=i/200, t=i%200; aoTs[i] = ldf(aout,(size_t)t*600+k,fdt); return; }
  i -= 40000;
  if (i < 200){ a2f[i] = ldf(a2h, i, fdt); return; }
  i -= 200;
  if (i < 200){ a2of[i] = ldf(a2o, i, fdt); return; }
  i -= 200;
  if (i < 2*26624){
    // MFMA B-frag tables, [n(13)][ks(4)][lane(64)][j(8)]; W[k][col],
    // k=ks*32+(l>>4)*8+j, col=n*16+(l&15); zero pad k>=100 / col>=200.
    int tbl = i / 26624, r0 = i % 26624;
    int j = r0 & 7, l = (r0>>3) & 63, ks = (r0>>9) & 3, n = r0>>11;
    int k = ks*32 + (l>>4)*8 + j;
    int col = n*16 + (l&15);
    float v = 0.f;
    if (k < 100 && col < 200)
      v = tbl ? ldf(ah, (size_t)col*300 + 100 + k, fdt) : ldf(went, (size_t)k*200 + col, fdt);
    unsigned short h = (fdt == 2) ? __builtin_bit_cast(unsigned short, __float2half_rn(v)) : f2bf(v);
    (tbl ? WswD : WswE)[r0] = h;
    return;
  }
  i -= 2*26624;
  if (i < 46592){
    // D2 B-table (ALWAYS fp16), [n(13)][ks(7)][lane(64)][j(8)]; aout[col][200+k], K pad 224
    int j = i & 7, l = (i>>3) & 63, r = i >> 9;
    int ks = r % 7, n = r / 7;
    int k = ks*32 + (l>>4)*8 + j;
    int col = n*16 + (l&15);
    float v = (k < 200 && col < 200) ? ldf(aout, (size_t)col*600 + 200 + k, fdt) : 0.f;
    WswD2[i] = __builtin_bit_cast(unsigned short, __float2half_rn(v));
  }
}

// f32 copy of entity rows + per-node inverse norms. One wave per row, 4 rows/block.
__global__ __launch_bounds__(256)
void k_cvt_en(const void* __restrict__ ent, const int* __restrict__ ifl,
              float* __restrict__ ENf, float* __restrict__ invn){
  const int w = threadIdx.x >> 6, l = threadIdx.x & 63;
  const int n = blockIdx.x*4 + w;
  const int fdt = ifl[1];
  float x = 0.f, y = 0.f;
  if (l < 50){
    if (fdt == 0){
      float2 v = ((const float2*)ent)[(size_t)n*50 + l];
      x = v.x; y = v.y;
    } else if (fdt == 2){
      __half2 h = ((const __half2*)ent)[(size_t)n*50 + l];
      float2 v = __half22float2(h); x = v.x; y = v.y;
    } else {
      unsigned int u = ((const unsigned int*)ent)[(size_t)n*50 + l];
      x = __builtin_bit_cast(float, u << 16);
      y = __builtin_bit_cast(float, u & 0xFFFF0000u);
    }
    if (fdt != 0) ((float2*)ENf)[(size_t)n*50 + l] = make_float2(x, y);
  }
  float ss = x*x + y*y;
  #pragma unroll
  for (int o = 1; o < 64; o <<= 1) ss += __shfl_xor(ss, o);
  if (l == 0) invn[n] = 1.f / fmaxf(sqrtf(ss), 1e-12f);
}

// ---------------- relation tables: blocks 0..199 = R1 ; 200..399 = M2row + R2 ----------------
__global__ __launch_bounds__(256)
void k_rel(const void* __restrict__ rtab, const void* __restrict__ ah, const void* __restrict__ aout,
           const void* __restrict__ wrel, const void* __restrict__ etype, const int* __restrict__ ifl,
           const float* __restrict__ a2f, const float* __restrict__ a2of,
           float* __restrict__ R1f, float* __restrict__ sR1,
           float* __restrict__ R2f, float* __restrict__ sR2){
  __shared__ float rt[100], mr[200], ml[200];
  const int bi = blockIdx.x, t = threadIdx.x, fdt = ifl[1];
  if (bi < 200){
    const int tt = bi;
    if (t < 100) rt[t] = ldf(rtab,(size_t)tt*100+t,fdt);
    __syncthreads();
    if (t < 200){
      float R = 0.f;
      for (int k = 0; k < 100; ++k) R += rt[k]*ldf(ah,(size_t)t*300+200+k,fdt);
      R1f[tt*200+t] = R; ml[t] = R*a2f[t];
    }
    __syncthreads();
    if (t < 64){
      float s = 0.f;
      for (int q = t; q < 100; q += 64) s += ml[q];
      for (int o = 1; o < 64; o <<= 1) s += __shfl_xor(s, o);
      if (t == 0) sR1[tt*2] = s;
    } else if (t < 128){
      int l = t - 64;
      float s = 0.f;
      for (int q = 100 + l; q < 200; q += 64) s += ml[q];
      for (int o = 1; o < 64; o <<= 1) s += __shfl_xor(s, o);
      if (l == 0) sR1[tt*2+1] = s;
    }
  } else {
    const int tt = bi - 200;
    const int g = ild(etype, tt, ifl[0]);
    if (t < 100) rt[t] = ldf(rtab,(size_t)g*100+t,fdt);
    __syncthreads();
    if (t < 200){
      float m = 0.f;
      for (int k = 0; k < 100; ++k) m += rt[k]*ldf(wrel,(size_t)k*200+t,fdt);
      mr[t] = m;
    }
    __syncthreads();
    if (t < 200){
      float R = 0.f;
      for (int k = 0; k < 200; ++k) R += mr[k]*ldf(aout,(size_t)t*600+400+k,fdt);
      R2f[tt*200+t] = R; ml[t] = R*a2of[t];
    }
    __syncthreads();
    if (t < 64){
      float s = 0.f;
      for (int q = t; q < 200; q += 64) s += ml[q];
      for (int o = 1; o < 64; o <<= 1) s += __shfl_xor(s, o);
      if (t == 0) sR2[tt] = s;
    }
  }
}

// ---------------- CSR (packed: dst | type<<16) ----------------
__global__ void k_count(const void* __restrict__ el, const int* __restrict__ ifl, int* __restrict__ cnt){
  int e = blockIdx.x*256 + threadIdx.x;
  if (e >= E_EDGES) return;
  atomicAdd(&cnt[ild(el, e, ifl[0])], 1);
}
// hierarchical exclusive scan of cnt[50000] -> offs ; also re-zeroes cnt (scatter cursor)
__global__ __launch_bounds__(256)
void k_scanA(int* __restrict__ cnt, int* __restrict__ offs, int* __restrict__ bsum){
  __shared__ int bs[256];
  const int t = threadIdx.x, i = blockIdx.x*256 + t;
  int v = (i < N_NODES) ? cnt[i] : 0;
  bs[t] = v;
  __syncthreads();
  for (int o = 1; o < 256; o <<= 1){
    int u = (t >= o) ? bs[t-o] : 0;
    __syncthreads();
    bs[t] += u;
    __syncthreads();
  }
  if (i < N_NODES){ offs[i] = bs[t] - v; cnt[i] = 0; }
  if (t == 255) bsum[blockIdx.x] = bs[255];
}
__global__ __launch_bounds__(256)
void k_scanB(const int* __restrict__ bsum, int* __restrict__ bbase, int nblk){
  __shared__ int bs[256];
  const int t = threadIdx.x;
  int v = (t < nblk) ? bsum[t] : 0;
  bs[t] = v;
  __syncthreads();
  for (int o = 1; o < 256; o <<= 1){
    int u = (t >= o) ? bs[t-o] : 0;
    __syncthreads();
    bs[t] += u;
    __syncthreads();
  }
  if (t < nblk) bbase[t] = bs[t] - v;
}
__global__ __launch_bounds__(256)
void k_scanC(int* __restrict__ offs, const int* __restrict__ bbase){
  const int i = blockIdx.x*256 + threadIdx.x;
  if (i < N_NODES) offs[i] += bbase[i >> 8];
  if (i == N_NODES) offs[N_NODES] = E_EDGES;
}
__global__ void k_scatter(const void* __restrict__ el, const void* __restrict__ et,
                          const int* __restrict__ ifl, const int* __restrict__ offs,
                          int* __restrict__ fill, int* __restrict__ csr){
  int e = blockIdx.x*256 + threadIdx.x;
  if (e >= E_EDGES) return;
  int f = ifl[0];
  int a = ild(el, e, f);
  int pos = offs[a] + atomicAdd(&fill[a], 1);
  csr[pos] = ild(el, (size_t)E_EDGES + e, f) | (ild(et, e, f) << 16);
}

// flag = masked nodes + their neighbors
__global__ void k_flag(const void* __restrict__ binp, const int* __restrict__ ifl,
                       const int* __restrict__ offs, const int* __restrict__ csr,
                       int* __restrict__ nflag){
  const int i = blockIdx.x, t = threadIdx.x;
  const int n = ild(binp, (size_t)i*4 + 2, ifl[0]);
  if (t == 0) nflag[n] = 1;
  for (int j = offs[n] + t; j < offs[n+1]; j += 256) nflag[csr[j] & 0xFFFF] = 1;
}
__global__ void k_compact(const int* __restrict__ nflag, int* __restrict__ fcnt, int* __restrict__ flist){
  int i = blockIdx.x*256 + threadIdx.x;
  if (i < N_NODES && nflag[i]) flist[atomicAdd(fcnt, 1)] = i;
}

// ---- A-fragment gather for EN GEMMs (K=100 padded to 128; tail zeroed in regs) ----
__device__ __forceinline__ void loadA(const void* ent, int fdt, int arow, int koff, uint4* a){
  if (fdt != 0){
    const unsigned short* E = (const unsigned short*)ent;
    #pragma unroll
    for (int ks = 0; ks < 3; ++ks){
      const uint2* p = (const uint2*)(E + (size_t)arow*100 + ks*32 + koff);
      uint2 u0 = p[0], u1 = p[1];
      a[ks] = make_uint4(u0.x, u0.y, u1.x, u1.y);
    }
    if (koff == 0){
      const uint2* p = (const uint2*)(E + (size_t)arow*100 + 96);
      uint2 u0 = p[0];
      a[3] = make_uint4(u0.x, u0.y, 0, 0);        // k=96..99 valid, 100..103 zeroed
    } else a[3] = make_uint4(0,0,0,0);
  } else {
    const float* E = (const float*)ent;
    #pragma unroll
    for (int ks = 0; ks < 3; ++ks){
      const uint4* p = (const uint4*)(E + (size_t)arow*100 + ks*32 + koff);
      uint4 lo = p[0], hi = p[1];
      a[ks].x = (lo.x>>16) | (lo.y & 0xFFFF0000u);
      a[ks].y = (lo.z>>16) | (lo.w & 0xFFFF0000u);
      a[ks].z = (hi.x>>16) | (hi.y & 0xFFFF0000u);
      a[ks].w = (hi.z>>16) | (hi.w & 0xFFFF0000u);
    }
    if (koff == 0){
      const uint4* p = (const uint4*)(E + (size_t)arow*100 + 96);
      uint4 lo = p[0];
      a[3] = make_uint4((lo.x>>16)|(lo.y&0xFFFF0000u), (lo.z>>16)|(lo.w&0xFFFF0000u), 0, 0);
    } else a[3] = make_uint4(0,0,0,0);
  }
}

// ---- MFMA GEMM: D1 = EN @ a_dst.T  (+ sD head sums) ----
__global__ __launch_bounds__(256)
void k_gemmD1(const void* __restrict__ ent, const int* __restrict__ ifl,
              const unsigned short* __restrict__ WswD, const float* __restrict__ a2f,
              __half* __restrict__ D1, float* __restrict__ sD)
{
  const int wid = threadIdx.x >> 6, l = threadIdx.x & 63;
  const int mt = blockIdx.x*4 + wid;
  if (mt >= 3125) return;
  const int fdt = ifl[1];
  const int arow = mt*16 + (l & 15);
  const int koff = (l >> 4)*8;
  uint4 a[4];
  loadA(ent, fdt, arow, koff, a);
  const int c15 = l & 15;
  const int rbase = mt*16 + (l >> 4)*4;
  float sh0[4] = {0,0,0,0}, sh1[4] = {0,0,0,0};
  const uint4* W4 = (const uint4*)WswD;
  #pragma unroll
  for (int n = 0; n < 13; ++n){
    const int col = n*16 + c15;
    f32x4v acc = {0.f, 0.f, 0.f, 0.f};
    if (fdt == 2){
      #pragma unroll
      for (int ks = 0; ks < 4; ++ks){
        uint4 w = W4[(n*4 + ks)*64 + l];
        acc = __builtin_amdgcn_mfma_f32_16x16x32_f16(
            __builtin_bit_cast(f16x8, a[ks]), __builtin_bit_cast(f16x8, w), acc, 0, 0, 0);
      }
    } else {
      #pragma unroll
      for (int ks = 0; ks < 4; ++ks){
        uint4 w = W4[(n*4 + ks)*64 + l];
        acc = __builtin_amdgcn_mfma_f32_16x16x32_bf16(
            __builtin_bit_cast(s16x8, a[ks]), __builtin_bit_cast(s16x8, w), acc, 0, 0, 0);
      }
    }
    const float a2v = (col < 200) ? a2f[col] : 0.f;
    #pragma unroll
    for (int r = 0; r < 4; ++r){
      float v = acc[r];
      if (col < 200) D1[(size_t)(rbase + r)*200 + col] = __float2half_rn(v);
      float m = v*a2v;
      if (col < 100) sh0[r] += m; else sh1[r] += m;
    }
  }
  #pragma unroll
  for (int o = 1; o < 16; o <<= 1){
    #pragma unroll
    for (int r = 0; r < 4; ++r){
      sh0[r] += __shfl_xor(sh0[r], o);
      sh1[r] += __shfl_xor(sh1[r], o);
    }
  }
  if (c15 == 0){
    #pragma unroll
    for (int r = 0; r < 4; ++r){
      sD[(size_t)(rbase + r)*2]     = sh0[r];
      sD[(size_t)(rbase + r)*2 + 1] = sh1[r];
    }
  }
}

// ---- MFMA GEMM + epilogue: out0 = l2norm(EN@Went * invn + mask*x2m) ----
__global__ __launch_bounds__(256)
void k_gemmEuf(const void* __restrict__ ent, const int* __restrict__ ifl,
               const unsigned short* __restrict__ WswE, const float* __restrict__ invn,
               const int* __restrict__ midx, const float* __restrict__ x2m, char* __restrict__ dout)
{
  const int wid = threadIdx.x >> 6, l = threadIdx.x & 63;
  const int mt = blockIdx.x*4 + wid;
  if (mt >= 3125) return;
  const int fdt = ifl[1];
  const int arow = mt*16 + (l & 15);
  const int koff = (l >> 4)*8;
  uint4 a[4];
  loadA(ent, fdt, arow, koff, a);
  const int c15 = l & 15;
  const int rbase = mt*16 + (l >> 4)*4;
  f32x4v acc[13];
  const uint4* W4 = (const uint4*)WswE;
  #pragma unroll
  for (int n = 0; n < 13; ++n){
    f32x4v c = {0.f, 0.f, 0.f, 0.f};
    if (fdt == 2){
      #pragma unroll
      for (int ks = 0; ks < 4; ++ks){
        uint4 w = W4[(n*4 + ks)*64 + l];
        c = __builtin_amdgcn_mfma_f32_16x16x32_f16(
            __builtin_bit_cast(f16x8, a[ks]), __builtin_bit_cast(f16x8, w), c, 0, 0, 0);
      }
    } else {
      #pragma unroll
      for (int ks = 0; ks < 4; ++ks){
        uint4 w = W4[(n*4 + ks)*64 + l];
        c = __builtin_amdgcn_mfma_f32_16x16x32_bf16(
            __builtin_bit_cast(s16x8, a[ks]), __builtin_bit_cast(s16x8, w), c, 0, 0, 0);
      }
    }
    acc[n] = c;
  }
  float iv[4]; int mi[4];
  #pragma unroll
  for (int r = 0; r < 4; ++r){ iv[r] = invn[rbase + r]; mi[r] = midx[rbase + r]; }
  float ssv[4] = {0,0,0,0};
  #pragma unroll
  for (int n = 0; n < 13; ++n){
    const int col = n*16 + c15;
    if (col < 200){
      #pragma unroll
      for (int r = 0; r < 4; ++r){
        float v = acc[n][r]*iv[r];
        if (mi[r] >= 0) v += x2m[(size_t)mi[r]*200 + col];
        acc[n][r] = v;
        ssv[r] += v*v;
      }
    }
  }
  #pragma unroll
  for (int o = 1; o < 16; o <<= 1){
    #pragma unroll
    for (int r = 0; r < 4; ++r) ssv[r] += __shfl_xor(ssv[r], o);
  }
  float rn[4];
  #pragma unroll
  for (int r = 0; r < 4; ++r) rn[r] = 1.f / fmaxf(sqrtf(ssv[r]), 1e-12f);
  #pragma unroll
  for (int n = 0; n < 13; ++n){
    const int col = n*16 + c15;
    if (col < 200){
      #pragma unroll
      for (int r = 0; r < 4; ++r)
        stf(dout, (size_t)(rbase + r)*200 + col, acc[n][r]*rn[r], fdt);
    }
  }
}

// ---- MFMA GEMM over compacted flagged list: D2 = X1[flist] @ a_dst2.T (+ sD2) ----
__global__ __launch_bounds__(256)
void k_D2g(const __half* __restrict__ x1, const int* __restrict__ flist, const int* __restrict__ fcnt,
           const unsigned short* __restrict__ WswD2, const float* __restrict__ a2of,
           __half* __restrict__ D2, float* __restrict__ sD2)
{
  const int wid = threadIdx.x >> 6, l = threadIdx.x & 63;
  const int mt = blockIdx.x*4 + wid;
  const int cnt = fcnt[0];
  if (mt*16 >= cnt) return;
  const int c15 = l & 15;
  const int koff = (l >> 4)*8;
  int ar = mt*16 + c15; if (ar >= cnt) ar = cnt - 1;
  const __half* xr = x1 + (size_t)flist[ar]*200;
  uint4 a[7];
  #pragma unroll
  for (int ks = 0; ks < 6; ++ks)
    a[ks] = *(const uint4*)(xr + ks*32 + koff);
  a[6] = (koff == 0) ? *(const uint4*)(xr + 192) : make_uint4(0,0,0,0);
  const int rbase = mt*16 + (l >> 4)*4;
  int ndR[4]; bool okR[4];
  #pragma unroll
  for (int r = 0; r < 4; ++r){
    int rr = rbase + r;
    okR[r] = rr < cnt;
    ndR[r] = flist[okR[r] ? rr : cnt - 1];
  }
  float sh[4] = {0,0,0,0};
  const uint4* W4 = (const uint4*)WswD2;
  #pragma unroll
  for (int n = 0; n < 13; ++n){
    const int col = n*16 + c15;
    f32x4v acc = {0.f, 0.f, 0.f, 0.f};
    #pragma unroll
    for (int ks = 0; ks < 7; ++ks){
      uint4 w = W4[(n*7 + ks)*64 + l];
      acc = __builtin_amdgcn_mfma_f32_16x16x32_f16(
          __builtin_bit_cast(f16x8, a[ks]), __builtin_bit_cast(f16x8, w), acc, 0, 0, 0);
    }
    const float a2v = (col < 200) ? a2of[col] : 0.f;
    #pragma unroll
    for (int r = 0; r < 4; ++r){
      float v = acc[r];
      if (col < 200 && okR[r]) D2[(size_t)ndR[r]*200 + col] = __float2half_rn(v);
      sh[r] += v*a2v;
    }
  }
  #pragma unroll
  for (int o = 1; o < 16; o <<= 1){
    #pragma unroll
    for (int r = 0; r < 4; ++r) sh[r] += __shfl_xor(sh[r], o);
  }
  if (c15 == 0){
    #pragma unroll
    for (int r = 0; r < 4; ++r)
      if (okR[r]) sD2[ndR[r]] = sh[r];
  }
}

// layer 1 aggregation, over compacted flagged list (contiguous active blocks)
__global__ __launch_bounds__(256)
void k_x1(const void* __restrict__ ent, const float* __restrict__ ENf, const int* __restrict__ ifl,
          const int* __restrict__ flist, const int* __restrict__ fcnt,
          const float* __restrict__ aTs, const float* __restrict__ a2f,
          const float* __restrict__ R1f, const float* __restrict__ sR1,
          const __half* __restrict__ D1, const float* __restrict__ sD,
          const int* __restrict__ offs, const int* __restrict__ csr, __half* __restrict__ x1)
{
  __shared__ float ml[200], sS2[2];
  const int bi = blockIdx.x, t = threadIdx.x;
  if (bi >= fcnt[0]) return;
  const int n = flist[bi];
  const int fdt = ifl[1];
  const float* ENp = (fdt == 0) ? (const float*)ent : ENf;
  float S = 0.f;
  if (t < 200){
    const float* ep = ENp + (size_t)n*100;
    for (int k = 0; k < 100; ++k) S += ep[k]*aTs[k*200+t];
    ml[t] = S*a2f[t];
  }
  __syncthreads();
  if (t < 64){
    float s = 0.f;
    for (int q = t; q < 100; q += 64) s += ml[q];
    for (int o = 1; o < 64; o <<= 1) s += __shfl_xor(s, o);
    if (t == 0) sS2[0] = s;
  } else if (t < 128){
    int l = t - 64;
    float s = 0.f;
    for (int q = 100 + l; q < 200; q += 64) s += ml[q];
    for (int o = 1; o < 64; o <<= 1) s += __shfl_xor(s, o);
    if (l == 0) sS2[1] = s;
  }
  __syncthreads();
  if (t >= 200) return;
  const int h = (t >= 100) ? 1 : 0;
  const float sS = sS2[h];
  float acc = 0.f, W = 0.f;
  const int beg = offs[n], end = offs[n+1];
  for (int j = beg; j < end; ++j){
    int pk = csr[j];
    int v = pk & 0xFFFF, tt = pk >> 16;
    float d = __half2float(D1[(size_t)v*200 + t]);
    float r = R1f[tt*200 + t];
    float p = sS + sD[(size_t)v*2 + h] + sR1[tt*2 + h];
    float lk = p > 0.f ? p : 0.2f*p;
    float w = expf(-lk);
    acc += w*(d + r); W += w;
  }
  float hh = (S*W + acc) / (W + 1e-12f);
  x1[(size_t)n*200 + t] = __float2half_rn(hh > 0.f ? hh : (expf(hh) - 1.f));
}

// layer 2, masked nodes only
__global__ __launch_bounds__(256)
void k_x2m(const void* __restrict__ binp, const __half* __restrict__ x1, const float* __restrict__ aoTs,
           const float* __restrict__ a2of, const float* __restrict__ R2f, const float* __restrict__ sR2,
           const __half* __restrict__ D2, const float* __restrict__ sD2, const int* __restrict__ ifl,
           const int* __restrict__ offs, const int* __restrict__ csr, float* __restrict__ x2m)
{
  __shared__ float xn[200], ml[200], sS2[1];
  const int i = blockIdx.x, t = threadIdx.x;
  const int n = ild(binp, (size_t)i*4 + 2, ifl[0]);
  if (t < 200) xn[t] = __half2float(x1[(size_t)n*200 + t]);
  __syncthreads();
  float S = 0.f;
  if (t < 200){
    for (int k = 0; k < 200; ++k) S += xn[k]*aoTs[k*200+t];
    ml[t] = S*a2of[t];
  }
  __syncthreads();
  if (t < 64){
    float s = 0.f;
    for (int q = t; q < 200; q += 64) s += ml[q];
    for (int o = 1; o < 64; o <<= 1) s += __shfl_xor(s, o);
    if (t == 0) sS2[0] = s;
  }
  __syncthreads();
  if (t >= 200) return;
  const float sS = sS2[0];
  float acc = 0.f, W = 0.f;
  const int beg = offs[n], end = offs[n+1];
  for (int j = beg; j < end; ++j){
    int pk = csr[j];
    int v = pk & 0xFFFF, tt = pk >> 16;
    float d = __half2float(D2[(size_t)v*200 + t]);
    float r = R2f[tt*200 + t];
    float p = sS + sD2[v] + sR2[tt];
    float lk = p > 0.f ? p : 0.2f*p;
    float w = expf(-lk);
    acc += w*(d + r); W += w;
  }
  float hh = (S*W + acc) / (W + 1e-12f);
  x2m[(size_t)i*200 + t] = hh > 0.f ? hh : (expf(hh) - 1.f);
}

// ---------------- his_temp: LDS tile + 16B vector stores ----------------
__global__ __launch_bounds__(256)
void k_his(const void* __restrict__ binp, const void* __restrict__ wt, const void* __restrict__ bt,
           const int* __restrict__ ifl, char* __restrict__ dout)
{
  __shared__ float he[100];
  __shared__ uint4 tile[50];
  const int i = blockIdx.x, t = threadIdx.x;
  const int fdt = ifl[1];
  const double t2 = (double)ild(binp, (size_t)i*4 + 3, ifl[0]);
  if (t < 100){
    double a = t2 * (double)ldf(wt, t, fdt) + (double)ldf(bt, t, fdt);
    he[t] = (float)cos(a);
  }
  __syncthreads();
  if (fdt == 0){
    float* tf = (float*)tile;          // 100 floats = 25 uint4, period 100
    if (t < 100) tf[t] = he[t];
    __syncthreads();
    uint4* out4 = (uint4*)(dout + 40000000 + (size_t)i*204800);
    for (int idx = t; idx < 12800; idx += 256) out4[idx] = tile[idx % 25];
  } else {
    unsigned short* th = (unsigned short*)tile;   // 400 halves = 50 uint4, period 400
    for (int j = t; j < 400; j += 256){
      float v = he[j % 100];
      th[j] = (fdt == 2) ? __builtin_bit_cast(unsigned short, __float2half_rn(v)) : f2bf(v);
    }
    __syncthreads();
    uint4* out4 = (uint4*)(dout + 20000000 + (size_t)i*102400);
    for (int idx = t; idx < 6400; idx += 256) out4[idx] = tile[idx % 50];
  }
}

// ---------------- launch ----------------
extern "C" void kernel_launch(void* const* d_in, const int* in_sizes, int n_in,
                              void* d_out, int out_size, void* d_ws, size_t ws_size,
                              hipStream_t stream)
{
  (void)in_sizes; (void)n_in; (void)out_size; (void)ws_size;
  const void* ent  = d_in[0];
  const void* rtab = d_in[1];
  const void* w_t2 = d_in[2];
  const void* b_t2 = d_in[3];
  const void* Went = d_in[4];
  const void* ah   = d_in[5];
  const void* a2h  = d_in[6];
  const void* Wrel = d_in[7];
  const void* aout = d_in[8];
  const void* a2o  = d_in[9];
  const void* elist = d_in[10];
  const void* etype = d_in[11];
  const void* binp  = d_in[12];

  int* ifl = (int*)d_ws;                         // [0]=int64 flag, [1]=float dtype

  char* dout = (char*)d_out;
  // ENf at [0,20MB): f32 copy of ent (16-bit dtypes only); consumed by k_x1, then
  // overwritten by k_gemmEuf's out0 stores. In f32 mode ENf unused (ent read directly).
  float* ENf = (float*)dout;
  // Region A [20MB,40MB): D1 then D2 (fp16).
  __half* D12 = (__half*)(dout + 20000000);
  // Region B [40MB,~66MB): consumed by kernels up to k_gemmEuf; inside out1 for all dtypes.
  char* scr = dout + 40000000;
  size_t cur = 0;
  auto alloc = [&](size_t bytes) -> char* {
    char* p = scr + cur;
    cur = (cur + bytes + 255) & ~(size_t)255;
    return p;
  };
  __half* X1     = (__half*)alloc((size_t)N_NODES*200*2);   // 20 MB
  int*   csr     = (int*)alloc((size_t)E_EDGES*4);          // 3.2 MB
  int*   offs    = (int*)alloc((size_t)(N_NODES+1)*4);
  int*   cnt     = (int*)alloc((size_t)N_NODES*4);
  int*   midx    = (int*)alloc((size_t)N_NODES*4);
  int*   nflag   = (int*)alloc((size_t)N_NODES*4);
  int*   flist   = (int*)alloc((size_t)N_NODES*4);
  int*   fcnt    = (int*)alloc(256);
  int*   bsum    = (int*)alloc(1024);
  int*   bbase   = (int*)alloc(1024);
  float* invn    = (float*)alloc((size_t)N_NODES*4);
  float* x2m     = (float*)alloc((size_t)B_BATCH*200*4);
  float* aTs     = (float*)alloc((size_t)100*200*4);
  float* aoTs    = (float*)alloc((size_t)200*200*4);
  float* R1f     = (float*)alloc((size_t)200*200*4);
  float* R2f     = (float*)alloc((size_t)200*200*4);
  float* sD      = (float*)alloc((size_t)N_NODES*2*4);
  float* sD2     = (float*)alloc((size_t)N_NODES*4);
  float* sR1     = (float*)alloc((size_t)200*2*4);
  float* sR2     = (float*)alloc((size_t)200*4);
  float* a2f     = (float*)alloc((size_t)200*4);
  float* a2of    = (float*)alloc((size_t)200*4);
  unsigned short* WswE  = (unsigned short*)alloc((size_t)26624*2);  // MFMA B-frag tables
  unsigned short* WswD  = (unsigned short*)alloc((size_t)26624*2);
  unsigned short* WswD2 = (unsigned short*)alloc((size_t)46592*2);
  // total ~26.5 MB -> ends ~66.5 MB < 72.4 MB (min d_out at esize=2)

  const int EB = (E_EDGES + 255) / 256;
  const int NB = (N_NODES + 255) / 256;        // 196
  const int NB1 = (N_NODES + 256) / 256;       // covers i == N_NODES for scanC

  k_probe<<<dim3(1), dim3(64), 0, stream>>>((const unsigned short*)ent, (const unsigned int*)ent,
                                            (const unsigned int*)elist, ifl);
  k_init <<<dim3(NB), dim3(256), 0, stream>>>(midx, cnt, nflag, fcnt);
  k_mset <<<dim3(2), dim3(256), 0, stream>>>(binp, ifl, midx);
  k_tables<<<dim3(627), dim3(256), 0, stream>>>(ah, aout, a2h, a2o, Went, ifl,
                                                aTs, aoTs, a2f, a2of, WswE, WswD, WswD2);
  k_cvt_en<<<dim3(N_NODES/4), dim3(256), 0, stream>>>(ent, ifl, ENf, invn);
  k_rel  <<<dim3(400), dim3(256), 0, stream>>>(rtab, ah, aout, Wrel, etype, ifl,
                                               a2f, a2of, R1f, sR1, R2f, sR2);

  k_count<<<dim3(EB), dim3(256), 0, stream>>>(elist, ifl, cnt);
  k_scanA<<<dim3(NB), dim3(256), 0, stream>>>(cnt, offs, bsum);
  k_scanB<<<dim3(1), dim3(256), 0, stream>>>(bsum, bbase, NB);
  k_scanC<<<dim3(NB1), dim3(256), 0, stream>>>(offs, bbase);
  k_scatter<<<dim3(EB), dim3(256), 0, stream>>>(elist, etype, ifl, offs, cnt, csr);

  k_flag <<<dim3(B_BATCH), dim3(256), 0, stream>>>(binp, ifl, offs, csr, nflag);
  k_compact<<<dim3(NB), dim3(256), 0, stream>>>(nflag, fcnt, flist);

  k_gemmD1<<<dim3(782), dim3(256), 0, stream>>>(ent, ifl, WswD, a2f, D12, sD);
  k_x1 <<<dim3(N_NODES), dim3(256), 0, stream>>>(ent, ENf, ifl, flist, fcnt, aTs, a2f, R1f, sR1, D12, sD, offs, csr, X1);
  k_D2g<<<dim3(782), dim3(256), 0, stream>>>(X1, flist, fcnt, WswD2, a2of, D12, sD2);
  k_x2m<<<dim3(B_BATCH), dim3(256), 0, stream>>>(binp, X1, aoTs, a2of, R2f, sR2, D12, sD2, ifl, offs, csr, x2m);
  k_gemmEuf<<<dim3(782), dim3(256), 0, stream>>>(ent, ifl, WswE, invn, midx, x2m, dout);

  // LAST: overwrites all of out1 (incl. all scratch); reads only inputs + ifl
  k_his<<<dim3(B_BATCH), dim3(256), 0, stream>>>(binp, w_t2, b_t2, ifl, dout);
}

// Round 7
// 458.068 us; speedup vs baseline: 2.4709x; 1.0722x over previous
//
#include <hip/hip_runtime.h>
#include <hip/hip_fp16.h>
#include <stdint.h>

#define N_NODES 50000
#define FIN_D   100
#define E_EDGES 800000
#define NRELS   200
#define B_BATCH 512
#define HDIM    100

typedef _Float16 f16x8 __attribute__((ext_vector_type(8)));
typedef short    s16x8 __attribute__((ext_vector_type(8)));
typedef float    f32x4v __attribute__((ext_vector_type(4)));

__device__ __forceinline__ unsigned short f2bf(float f){
  unsigned int x = __builtin_bit_cast(unsigned int, f);
  unsigned int lsb = (x >> 16) & 1u;
  x += 0x7fffu + lsb;
  return (unsigned short)(x >> 16);
}
// float-tensor load: fdt 2=fp16, 1=bf16, 0=f32
__device__ __forceinline__ float ldf(const void* p, size_t i, int fdt){
  if (fdt == 2) return __half2float(((const __half*)p)[i]);
  if (fdt == 1){ unsigned int x = ((unsigned int)((const unsigned short*)p)[i]) << 16;
                 return __builtin_bit_cast(float, x); }
  return ((const float*)p)[i];
}
// output store, same dtype as inputs
__device__ __forceinline__ void stf(void* p, size_t i, float v, int fdt){
  if (fdt == 2) ((__half*)p)[i] = __float2half_rn(v);
  else if (fdt == 1) ((unsigned short*)p)[i] = f2bf(v);
  else ((float*)p)[i] = v;
}
// integer-tensor load: i64 flag
__device__ __forceinline__ int ild(const void* p, size_t i, int i64){
  return i64 ? (int)((const long long*)p)[i] : ((const int*)p)[i];
}

// ---------------- init (fills) + dtype probe (extra block) ----------------
__global__ void k_init(const unsigned short* __restrict__ eh, const unsigned int* __restrict__ ew,
                       const unsigned int* __restrict__ elw,
                       int* __restrict__ midx, int* __restrict__ cnt,
                       int* __restrict__ nflag, int* __restrict__ fcnt, int* __restrict__ ifl){
  const int NB = (N_NODES + 255) / 256;
  if ((int)blockIdx.x == NB){
    int t = threadIdx.x;
    if (t >= 64) return;
    int cF = 0, cB = 0, c32 = 0;
    #pragma unroll
    for (int j = 0; j < 4; ++j){
      unsigned short u = eh[4*t + j];
      {
        int e5 = (u >> 10) & 31, m = u & 1023;
        float v = (e5 == 0) ? ldexpf((float)m, -24) : ldexpf(1.f + m/1024.f, e5 - 15);
        if (v >= 0.004f && v <= 0.30f) cF++;
      }
      {
        unsigned int x = ((unsigned int)(u & 0x7FFF)) << 16;
        float v = __builtin_bit_cast(float, x);
        if (v >= 0.004f && v <= 0.30f) cB++;
      }
    }
    #pragma unroll
    for (int j = 0; j < 2; ++j){
      unsigned int w = ew[2*t + j] & 0x7FFFFFFFu;
      float v = __builtin_bit_cast(float, w);
      if (v >= 0.004f && v <= 0.30f) c32++;
    }
    for (int o = 1; o < 64; o <<= 1){
      cF += __shfl_xor(cF, o); cB += __shfl_xor(cB, o); c32 += __shfl_xor(c32, o);
    }
    int z = (elw[2*t + 1] == 0u) ? 1 : 0;
    unsigned long long mb = __ballot(z);
    if (t == 0){
      int fdt;
      if (c32 >= 96) fdt = 0;
      else fdt = (cB > cF) ? 1 : 2;
      ifl[1] = fdt;
      ifl[0] = (__popcll(mb) >= 60) ? 1 : 0;
    }
    return;
  }
  int i = blockIdx.x*256 + threadIdx.x;
  if (i < N_NODES){ midx[i] = -1; cnt[i] = 0; nflag[i] = 0; }
  if (i == 0) fcnt[0] = 0;
}

// mset + dedup-append masked nodes to flist
__global__ void k_mset(const void* __restrict__ binp, const int* __restrict__ ifl,
                       int* __restrict__ midx, int* __restrict__ nflag,
                       int* __restrict__ fcnt, int* __restrict__ flist){
  int i = blockIdx.x*256 + threadIdx.x;
  if (i >= B_BATCH) return;
  int n = ild(binp, (size_t)i*4 + 2, ifl[0]);
  midx[n] = i;
  if (atomicExch(&nflag[n], 1) == 0) flist[atomicAdd(fcnt, 1)] = n;
}

// ---------------- fused setup: cvt_en (blocks < 12500) + all weight tables ----------------
// table ranges: [0,20000) aTs ; [20000,60000) aoTs ; [+200) a2f ; [+200) a2of ;
// [+53248) WswE/WswD ; [+46592) WswD2 ; [+20000) aTr ; [+40000) aoTr
__global__ __launch_bounds__(256)
void k_setup(const void* __restrict__ ent, const void* __restrict__ ah, const void* __restrict__ aout,
             const void* __restrict__ a2h, const void* __restrict__ a2o, const void* __restrict__ went,
             const int* __restrict__ ifl,
             float* __restrict__ ENf, float* __restrict__ invn,
             float* __restrict__ aTs, float* __restrict__ aoTs,
             float* __restrict__ aTr, float* __restrict__ aoTr,
             float* __restrict__ a2f, float* __restrict__ a2of,
             unsigned short* __restrict__ WswE, unsigned short* __restrict__ WswD,
             unsigned short* __restrict__ WswD2){
  const int fdt = ifl[1];
  if (blockIdx.x < 12500){
    const int w = threadIdx.x >> 6, l = threadIdx.x & 63;
    const int n = blockIdx.x*4 + w;
    float x = 0.f, y = 0.f;
    if (l < 50){
      if (fdt == 0){
        float2 v = ((const float2*)ent)[(size_t)n*50 + l];
        x = v.x; y = v.y;
      } else if (fdt == 2){
        __half2 h = ((const __half2*)ent)[(size_t)n*50 + l];
        float2 v = __half22float2(h); x = v.x; y = v.y;
      } else {
        unsigned int u = ((const unsigned int*)ent)[(size_t)n*50 + l];
        x = __builtin_bit_cast(float, u << 16);
        y = __builtin_bit_cast(float, u & 0xFFFF0000u);
      }
      if (fdt != 0) ((float2*)ENf)[(size_t)n*50 + l] = make_float2(x, y);
    }
    float ss = x*x + y*y;
    #pragma unroll
    for (int o = 1; o < 64; o <<= 1) ss += __shfl_xor(ss, o);
    if (l == 0) invn[n] = 1.f / fmaxf(sqrtf(ss), 1e-12f);
    return;
  }
  int i = (blockIdx.x - 12500)*256 + threadIdx.x;
  if (i < 20000){ int k=i/200, t=i%200; aTs[i] = ldf(ah,(size_t)t*300+k,fdt); return; }
  i -= 20000;
  if (i < 40000){ int k=i/200, t=i%200; aoTs[i] = ldf(aout,(size_t)t*600+k,fdt); return; }
  i -= 40000;
  if (i < 200){ a2f[i] = ldf(a2h, i, fdt); return; }
  i -= 200;
  if (i < 200){ a2of[i] = ldf(a2o, i, fdt); return; }
  i -= 200;
  if (i < 2*26624){
    // MFMA B-frag tables, [n(13)][ks(4)][lane(64)][j(8)]; W[k][col],
    // k=ks*32+(l>>4)*8+j, col=n*16+(l&15); zero pad k>=100 / col>=200.
    int tbl = i / 26624, r0 = i % 26624;
    int j = r0 & 7, l = (r0>>3) & 63, ks = (r0>>9) & 3, n = r0>>11;
    int k = ks*32 + (l>>4)*8 + j;
    int col = n*16 + (l&15);
    float v = 0.f;
    if (k < 100 && col < 200)
      v = tbl ? ldf(ah, (size_t)col*300 + 100 + k, fdt) : ldf(went, (size_t)k*200 + col, fdt);
    unsigned short h = (fdt == 2) ? __builtin_bit_cast(unsigned short, __float2half_rn(v)) : f2bf(v);
    (tbl ? WswD : WswE)[r0] = h;
    return;
  }
  i -= 2*26624;
  if (i < 46592){
    // D2 B-table (ALWAYS fp16), [n(13)][ks(7)][lane(64)][j(8)]; aout[col][200+k], K pad 224
    int j = i & 7, l = (i>>3) & 63, r = i >> 9;
    int ks = r % 7, n = r / 7;
    int k = ks*32 + (l>>4)*8 + j;
    int col = n*16 + (l&15);
    float v = (k < 200 && col < 200) ? ldf(aout, (size_t)col*600 + 200 + k, fdt) : 0.f;
    WswD2[i] = __builtin_bit_cast(unsigned short, __float2half_rn(v));
    return;
  }
  i -= 46592;
  if (i < 20000){ int k=i/200, t=i%200; aTr[i] = ldf(ah,(size_t)t*300+200+k,fdt); return; }
  i -= 20000;
  if (i < 40000){ int k=i/200, t=i%200; aoTr[i] = ldf(aout,(size_t)t*600+400+k,fdt); return; }
}

// ---------------- relation tables (coalesced): blocks 0..199 R1 ; 200..399 M2row+R2 ----------------
__global__ __launch_bounds__(256)
void k_rel(const void* __restrict__ rtab, const void* __restrict__ wrel, const void* __restrict__ etype,
           const int* __restrict__ ifl, const float* __restrict__ aTr, const float* __restrict__ aoTr,
           const float* __restrict__ a2f, const float* __restrict__ a2of,
           float* __restrict__ R1f, float* __restrict__ sR1,
           float* __restrict__ R2f, float* __restrict__ sR2){
  __shared__ float rt[100], mr[200], ml[200];
  const int bi = blockIdx.x, t = threadIdx.x, fdt = ifl[1];
  if (bi < 200){
    const int tt = bi;
    if (t < 100) rt[t] = ldf(rtab,(size_t)tt*100+t,fdt);
    __syncthreads();
    if (t < 200){
      float R = 0.f;
      for (int k = 0; k < 100; ++k) R += rt[k]*aTr[k*200+t];
      R1f[tt*200+t] = R; ml[t] = R*a2f[t];
    }
    __syncthreads();
    if (t < 64){
      float s = 0.f;
      for (int q = t; q < 100; q += 64) s += ml[q];
      for (int o = 1; o < 64; o <<= 1) s += __shfl_xor(s, o);
      if (t == 0) sR1[tt*2] = s;
    } else if (t < 128){
      int l = t - 64;
      float s = 0.f;
      for (int q = 100 + l; q < 200; q += 64) s += ml[q];
      for (int o = 1; o < 64; o <<= 1) s += __shfl_xor(s, o);
      if (l == 0) sR1[tt*2+1] = s;
    }
  } else {
    const int tt = bi - 200;
    const int g = ild(etype, tt, ifl[0]);
    if (t < 100) rt[t] = ldf(rtab,(size_t)g*100+t,fdt);
    __syncthreads();
    if (t < 200){
      float m = 0.f;
      for (int k = 0; k < 100; ++k) m += rt[k]*ldf(wrel,(size_t)k*200+t,fdt);
      mr[t] = m;
    }
    __syncthreads();
    if (t < 200){
      float R = 0.f;
      for (int k = 0; k < 200; ++k) R += mr[k]*aoTr[k*200+t];
      R2f[tt*200+t] = R; ml[t] = R*a2of[t];
    }
    __syncthreads();
    if (t < 64){
      float s = 0.f;
      for (int q = t; q < 200; q += 64) s += ml[q];
      for (int o = 1; o < 64; o <<= 1) s += __shfl_xor(s, o);
      if (t == 0) sR2[tt] = s;
    }
  }
}

// ---------------- CSR (packed: dst | type<<16) ----------------
__global__ void k_count(const void* __restrict__ el, const int* __restrict__ ifl, int* __restrict__ cnt){
  int e = blockIdx.x*256 + threadIdx.x;
  if (e >= E_EDGES) return;
  atomicAdd(&cnt[ild(el, e, ifl[0])], 1);
}
// hierarchical exclusive scan; scanA also re-zeroes cnt (scatter cursor)
__global__ __launch_bounds__(256)
void k_scanA(int* __restrict__ cnt, int* __restrict__ offs, int* __restrict__ bsum){
  __shared__ int bs[256];
  const int t = threadIdx.x, i = blockIdx.x*256 + t;
  int v = (i < N_NODES) ? cnt[i] : 0;
  bs[t] = v;
  __syncthreads();
  for (int o = 1; o < 256; o <<= 1){
    int u = (t >= o) ? bs[t-o] : 0;
    __syncthreads();
    bs[t] += u;
    __syncthreads();
  }
  if (i < N_NODES){ offs[i] = bs[t] - v; cnt[i] = 0; }
  if (t == 255) bsum[blockIdx.x] = bs[255];
}
// each block computes its own base from the 196 block sums (nblk < 256)
__global__ __launch_bounds__(256)
void k_scanC(int* __restrict__ offs, const int* __restrict__ bsum){
  __shared__ int part[4];
  const int t = threadIdx.x, b = blockIdx.x;
  int u = (t < b) ? bsum[t] : 0;
  #pragma unroll
  for (int o = 1; o < 64; o <<= 1) u += __shfl_xor(u, o);
  if ((t & 63) == 0) part[t >> 6] = u;
  __syncthreads();
  const int base = part[0] + part[1] + part[2] + part[3];
  const int i = b*256 + t;
  if (i < N_NODES) offs[i] += base;
  if (i == N_NODES) offs[N_NODES] = E_EDGES;
}
__global__ void k_scatter(const void* __restrict__ el, const void* __restrict__ et,
                          const int* __restrict__ ifl, const int* __restrict__ offs,
                          int* __restrict__ fill, int* __restrict__ csr){
  int e = blockIdx.x*256 + threadIdx.x;
  if (e >= E_EDGES) return;
  int f = ifl[0];
  int a = ild(el, e, f);
  int pos = offs[a] + atomicAdd(&fill[a], 1);
  csr[pos] = ild(el, (size_t)E_EDGES + e, f) | (ild(et, e, f) << 16);
}

// neighbors of masked nodes: dedup-append to flist (masked already appended in k_mset)
__global__ void k_flag(const void* __restrict__ binp, const int* __restrict__ ifl,
                       const int* __restrict__ offs, const int* __restrict__ csr,
                       int* __restrict__ nflag, int* __restrict__ fcnt, int* __restrict__ flist){
  const int i = blockIdx.x, t = threadIdx.x;
  const int n = ild(binp, (size_t)i*4 + 2, ifl[0]);
  for (int j = offs[n] + t; j < offs[n+1]; j += 256){
    int v = csr[j] & 0xFFFF;
    if (atomicExch(&nflag[v], 1) == 0) flist[atomicAdd(fcnt, 1)] = v;
  }
}

// ---- A-fragment gather for EN GEMMs (K=100 padded to 128; tail zeroed in regs) ----
__device__ __forceinline__ void loadA(const void* ent, int fdt, int arow, int koff, uint4* a){
  if (fdt != 0){
    const unsigned short* E = (const unsigned short*)ent;
    #pragma unroll
    for (int ks = 0; ks < 3; ++ks){
      const uint2* p = (const uint2*)(E + (size_t)arow*100 + ks*32 + koff);
      uint2 u0 = p[0], u1 = p[1];
      a[ks] = make_uint4(u0.x, u0.y, u1.x, u1.y);
    }
    if (koff == 0){
      const uint2* p = (const uint2*)(E + (size_t)arow*100 + 96);
      uint2 u0 = p[0];
      a[3] = make_uint4(u0.x, u0.y, 0, 0);        // k=96..99 valid, 100..103 zeroed
    } else a[3] = make_uint4(0,0,0,0);
  } else {
    const float* E = (const float*)ent;
    #pragma unroll
    for (int ks = 0; ks < 3; ++ks){
      const uint4* p = (const uint4*)(E + (size_t)arow*100 + ks*32 + koff);
      uint4 lo = p[0], hi = p[1];
      a[ks].x = (lo.x>>16) | (lo.y & 0xFFFF0000u);
      a[ks].y = (lo.z>>16) | (lo.w & 0xFFFF0000u);
      a[ks].z = (hi.x>>16) | (hi.y & 0xFFFF0000u);
      a[ks].w = (hi.z>>16) | (hi.w & 0xFFFF0000u);
    }
    if (koff == 0){
      const uint4* p = (const uint4*)(E + (size_t)arow*100 + 96);
      uint4 lo = p[0];
      a[3] = make_uint4((lo.x>>16)|(lo.y&0xFFFF0000u), (lo.z>>16)|(lo.w&0xFFFF0000u), 0, 0);
    } else a[3] = make_uint4(0,0,0,0);
  }
}

// ---- MFMA GEMM: D1 = EN @ a_dst.T  (+ sD head sums) ----
__global__ __launch_bounds__(256)
void k_gemmD1(const void* __restrict__ ent, const int* __restrict__ ifl,
              const unsigned short* __restrict__ WswD, const float* __restrict__ a2f,
              __half* __restrict__ D1, float* __restrict__ sD)
{
  const int wid = threadIdx.x >> 6, l = threadIdx.x & 63;
  const int mt = blockIdx.x*4 + wid;
  if (mt >= 3125) return;
  const int fdt = ifl[1];
  const int arow = mt*16 + (l & 15);
  const int koff = (l >> 4)*8;
  uint4 a[4];
  loadA(ent, fdt, arow, koff, a);
  const int c15 = l & 15;
  const int rbase = mt*16 + (l >> 4)*4;
  float sh0[4] = {0,0,0,0}, sh1[4] = {0,0,0,0};
  const uint4* W4 = (const uint4*)WswD;
  #pragma unroll
  for (int n = 0; n < 13; ++n){
    const int col = n*16 + c15;
    f32x4v acc = {0.f, 0.f, 0.f, 0.f};
    if (fdt == 2){
      #pragma unroll
      for (int ks = 0; ks < 4; ++ks){
        uint4 w = W4[(n*4 + ks)*64 + l];
        acc = __builtin_amdgcn_mfma_f32_16x16x32_f16(
            __builtin_bit_cast(f16x8, a[ks]), __builtin_bit_cast(f16x8, w), acc, 0, 0, 0);
      }
    } else {
      #pragma unroll
      for (int ks = 0; ks < 4; ++ks){
        uint4 w = W4[(n*4 + ks)*64 + l];
        acc = __builtin_amdgcn_mfma_f32_16x16x32_bf16(
            __builtin_bit_cast(s16x8, a[ks]), __builtin_bit_cast(s16x8, w), acc, 0, 0, 0);
      }
    }
    const float a2v = (col < 200) ? a2f[col] : 0.f;
    #pragma unroll
    for (int r = 0; r < 4; ++r){
      float v = acc[r];
      if (col < 200) D1[(size_t)(rbase + r)*200 + col] = __float2half_rn(v);
      float m = v*a2v;
      if (col < 100) sh0[r] += m; else sh1[r] += m;
    }
  }
  #pragma unroll
  for (int o = 1; o < 16; o <<= 1){
    #pragma unroll
    for (int r = 0; r < 4; ++r){
      sh0[r] += __shfl_xor(sh0[r], o);
      sh1[r] += __shfl_xor(sh1[r], o);
    }
  }
  if (c15 == 0){
    #pragma unroll
    for (int r = 0; r < 4; ++r){
      sD[(size_t)(rbase + r)*2]     = sh0[r];
      sD[(size_t)(rbase + r)*2 + 1] = sh1[r];
    }
  }
}

// ---- MFMA GEMM + epilogue: out0 = l2norm(EN@Went * invn + mask*x2m) ----
__global__ __launch_bounds__(256)
void k_gemmEuf(const void* __restrict__ ent, const int* __restrict__ ifl,
               const unsigned short* __restrict__ WswE, const float* __restrict__ invn,
               const int* __restrict__ midx, const float* __restrict__ x2m, char* __restrict__ dout)
{
  const int wid = threadIdx.x >> 6, l = threadIdx.x & 63;
  const int mt = blockIdx.x*4 + wid;
  if (mt >= 3125) return;
  const int fdt = ifl[1];
  const int arow = mt*16 + (l & 15);
  const int koff = (l >> 4)*8;
  uint4 a[4];
  loadA(ent, fdt, arow, koff, a);
  const int c15 = l & 15;
  const int rbase = mt*16 + (l >> 4)*4;
  f32x4v acc[13];
  const uint4* W4 = (const uint4*)WswE;
  #pragma unroll
  for (int n = 0; n < 13; ++n){
    f32x4v c = {0.f, 0.f, 0.f, 0.f};
    if (fdt == 2){
      #pragma unroll
      for (int ks = 0; ks < 4; ++ks){
        uint4 w = W4[(n*4 + ks)*64 + l];
        c = __builtin_amdgcn_mfma_f32_16x16x32_f16(
            __builtin_bit_cast(f16x8, a[ks]), __builtin_bit_cast(f16x8, w), c, 0, 0, 0);
      }
    } else {
      #pragma unroll
      for (int ks = 0; ks < 4; ++ks){
        uint4 w = W4[(n*4 + ks)*64 + l];
        c = __builtin_amdgcn_mfma_f32_16x16x32_bf16(
            __builtin_bit_cast(s16x8, a[ks]), __builtin_bit_cast(s16x8, w), c, 0, 0, 0);
      }
    }
    acc[n] = c;
  }
  float iv[4]; int mi[4];
  #pragma unroll
  for (int r = 0; r < 4; ++r){ iv[r] = invn[rbase + r]; mi[r] = midx[rbase + r]; }
  float ssv[4] = {0,0,0,0};
  #pragma unroll
  for (int n = 0; n < 13; ++n){
    const int col = n*16 + c15;
    if (col < 200){
      #pragma unroll
      for (int r = 0; r < 4; ++r){
        float v = acc[n][r]*iv[r];
        if (mi[r] >= 0) v += x2m[(size_t)mi[r]*200 + col];
        acc[n][r] = v;
        ssv[r] += v*v;
      }
    }
  }
  #pragma unroll
  for (int o = 1; o < 16; o <<= 1){
    #pragma unroll
    for (int r = 0; r < 4; ++r) ssv[r] += __shfl_xor(ssv[r], o);
  }
  float rn[4];
  #pragma unroll
  for (int r = 0; r < 4; ++r) rn[r] = 1.f / fmaxf(sqrtf(ssv[r]), 1e-12f);
  #pragma unroll
  for (int n = 0; n < 13; ++n){
    const int col = n*16 + c15;
    if (col < 200){
      #pragma unroll
      for (int r = 0; r < 4; ++r)
        stf(dout, (size_t)(rbase + r)*200 + col, acc[n][r]*rn[r], fdt);
    }
  }
}

// ---- MFMA GEMM over compacted flagged list: D2 = X1[flist] @ a_dst2.T (+ sD2) ----
__global__ __launch_bounds__(256)
void k_D2g(const __half* __restrict__ x1, const int* __restrict__ flist, const int* __restrict__ fcnt,
           const unsigned short* __restrict__ WswD2, const float* __restrict__ a2of,
           __half* __restrict__ D2, float* __restrict__ sD2)
{
  const int wid = threadIdx.x >> 6, l = threadIdx.x & 63;
  const int mt = blockIdx.x*4 + wid;
  const int cnt = fcnt[0];
  if (mt*16 >= cnt) return;
  const int c15 = l & 15;
  const int koff = (l >> 4)*8;
  int ar = mt*16 + c15; if (ar >= cnt) ar = cnt - 1;
  const __half* xr = x1 + (size_t)flist[ar]*200;
  uint4 a[7];
  #pragma unroll
  for (int ks = 0; ks < 6; ++ks)
    a[ks] = *(const uint4*)(xr + ks*32 + koff);
  a[6] = (koff == 0) ? *(const uint4*)(xr + 192) : make_uint4(0,0,0,0);
  const int rbase = mt*16 + (l >> 4)*4;
  int ndR[4]; bool okR[4];
  #pragma unroll
  for (int r = 0; r < 4; ++r){
    int rr = rbase + r;
    okR[r] = rr < cnt;
    ndR[r] = flist[okR[r] ? rr : cnt - 1];
  }
  float sh[4] = {0,0,0,0};
  const uint4* W4 = (const uint4*)WswD2;
  #pragma unroll
  for (int n = 0; n < 13; ++n){
    const int col = n*16 + c15;
    f32x4v acc = {0.f, 0.f, 0.f, 0.f};
    #pragma unroll
    for (int ks = 0; ks < 7; ++ks){
      uint4 w = W4[(n*7 + ks)*64 + l];
      acc = __builtin_amdgcn_mfma_f32_16x16x32_f16(
          __builtin_bit_cast(f16x8, a[ks]), __builtin_bit_cast(f16x8, w), acc, 0, 0, 0);
    }
    const float a2v = (col < 200) ? a2of[col] : 0.f;
    #pragma unroll
    for (int r = 0; r < 4; ++r){
      float v = acc[r];
      if (col < 200 && okR[r]) D2[(size_t)ndR[r]*200 + col] = __float2half_rn(v);
      sh[r] += v*a2v;
    }
  }
  #pragma unroll
  for (int o = 1; o < 16; o <<= 1){
    #pragma unroll
    for (int r = 0; r < 4; ++r) sh[r] += __shfl_xor(sh[r], o);
  }
  if (c15 == 0){
    #pragma unroll
    for (int r = 0; r < 4; ++r)
      if (okR[r]) sD2[ndR[r]] = sh[r];
  }
}

// layer 1 aggregation, grid-stride over compacted flagged list
__global__ __launch_bounds__(256)
void k_x1(const void* __restrict__ ent, const float* __restrict__ ENf, const int* __restrict__ ifl,
          const int* __restrict__ flist, const int* __restrict__ fcnt,
          const float* __restrict__ aTs, const float* __restrict__ a2f,
          const float* __restrict__ R1f, const float* __restrict__ sR1,
          const __half* __restrict__ D1, const float* __restrict__ sD,
          const int* __restrict__ offs, const int* __restrict__ csr, __half* __restrict__ x1)
{
  __shared__ float ml[200], sS2[2];
  const int t = threadIdx.x;
  const int FC = fcnt[0];
  const int fdt = ifl[1];
  const float* ENp = (fdt == 0) ? (const float*)ent : ENf;
  for (int bi = blockIdx.x; bi < FC; bi += gridDim.x){
    const int n = flist[bi];
    float S = 0.f;
    if (t < 200){
      const float* ep = ENp + (size_t)n*100;
      for (int k = 0; k < 100; ++k) S += ep[k]*aTs[k*200+t];
      ml[t] = S*a2f[t];
    }
    __syncthreads();
    if (t < 64){
      float s = 0.f;
      for (int q = t; q < 100; q += 64) s += ml[q];
      for (int o = 1; o < 64; o <<= 1) s += __shfl_xor(s, o);
      if (t == 0) sS2[0] = s;
    } else if (t < 128){
      int l = t - 64;
      float s = 0.f;
      for (int q = 100 + l; q < 200; q += 64) s += ml[q];
      for (int o = 1; o < 64; o <<= 1) s += __shfl_xor(s, o);
      if (l == 0) sS2[1] = s;
    }
    __syncthreads();
    if (t < 200){
      const int h = (t >= 100) ? 1 : 0;
      const float sS = sS2[h];
      float acc = 0.f, W = 0.f;
      const int beg = offs[n], end = offs[n+1];
      for (int j = beg; j < end; ++j){
        int pk = csr[j];
        int v = pk & 0xFFFF, tt = pk >> 16;
        float d = __half2float(D1[(size_t)v*200 + t]);
        float r = R1f[tt*200 + t];
        float p = sS + sD[(size_t)v*2 + h] + sR1[tt*2 + h];
        float lk = p > 0.f ? p : 0.2f*p;
        float w = expf(-lk);
        acc += w*(d + r); W += w;
      }
      float hh = (S*W + acc) / (W + 1e-12f);
      x1[(size_t)n*200 + t] = __float2half_rn(hh > 0.f ? hh : (expf(hh) - 1.f));
    }
    __syncthreads();
  }
}

// layer 2, masked nodes only
__global__ __launch_bounds__(256)
void k_x2m(const void* __restrict__ binp, const __half* __restrict__ x1, const float* __restrict__ aoTs,
           const float* __restrict__ a2of, const float* __restrict__ R2f, const float* __restrict__ sR2,
           const __half* __restrict__ D2, const float* __restrict__ sD2, const int* __restrict__ ifl,
           const int* __restrict__ offs, const int* __restrict__ csr, float* __restrict__ x2m)
{
  __shared__ float xn[200], ml[200], sS2[1];
  const int i = blockIdx.x, t = threadIdx.x;
  const int n = ild(binp, (size_t)i*4 + 2, ifl[0]);
  if (t < 200) xn[t] = __half2float(x1[(size_t)n*200 + t]);
  __syncthreads();
  float S = 0.f;
  if (t < 200){
    for (int k = 0; k < 200; ++k) S += xn[k]*aoTs[k*200+t];
    ml[t] = S*a2of[t];
  }
  __syncthreads();
  if (t < 64){
    float s = 0.f;
    for (int q = t; q < 200; q += 64) s += ml[q];
    for (int o = 1; o < 64; o <<= 1) s += __shfl_xor(s, o);
    if (t == 0) sS2[0] = s;
  }
  __syncthreads();
  if (t >= 200) return;
  const float sS = sS2[0];
  float acc = 0.f, W = 0.f;
  const int beg = offs[n], end = offs[n+1];
  for (int j = beg; j < end; ++j){
    int pk = csr[j];
    int v = pk & 0xFFFF, tt = pk >> 16;
    float d = __half2float(D2[(size_t)v*200 + t]);
    float r = R2f[tt*200 + t];
    float p = sS + sD2[v] + sR2[tt];
    float lk = p > 0.f ? p : 0.2f*p;
    float w = expf(-lk);
    acc += w*(d + r); W += w;
  }
  float hh = (S*W + acc) / (W + 1e-12f);
  x2m[(size_t)i*200 + t] = hh > 0.f ? hh : (expf(hh) - 1.f);
}

// ---------------- his_temp: LDS tile + 16B vector stores ----------------
__global__ __launch_bounds__(256)
void k_his(const void* __restrict__ binp, const void* __restrict__ wt, const void* __restrict__ bt,
           const int* __restrict__ ifl, char* __restrict__ dout)
{
  __shared__ float he[100];
  __shared__ uint4 tile[50];
  const int i = blockIdx.x, t = threadIdx.x;
  const int fdt = ifl[1];
  const double t2 = (double)ild(binp, (size_t)i*4 + 3, ifl[0]);
  if (t < 100){
    double a = t2 * (double)ldf(wt, t, fdt) + (double)ldf(bt, t, fdt);
    he[t] = (float)cos(a);
  }
  __syncthreads();
  if (fdt == 0){
    float* tf = (float*)tile;          // 100 floats = 25 uint4, period 100
    if (t < 100) tf[t] = he[t];
    __syncthreads();
    uint4* out4 = (uint4*)(dout + 40000000 + (size_t)i*204800);
    for (int idx = t; idx < 12800; idx += 256) out4[idx] = tile[idx % 25];
  } else {
    unsigned short* th = (unsigned short*)tile;   // 400 halves = 50 uint4, period 400
    for (int j = t; j < 400; j += 256){
      float v = he[j % 100];
      th[j] = (fdt == 2) ? __builtin_bit_cast(unsigned short, __float2half_rn(v)) : f2bf(v);
    }
    __syncthreads();
    uint4* out4 = (uint4*)(dout + 20000000 + (size_t)i*102400);
    for (int idx = t; idx < 6400; idx += 256) out4[idx] = tile[idx % 50];
  }
}

// ---------------- launch ----------------
extern "C" void kernel_launch(void* const* d_in, const int* in_sizes, int n_in,
                              void* d_out, int out_size, void* d_ws, size_t ws_size,
                              hipStream_t stream)
{
  (void)in_sizes; (void)n_in; (void)out_size; (void)ws_size;
  const void* ent  = d_in[0];
  const void* rtab = d_in[1];
  const void* w_t2 = d_in[2];
  const void* b_t2 = d_in[3];
  const void* Went = d_in[4];
  const void* ah   = d_in[5];
  const void* a2h  = d_in[6];
  const void* Wrel = d_in[7];
  const void* aout = d_in[8];
  const void* a2o  = d_in[9];
  const void* elist = d_in[10];
  const void* etype = d_in[11];
  const void* binp  = d_in[12];

  int* ifl = (int*)d_ws;                         // [0]=int64 flag, [1]=float dtype

  char* dout = (char*)d_out;
  // ENf at [0,20MB): f32 copy of ent (16-bit dtypes only); consumed by k_x1, then
  // overwritten by k_gemmEuf's out0 stores. In f32 mode ENf unused (ent read directly).
  float* ENf = (float*)dout;
  // Region A [20MB,40MB): D1 then D2 (fp16).
  __half* D12 = (__half*)(dout + 20000000);
  // Region B [40MB,~66MB): consumed by kernels up to k_gemmEuf; inside out1 for all dtypes.
  char* scr = dout + 40000000;
  size_t cur = 0;
  auto alloc = [&](size_t bytes) -> char* {
    char* p = scr + cur;
    cur = (cur + bytes + 255) & ~(size_t)255;
    return p;
  };
  __half* X1     = (__half*)alloc((size_t)N_NODES*200*2);   // 20 MB
  int*   csr     = (int*)alloc((size_t)E_EDGES*4);          // 3.2 MB
  int*   offs    = (int*)alloc((size_t)(N_NODES+1)*4);
  int*   cnt     = (int*)alloc((size_t)N_NODES*4);
  int*   midx    = (int*)alloc((size_t)N_NODES*4);
  int*   nflag   = (int*)alloc((size_t)N_NODES*4);
  int*   flist   = (int*)alloc((size_t)N_NODES*4);
  int*   fcnt    = (int*)alloc(256);
  int*   bsum    = (int*)alloc(1024);
  float* invn    = (float*)alloc((size_t)N_NODES*4);
  float* x2m     = (float*)alloc((size_t)B_BATCH*200*4);
  float* aTs     = (float*)alloc((size_t)100*200*4);
  float* aoTs    = (float*)alloc((size_t)200*200*4);
  float* aTr     = (float*)alloc((size_t)100*200*4);
  float* aoTr    = (float*)alloc((size_t)200*200*4);
  float* R1f     = (float*)alloc((size_t)200*200*4);
  float* R2f     = (float*)alloc((size_t)200*200*4);
  float* sD      = (float*)alloc((size_t)N_NODES*2*4);
  float* sD2     = (float*)alloc((size_t)N_NODES*4);
  float* sR1     = (float*)alloc((size_t)200*2*4);
  float* sR2     = (float*)alloc((size_t)200*4);
  float* a2f     = (float*)alloc((size_t)200*4);
  float* a2of    = (float*)alloc((size_t)200*4);
  unsigned short* WswE  = (unsigned short*)alloc((size_t)26624*2);  // MFMA B-frag tables
  unsigned short* WswD  = (unsigned short*)alloc((size_t)26624*2);
  unsigned short* WswD2 = (unsigned short*)alloc((size_t)46592*2);
  // total ~26.8 MB -> ends ~66.8 MB < 72.4 MB (min d_out at esize=2)

  const int EB = (E_EDGES + 255) / 256;
  const int NB = (N_NODES + 255) / 256;        // 196

  k_init <<<dim3(NB + 1), dim3(256), 0, stream>>>((const unsigned short*)ent, (const unsigned int*)ent,
                                                  (const unsigned int*)elist, midx, cnt, nflag, fcnt, ifl);
  k_mset <<<dim3(2), dim3(256), 0, stream>>>(binp, ifl, midx, nflag, fcnt, flist);
  k_setup<<<dim3(12500 + 861), dim3(256), 0, stream>>>(ent, ah, aout, a2h, a2o, Went, ifl,
                                                       ENf, invn, aTs, aoTs, aTr, aoTr, a2f, a2of,
                                                       WswE, WswD, WswD2);
  k_rel  <<<dim3(400), dim3(256), 0, stream>>>(rtab, Wrel, etype, ifl, aTr, aoTr,
                                               a2f, a2of, R1f, sR1, R2f, sR2);

  k_count<<<dim3(EB), dim3(256), 0, stream>>>(elist, ifl, cnt);
  k_scanA<<<dim3(NB), dim3(256), 0, stream>>>(cnt, offs, bsum);
  k_scanC<<<dim3(NB), dim3(256), 0, stream>>>(offs, bsum);
  k_scatter<<<dim3(EB), dim3(256), 0, stream>>>(elist, etype, ifl, offs, cnt, csr);

  k_flag <<<dim3(B_BATCH), dim3(256), 0, stream>>>(binp, ifl, offs, csr, nflag, fcnt, flist);

  k_gemmD1<<<dim3(782), dim3(256), 0, stream>>>(ent, ifl, WswD, a2f, D12, sD);
  k_x1 <<<dim3(12288), dim3(256), 0, stream>>>(ent, ENf, ifl, flist, fcnt, aTs, a2f, R1f, sR1, D12, sD, offs, csr, X1);
  k_D2g<<<dim3(782), dim3(256), 0, stream>>>(X1, flist, fcnt, WswD2, a2of, D12, sD2);
  k_x2m<<<dim3(B_BATCH), dim3(256), 0, stream>>>(binp, X1, aoTs, a2of, R2f, sR2, D12, sD2, ifl, offs, csr, x2m);
  k_gemmEuf<<<dim3(782), dim3(256), 0, stream>>>(ent, ifl, WswE, invn, midx, x2m, dout);

  // LAST: overwrites all of out1 (incl. all scratch); reads only inputs + ifl
  k_his<<<dim3(B_BATCH), dim3(256), 0, stream>>>(binp, w_t2, b_t2, ifl, dout);
}

// Round 8
// 456.596 us; speedup vs baseline: 2.4788x; 1.0032x over previous
//
#include <hip/hip_runtime.h>
#include <hip/hip_fp16.h>
#include <stdint.h>

#define N_NODES 50000
#define FIN_D   100
#define E_EDGES 800000
#define NRELS   200
#define B_BATCH 512
#define HDIM    100

typedef _Float16 f16x8 __attribute__((ext_vector_type(8)));
typedef short    s16x8 __attribute__((ext_vector_type(8)));
typedef float    f32x4v __attribute__((ext_vector_type(4)));

__device__ __forceinline__ unsigned short f2bf(float f){
  unsigned int x = __builtin_bit_cast(unsigned int, f);
  unsigned int lsb = (x >> 16) & 1u;
  x += 0x7fffu + lsb;
  return (unsigned short)(x >> 16);
}
// float-tensor load: fdt 2=fp16, 1=bf16, 0=f32
__device__ __forceinline__ float ldf(const void* p, size_t i, int fdt){
  if (fdt == 2) return __half2float(((const __half*)p)[i]);
  if (fdt == 1){ unsigned int x = ((unsigned int)((const unsigned short*)p)[i]) << 16;
                 return __builtin_bit_cast(float, x); }
  return ((const float*)p)[i];
}
// output store, same dtype as inputs
__device__ __forceinline__ void stf(void* p, size_t i, float v, int fdt){
  if (fdt == 2) ((__half*)p)[i] = __float2half_rn(v);
  else if (fdt == 1) ((unsigned short*)p)[i] = f2bf(v);
  else ((float*)p)[i] = v;
}
// integer-tensor load: i64 flag
__device__ __forceinline__ int ild(const void* p, size_t i, int i64){
  return i64 ? (int)((const long long*)p)[i] : ((const int*)p)[i];
}

// ---------------- init (fills) + dtype probe (extra block) ----------------
__global__ void k_init(const unsigned short* __restrict__ eh, const unsigned int* __restrict__ ew,
                       const unsigned int* __restrict__ elw,
                       int* __restrict__ midx, int* __restrict__ cnt,
                       int* __restrict__ nflag, int* __restrict__ fcnt, int* __restrict__ ifl){
  const int NB = (N_NODES + 255) / 256;
  if ((int)blockIdx.x == NB){
    int t = threadIdx.x;
    if (t >= 64) return;
    int cF = 0, cB = 0, c32 = 0;
    #pragma unroll
    for (int j = 0; j < 4; ++j){
      unsigned short u = eh[4*t + j];
      {
        int e5 = (u >> 10) & 31, m = u & 1023;
        float v = (e5 == 0) ? ldexpf((float)m, -24) : ldexpf(1.f + m/1024.f, e5 - 15);
        if (v >= 0.004f && v <= 0.30f) cF++;
      }
      {
        unsigned int x = ((unsigned int)(u & 0x7FFF)) << 16;
        float v = __builtin_bit_cast(float, x);
        if (v >= 0.004f && v <= 0.30f) cB++;
      }
    }
    #pragma unroll
    for (int j = 0; j < 2; ++j){
      unsigned int w = ew[2*t + j] & 0x7FFFFFFFu;
      float v = __builtin_bit_cast(float, w);
      if (v >= 0.004f && v <= 0.30f) c32++;
    }
    for (int o = 1; o < 64; o <<= 1){
      cF += __shfl_xor(cF, o); cB += __shfl_xor(cB, o); c32 += __shfl_xor(c32, o);
    }
    int z = (elw[2*t + 1] == 0u) ? 1 : 0;
    unsigned long long mb = __ballot(z);
    if (t == 0){
      int fdt;
      if (c32 >= 96) fdt = 0;
      else fdt = (cB > cF) ? 1 : 2;
      ifl[1] = fdt;
      ifl[0] = (__popcll(mb) >= 60) ? 1 : 0;
    }
    return;
  }
  int i = blockIdx.x*256 + threadIdx.x;
  if (i < N_NODES){ midx[i] = -1; cnt[i] = 0; nflag[i] = 0; }
  if (i == 0) fcnt[0] = 0;
}

// mset + dedup-append masked nodes to flist
__global__ void k_mset(const void* __restrict__ binp, const int* __restrict__ ifl,
                       int* __restrict__ midx, int* __restrict__ nflag,
                       int* __restrict__ fcnt, int* __restrict__ flist){
  int i = blockIdx.x*256 + threadIdx.x;
  if (i >= B_BATCH) return;
  int n = ild(binp, (size_t)i*4 + 2, ifl[0]);
  midx[n] = i;
  if (atomicExch(&nflag[n], 1) == 0) flist[atomicAdd(fcnt, 1)] = n;
}

// ---------------- fused setup: invn (blocks < 12500) + all weight tables ----------------
__global__ __launch_bounds__(256)
void k_setup(const void* __restrict__ ent, const void* __restrict__ ah, const void* __restrict__ aout,
             const void* __restrict__ a2h, const void* __restrict__ a2o, const void* __restrict__ went,
             const int* __restrict__ ifl,
             float* __restrict__ invn,
             float* __restrict__ aTs, float* __restrict__ aoTs,
             float* __restrict__ aTr, float* __restrict__ aoTr,
             float* __restrict__ a2f, float* __restrict__ a2of,
             unsigned short* __restrict__ WswE, unsigned short* __restrict__ WswD,
             unsigned short* __restrict__ WswD2){
  const int fdt = ifl[1];
  if (blockIdx.x < 12500){
    const int w = threadIdx.x >> 6, l = threadIdx.x & 63;
    const int n = blockIdx.x*4 + w;
    float x = 0.f, y = 0.f;
    if (l < 50){
      if (fdt == 0){
        float2 v = ((const float2*)ent)[(size_t)n*50 + l];
        x = v.x; y = v.y;
      } else if (fdt == 2){
        __half2 h = ((const __half2*)ent)[(size_t)n*50 + l];
        float2 v = __half22float2(h); x = v.x; y = v.y;
      } else {
        unsigned int u = ((const unsigned int*)ent)[(size_t)n*50 + l];
        x = __builtin_bit_cast(float, u << 16);
        y = __builtin_bit_cast(float, u & 0xFFFF0000u);
      }
    }
    float ss = x*x + y*y;
    #pragma unroll
    for (int o = 1; o < 64; o <<= 1) ss += __shfl_xor(ss, o);
    if (l == 0) invn[n] = 1.f / fmaxf(sqrtf(ss), 1e-12f);
    return;
  }
  int i = (blockIdx.x - 12500)*256 + threadIdx.x;
  if (i < 20000){ int k=i/200, t=i%200; aTs[i] = ldf(ah,(size_t)t*300+k,fdt); return; }
  i -= 20000;
  if (i < 40000){ int k=i/200, t=i%200; aoTs[i] = ldf(aout,(size_t)t*600+k,fdt); return; }
  i -= 40000;
  if (i < 200){ a2f[i] = ldf(a2h, i, fdt); return; }
  i -= 200;
  if (i < 200){ a2of[i] = ldf(a2o, i, fdt); return; }
  i -= 200;
  if (i < 2*26624){
    // MFMA B-frag tables, [n(13)][ks(4)][lane(64)][j(8)]; W[k][col],
    // k=ks*32+(l>>4)*8+j, col=n*16+(l&15); zero pad k>=100 / col>=200.
    int tbl = i / 26624, r0 = i % 26624;
    int j = r0 & 7, l = (r0>>3) & 63, ks = (r0>>9) & 3, n = r0>>11;
    int k = ks*32 + (l>>4)*8 + j;
    int col = n*16 + (l&15);
    float v = 0.f;
    if (k < 100 && col < 200)
      v = tbl ? ldf(ah, (size_t)col*300 + 100 + k, fdt) : ldf(went, (size_t)k*200 + col, fdt);
    unsigned short h = (fdt == 2) ? __builtin_bit_cast(unsigned short, __float2half_rn(v)) : f2bf(v);
    (tbl ? WswD : WswE)[r0] = h;
    return;
  }
  i -= 2*26624;
  if (i < 46592){
    // D2 B-table (ALWAYS fp16), [n(13)][ks(7)][lane(64)][j(8)]; aout[col][200+k], K pad 224
    int j = i & 7, l = (i>>3) & 63, r = i >> 9;
    int ks = r % 7, n = r / 7;
    int k = ks*32 + (l>>4)*8 + j;
    int col = n*16 + (l&15);
    float v = (k < 200 && col < 200) ? ldf(aout, (size_t)col*600 + 200 + k, fdt) : 0.f;
    WswD2[i] = __builtin_bit_cast(unsigned short, __float2half_rn(v));
    return;
  }
  i -= 46592;
  if (i < 20000){ int k=i/200, t=i%200; aTr[i] = ldf(ah,(size_t)t*300+200+k,fdt); return; }
  i -= 20000;
  if (i < 40000){ int k=i/200, t=i%200; aoTr[i] = ldf(aout,(size_t)t*600+400+k,fdt); return; }
}

// ---------------- relation tables (coalesced, fp16 out): 0..199 R1 ; 200..399 M2row+R2 ----------------
__global__ __launch_bounds__(256)
void k_rel(const void* __restrict__ rtab, const void* __restrict__ wrel, const void* __restrict__ etype,
           const int* __restrict__ ifl, const float* __restrict__ aTr, const float* __restrict__ aoTr,
           const float* __restrict__ a2f, const float* __restrict__ a2of,
           __half* __restrict__ R1h, float* __restrict__ sR1,
           __half* __restrict__ R2h, float* __restrict__ sR2){
  __shared__ float rt[100], mr[200], ml[200];
  const int bi = blockIdx.x, t = threadIdx.x, fdt = ifl[1];
  if (bi < 200){
    const int tt = bi;
    if (t < 100) rt[t] = ldf(rtab,(size_t)tt*100+t,fdt);
    __syncthreads();
    if (t < 200){
      float R = 0.f;
      for (int k = 0; k < 100; ++k) R += rt[k]*aTr[k*200+t];
      R1h[tt*200+t] = __float2half_rn(R); ml[t] = R*a2f[t];
    }
    __syncthreads();
    if (t < 64){
      float s = 0.f;
      for (int q = t; q < 100; q += 64) s += ml[q];
      for (int o = 1; o < 64; o <<= 1) s += __shfl_xor(s, o);
      if (t == 0) sR1[tt*2] = s;
    } else if (t < 128){
      int l = t - 64;
      float s = 0.f;
      for (int q = 100 + l; q < 200; q += 64) s += ml[q];
      for (int o = 1; o < 64; o <<= 1) s += __shfl_xor(s, o);
      if (l == 0) sR1[tt*2+1] = s;
    }
  } else {
    const int tt = bi - 200;
    const int g = ild(etype, tt, ifl[0]);
    if (t < 100) rt[t] = ldf(rtab,(size_t)g*100+t,fdt);
    __syncthreads();
    if (t < 200){
      float m = 0.f;
      for (int k = 0; k < 100; ++k) m += rt[k]*ldf(wrel,(size_t)k*200+t,fdt);
      mr[t] = m;
    }
    __syncthreads();
    if (t < 200){
      float R = 0.f;
      for (int k = 0; k < 200; ++k) R += mr[k]*aoTr[k*200+t];
      R2h[tt*200+t] = __float2half_rn(R); ml[t] = R*a2of[t];
    }
    __syncthreads();
    if (t < 64){
      float s = 0.f;
      for (int q = t; q < 200; q += 64) s += ml[q];
      for (int o = 1; o < 64; o <<= 1) s += __shfl_xor(s, o);
      if (t == 0) sR2[tt] = s;
    }
  }
}

// ---------------- CSR (packed: dst | type<<16) ----------------
__global__ void k_count(const void* __restrict__ el, const int* __restrict__ ifl, int* __restrict__ cnt){
  int e = blockIdx.x*256 + threadIdx.x;
  if (e >= E_EDGES) return;
  atomicAdd(&cnt[ild(el, e, ifl[0])], 1);
}
// hierarchical exclusive scan; scanA also re-zeroes cnt (scatter cursor)
__global__ __launch_bounds__(256)
void k_scanA(int* __restrict__ cnt, int* __restrict__ offs, int* __restrict__ bsum){
  __shared__ int bs[256];
  const int t = threadIdx.x, i = blockIdx.x*256 + t;
  int v = (i < N_NODES) ? cnt[i] : 0;
  bs[t] = v;
  __syncthreads();
  for (int o = 1; o < 256; o <<= 1){
    int u = (t >= o) ? bs[t-o] : 0;
    __syncthreads();
    bs[t] += u;
    __syncthreads();
  }
  if (i < N_NODES){ offs[i] = bs[t] - v; cnt[i] = 0; }
  if (t == 255) bsum[blockIdx.x] = bs[255];
}
// each block computes its own base from the 196 block sums (nblk < 256)
__global__ __launch_bounds__(256)
void k_scanC(int* __restrict__ offs, const int* __restrict__ bsum){
  __shared__ int part[4];
  const int t = threadIdx.x, b = blockIdx.x;
  int u = (t < b) ? bsum[t] : 0;
  #pragma unroll
  for (int o = 1; o < 64; o <<= 1) u += __shfl_xor(u, o);
  if ((t & 63) == 0) part[t >> 6] = u;
  __syncthreads();
  const int base = part[0] + part[1] + part[2] + part[3];
  const int i = b*256 + t;
  if (i < N_NODES) offs[i] += base;
  if (i == N_NODES) offs[N_NODES] = E_EDGES;
}
__global__ void k_scatter(const void* __restrict__ el, const void* __restrict__ et,
                          const int* __restrict__ ifl, const int* __restrict__ offs,
                          int* __restrict__ fill, int* __restrict__ csr){
  int e = blockIdx.x*256 + threadIdx.x;
  if (e >= E_EDGES) return;
  int f = ifl[0];
  int a = ild(el, e, f);
  int pos = offs[a] + atomicAdd(&fill[a], 1);
  csr[pos] = ild(el, (size_t)E_EDGES + e, f) | (ild(et, e, f) << 16);
}

// neighbors of masked nodes: dedup-append to flist (masked already appended in k_mset)
__global__ void k_flag(const void* __restrict__ binp, const int* __restrict__ ifl,
                       const int* __restrict__ offs, const int* __restrict__ csr,
                       int* __restrict__ nflag, int* __restrict__ fcnt, int* __restrict__ flist){
  const int i = blockIdx.x, t = threadIdx.x;
  const int n = ild(binp, (size_t)i*4 + 2, ifl[0]);
  for (int j = offs[n] + t; j < offs[n+1]; j += 256){
    int v = csr[j] & 0xFFFF;
    if (atomicExch(&nflag[v], 1) == 0) flist[atomicAdd(fcnt, 1)] = v;
  }
}

// ---- A-fragment gather for EN GEMMs (K=100 padded to 128; tail zeroed in regs) ----
__device__ __forceinline__ void loadA(const void* ent, int fdt, int arow, int koff, uint4* a){
  if (fdt != 0){
    const unsigned short* E = (const unsigned short*)ent;
    #pragma unroll
    for (int ks = 0; ks < 3; ++ks){
      const uint2* p = (const uint2*)(E + (size_t)arow*100 + ks*32 + koff);
      uint2 u0 = p[0], u1 = p[1];
      a[ks] = make_uint4(u0.x, u0.y, u1.x, u1.y);
    }
    if (koff == 0){
      const uint2* p = (const uint2*)(E + (size_t)arow*100 + 96);
      uint2 u0 = p[0];
      a[3] = make_uint4(u0.x, u0.y, 0, 0);        // k=96..99 valid, 100..103 zeroed
    } else a[3] = make_uint4(0,0,0,0);
  } else {
    const float* E = (const float*)ent;
    #pragma unroll
    for (int ks = 0; ks < 3; ++ks){
      const uint4* p = (const uint4*)(E + (size_t)arow*100 + ks*32 + koff);
      uint4 lo = p[0], hi = p[1];
      a[ks].x = (lo.x>>16) | (lo.y & 0xFFFF0000u);
      a[ks].y = (lo.z>>16) | (lo.w & 0xFFFF0000u);
      a[ks].z = (hi.x>>16) | (hi.y & 0xFFFF0000u);
      a[ks].w = (hi.z>>16) | (hi.w & 0xFFFF0000u);
    }
    if (koff == 0){
      const uint4* p = (const uint4*)(E + (size_t)arow*100 + 96);
      uint4 lo = p[0];
      a[3] = make_uint4((lo.x>>16)|(lo.y&0xFFFF0000u), (lo.z>>16)|(lo.w&0xFFFF0000u), 0, 0);
    } else a[3] = make_uint4(0,0,0,0);
  }
}

// ---- MFMA GEMM: D1 = EN @ a_dst.T  (+ sD head sums) ----
__global__ __launch_bounds__(256)
void k_gemmD1(const void* __restrict__ ent, const int* __restrict__ ifl,
              const unsigned short* __restrict__ WswD, const float* __restrict__ a2f,
              __half* __restrict__ D1, float* __restrict__ sD)
{
  const int wid = threadIdx.x >> 6, l = threadIdx.x & 63;
  const int mt = blockIdx.x*4 + wid;
  if (mt >= 3125) return;
  const int fdt = ifl[1];
  const int arow = mt*16 + (l & 15);
  const int koff = (l >> 4)*8;
  uint4 a[4];
  loadA(ent, fdt, arow, koff, a);
  const int c15 = l & 15;
  const int rbase = mt*16 + (l >> 4)*4;
  float sh0[4] = {0,0,0,0}, sh1[4] = {0,0,0,0};
  const uint4* W4 = (const uint4*)WswD;
  #pragma unroll
  for (int n = 0; n < 13; ++n){
    const int col = n*16 + c15;
    f32x4v acc = {0.f, 0.f, 0.f, 0.f};
    if (fdt == 2){
      #pragma unroll
      for (int ks = 0; ks < 4; ++ks){
        uint4 w = W4[(n*4 + ks)*64 + l];
        acc = __builtin_amdgcn_mfma_f32_16x16x32_f16(
            __builtin_bit_cast(f16x8, a[ks]), __builtin_bit_cast(f16x8, w), acc, 0, 0, 0);
      }
    } else {
      #pragma unroll
      for (int ks = 0; ks < 4; ++ks){
        uint4 w = W4[(n*4 + ks)*64 + l];
        acc = __builtin_amdgcn_mfma_f32_16x16x32_bf16(
            __builtin_bit_cast(s16x8, a[ks]), __builtin_bit_cast(s16x8, w), acc, 0, 0, 0);
      }
    }
    const float a2v = (col < 200) ? a2f[col] : 0.f;
    #pragma unroll
    for (int r = 0; r < 4; ++r){
      float v = acc[r];
      if (col < 200) D1[(size_t)(rbase + r)*200 + col] = __float2half_rn(v);
      float m = v*a2v;
      if (col < 100) sh0[r] += m; else sh1[r] += m;
    }
  }
  #pragma unroll
  for (int o = 1; o < 16; o <<= 1){
    #pragma unroll
    for (int r = 0; r < 4; ++r){
      sh0[r] += __shfl_xor(sh0[r], o);
      sh1[r] += __shfl_xor(sh1[r], o);
    }
  }
  if (c15 == 0){
    #pragma unroll
    for (int r = 0; r < 4; ++r){
      sD[(size_t)(rbase + r)*2]     = sh0[r];
      sD[(size_t)(rbase + r)*2 + 1] = sh1[r];
    }
  }
}

// ---- MFMA GEMM + epilogue: out0 = l2norm(EN@Went * invn + mask*x2m) ----
__global__ __launch_bounds__(256)
void k_gemmEuf(const void* __restrict__ ent, const int* __restrict__ ifl,
               const unsigned short* __restrict__ WswE, const float* __restrict__ invn,
               const int* __restrict__ midx, const float* __restrict__ x2m, char* __restrict__ dout)
{
  const int wid = threadIdx.x >> 6, l = threadIdx.x & 63;
  const int mt = blockIdx.x*4 + wid;
  if (mt >= 3125) return;
  const int fdt = ifl[1];
  const int arow = mt*16 + (l & 15);
  const int koff = (l >> 4)*8;
  uint4 a[4];
  loadA(ent, fdt, arow, koff, a);
  const int c15 = l & 15;
  const int rbase = mt*16 + (l >> 4)*4;
  f32x4v acc[13];
  const uint4* W4 = (const uint4*)WswE;
  #pragma unroll
  for (int n = 0; n < 13; ++n){
    f32x4v c = {0.f, 0.f, 0.f, 0.f};
    if (fdt == 2){
      #pragma unroll
      for (int ks = 0; ks < 4; ++ks){
        uint4 w = W4[(n*4 + ks)*64 + l];
        c = __builtin_amdgcn_mfma_f32_16x16x32_f16(
            __builtin_bit_cast(f16x8, a[ks]), __builtin_bit_cast(f16x8, w), c, 0, 0, 0);
      }
    } else {
      #pragma unroll
      for (int ks = 0; ks < 4; ++ks){
        uint4 w = W4[(n*4 + ks)*64 + l];
        c = __builtin_amdgcn_mfma_f32_16x16x32_bf16(
            __builtin_bit_cast(s16x8, a[ks]), __builtin_bit_cast(s16x8, w), c, 0, 0, 0);
      }
    }
    acc[n] = c;
  }
  float iv[4]; int mi[4];
  #pragma unroll
  for (int r = 0; r < 4; ++r){ iv[r] = invn[rbase + r]; mi[r] = midx[rbase + r]; }
  float ssv[4] = {0,0,0,0};
  #pragma unroll
  for (int n = 0; n < 13; ++n){
    const int col = n*16 + c15;
    if (col < 200){
      #pragma unroll
      for (int r = 0; r < 4; ++r){
        float v = acc[n][r]*iv[r];
        if (mi[r] >= 0) v += x2m[(size_t)mi[r]*200 + col];
        acc[n][r] = v;
        ssv[r] += v*v;
      }
    }
  }
  #pragma unroll
  for (int o = 1; o < 16; o <<= 1){
    #pragma unroll
    for (int r = 0; r < 4; ++r) ssv[r] += __shfl_xor(ssv[r], o);
  }
  float rn[4];
  #pragma unroll
  for (int r = 0; r < 4; ++r) rn[r] = 1.f / fmaxf(sqrtf(ssv[r]), 1e-12f);
  #pragma unroll
  for (int n = 0; n < 13; ++n){
    const int col = n*16 + c15;
    if (col < 200){
      #pragma unroll
      for (int r = 0; r < 4; ++r)
        stf(dout, (size_t)(rbase + r)*200 + col, acc[n][r]*rn[r], fdt);
    }
  }
}

// ---- MFMA GEMM over compacted flagged list: D2 = X1[flist] @ a_dst2.T (+ sD2) ----
__global__ __launch_bounds__(256)
void k_D2g(const __half* __restrict__ x1, const int* __restrict__ flist, const int* __restrict__ fcnt,
           const unsigned short* __restrict__ WswD2, const float* __restrict__ a2of,
           __half* __restrict__ D2, float* __restrict__ sD2)
{
  const int wid = threadIdx.x >> 6, l = threadIdx.x & 63;
  const int mt = blockIdx.x*4 + wid;
  const int cnt = fcnt[0];
  if (mt*16 >= cnt) return;
  const int c15 = l & 15;
  const int koff = (l >> 4)*8;
  int ar = mt*16 + c15; if (ar >= cnt) ar = cnt - 1;
  const __half* xr = x1 + (size_t)flist[ar]*200;
  uint4 a[7];
  #pragma unroll
  for (int ks = 0; ks < 6; ++ks)
    a[ks] = *(const uint4*)(xr + ks*32 + koff);
  a[6] = (koff == 0) ? *(const uint4*)(xr + 192) : make_uint4(0,0,0,0);
  const int rbase = mt*16 + (l >> 4)*4;
  int ndR[4]; bool okR[4];
  #pragma unroll
  for (int r = 0; r < 4; ++r){
    int rr = rbase + r;
    okR[r] = rr < cnt;
    ndR[r] = flist[okR[r] ? rr : cnt - 1];
  }
  float sh[4] = {0,0,0,0};
  const uint4* W4 = (const uint4*)WswD2;
  #pragma unroll
  for (int n = 0; n < 13; ++n){
    const int col = n*16 + c15;
    f32x4v acc = {0.f, 0.f, 0.f, 0.f};
    #pragma unroll
    for (int ks = 0; ks < 7; ++ks){
      uint4 w = W4[(n*7 + ks)*64 + l];
      acc = __builtin_amdgcn_mfma_f32_16x16x32_f16(
          __builtin_bit_cast(f16x8, a[ks]), __builtin_bit_cast(f16x8, w), acc, 0, 0, 0);
    }
    const float a2v = (col < 200) ? a2of[col] : 0.f;
    #pragma unroll
    for (int r = 0; r < 4; ++r){
      float v = acc[r];
      if (col < 200 && okR[r]) D2[(size_t)ndR[r]*200 + col] = __float2half_rn(v);
      sh[r] += v*a2v;
    }
  }
  #pragma unroll
  for (int o = 1; o < 16; o <<= 1){
    #pragma unroll
    for (int r = 0; r < 4; ++r) sh[r] += __shfl_xor(sh[r], o);
  }
  if (c15 == 0){
    #pragma unroll
    for (int r = 0; r < 4; ++r)
      if (okR[r]) sD2[ndR[r]] = sh[r];
  }
}

// layer 1 aggregation, grid-stride over compacted flagged list
__global__ __launch_bounds__(256)
void k_x1(const void* __restrict__ ent, const int* __restrict__ ifl,
          const int* __restrict__ flist, const int* __restrict__ fcnt,
          const float* __restrict__ aTs, const float* __restrict__ a2f,
          const __half* __restrict__ R1h, const float* __restrict__ sR1,
          const __half* __restrict__ D1, const float* __restrict__ sD,
          const int* __restrict__ offs, const int* __restrict__ csr, __half* __restrict__ x1)
{
  __shared__ float en[100], ml[200], sS2[2];
  const int t = threadIdx.x;
  const int FC = fcnt[0];
  const int fdt = ifl[1];
  for (int bi = blockIdx.x; bi < FC; bi += gridDim.x){
    const int n = flist[bi];
    if (t < 100) en[t] = ldf(ent, (size_t)n*100 + t, fdt);
    __syncthreads();
    float S = 0.f;
    if (t < 200){
      for (int k = 0; k < 100; ++k) S += en[k]*aTs[k*200+t];
      ml[t] = S*a2f[t];
    }
    __syncthreads();
    if (t < 64){
      float s = 0.f;
      for (int q = t; q < 100; q += 64) s += ml[q];
      for (int o = 1; o < 64; o <<= 1) s += __shfl_xor(s, o);
      if (t == 0) sS2[0] = s;
    } else if (t < 128){
      int l = t - 64;
      float s = 0.f;
      for (int q = 100 + l; q < 200; q += 64) s += ml[q];
      for (int o = 1; o < 64; o <<= 1) s += __shfl_xor(s, o);
      if (l == 0) sS2[1] = s;
    }
    __syncthreads();
    if (t < 200){
      const int h = (t >= 100) ? 1 : 0;
      const float sS = sS2[h];
      float acc = 0.f, W = 0.f;
      const int beg = offs[n], end = offs[n+1];
      for (int j = beg; j < end; ++j){
        int pk = csr[j];
        int v = pk & 0xFFFF, tt = pk >> 16;
        float d = __half2float(D1[(size_t)v*200 + t]);
        float r = __half2float(R1h[tt*200 + t]);
        float p = sS + sD[(size_t)v*2 + h] + sR1[tt*2 + h];
        float lk = p > 0.f ? p : 0.2f*p;
        float w = expf(-lk);
        acc += w*(d + r); W += w;
      }
      float hh = (S*W + acc) / (W + 1e-12f);
      x1[(size_t)n*200 + t] = __float2half_rn(hh > 0.f ? hh : (expf(hh) - 1.f));
    }
    __syncthreads();
  }
}

// layer 2, masked nodes only
__global__ __launch_bounds__(256)
void k_x2m(const void* __restrict__ binp, const __half* __restrict__ x1, const float* __restrict__ aoTs,
           const float* __restrict__ a2of, const __half* __restrict__ R2h, const float* __restrict__ sR2,
           const __half* __restrict__ D2, const float* __restrict__ sD2, const int* __restrict__ ifl,
           const int* __restrict__ offs, const int* __restrict__ csr, float* __restrict__ x2m)
{
  __shared__ float xn[200], ml[200], sS2[1];
  const int i = blockIdx.x, t = threadIdx.x;
  const int n = ild(binp, (size_t)i*4 + 2, ifl[0]);
  if (t < 200) xn[t] = __half2float(x1[(size_t)n*200 + t]);
  __syncthreads();
  float S = 0.f;
  if (t < 200){
    for (int k = 0; k < 200; ++k) S += xn[k]*aoTs[k*200+t];
    ml[t] = S*a2of[t];
  }
  __syncthreads();
  if (t < 64){
    float s = 0.f;
    for (int q = t; q < 200; q += 64) s += ml[q];
    for (int o = 1; o < 64; o <<= 1) s += __shfl_xor(s, o);
    if (t == 0) sS2[0] = s;
  }
  __syncthreads();
  if (t >= 200) return;
  const float sS = sS2[0];
  float acc = 0.f, W = 0.f;
  const int beg = offs[n], end = offs[n+1];
  for (int j = beg; j < end; ++j){
    int pk = csr[j];
    int v = pk & 0xFFFF, tt = pk >> 16;
    float d = __half2float(D2[(size_t)v*200 + t]);
    float r = __half2float(R2h[tt*200 + t]);
    float p = sS + sD2[v] + sR2[tt];
    float lk = p > 0.f ? p : 0.2f*p;
    float w = expf(-lk);
    acc += w*(d + r); W += w;
  }
  float hh = (S*W + acc) / (W + 1e-12f);
  x2m[(size_t)i*200 + t] = hh > 0.f ? hh : (expf(hh) - 1.f);
}

// ---------------- his_temp: LDS tile + 16B vector stores ----------------
__global__ __launch_bounds__(256)
void k_his(const void* __restrict__ binp, const void* __restrict__ wt, const void* __restrict__ bt,
           const int* __restrict__ ifl, char* __restrict__ dout)
{
  __shared__ float he[100];
  __shared__ uint4 tile[50];
  const int i = blockIdx.x, t = threadIdx.x;
  const int fdt = ifl[1];
  const double t2 = (double)ild(binp, (size_t)i*4 + 3, ifl[0]);
  if (t < 100){
    double a = t2 * (double)ldf(wt, t, fdt) + (double)ldf(bt, t, fdt);
    he[t] = (float)cos(a);
  }
  __syncthreads();
  if (fdt == 0){
    float* tf = (float*)tile;          // 100 floats = 25 uint4, period 100
    if (t < 100) tf[t] = he[t];
    __syncthreads();
    uint4* out4 = (uint4*)(dout + 40000000 + (size_t)i*204800);
    for (int idx = t; idx < 12800; idx += 256) out4[idx] = tile[idx % 25];
  } else {
    unsigned short* th = (unsigned short*)tile;   // 400 halves = 50 uint4, period 400
    for (int j = t; j < 400; j += 256){
      float v = he[j % 100];
      th[j] = (fdt == 2) ? __builtin_bit_cast(unsigned short, __float2half_rn(v)) : f2bf(v);
    }
    __syncthreads();
    uint4* out4 = (uint4*)(dout + 20000000 + (size_t)i*102400);
    for (int idx = t; idx < 6400; idx += 256) out4[idx] = tile[idx % 50];
  }
}

// ---------------- launch ----------------
extern "C" void kernel_launch(void* const* d_in, const int* in_sizes, int n_in,
                              void* d_out, int out_size, void* d_ws, size_t ws_size,
                              hipStream_t stream)
{
  (void)in_sizes; (void)n_in; (void)out_size; (void)ws_size;
  const void* ent  = d_in[0];
  const void* rtab = d_in[1];
  const void* w_t2 = d_in[2];
  const void* b_t2 = d_in[3];
  const void* Went = d_in[4];
  const void* ah   = d_in[5];
  const void* a2h  = d_in[6];
  const void* Wrel = d_in[7];
  const void* aout = d_in[8];
  const void* a2o  = d_in[9];
  const void* elist = d_in[10];
  const void* etype = d_in[11];
  const void* binp  = d_in[12];

  int* ifl = (int*)d_ws;                         // [0]=int64 flag, [1]=float dtype

  char* dout = (char*)d_out;
  // Region A [20MB,40MB): D1 then D2 (fp16). [0,20MB) unused scratch now.
  __half* D12 = (__half*)(dout + 20000000);
  // Region B [40MB,~66MB): consumed by kernels up to k_gemmEuf; inside out1 for all dtypes.
  char* scr = dout + 40000000;
  size_t cur = 0;
  auto alloc = [&](size_t bytes) -> char* {
    char* p = scr + cur;
    cur = (cur + bytes + 255) & ~(size_t)255;
    return p;
  };
  __half* X1     = (__half*)alloc((size_t)N_NODES*200*2);   // 20 MB
  int*   csr     = (int*)alloc((size_t)E_EDGES*4);          // 3.2 MB
  int*   offs    = (int*)alloc((size_t)(N_NODES+1)*4);
  int*   cnt     = (int*)alloc((size_t)N_NODES*4);
  int*   midx    = (int*)alloc((size_t)N_NODES*4);
  int*   nflag   = (int*)alloc((size_t)N_NODES*4);
  int*   flist   = (int*)alloc((size_t)N_NODES*4);
  int*   fcnt    = (int*)alloc(256);
  int*   bsum    = (int*)alloc(1024);
  float* invn    = (float*)alloc((size_t)N_NODES*4);
  float* x2m     = (float*)alloc((size_t)B_BATCH*200*4);
  float* aTs     = (float*)alloc((size_t)100*200*4);
  float* aoTs    = (float*)alloc((size_t)200*200*4);
  float* aTr     = (float*)alloc((size_t)100*200*4);
  float* aoTr    = (float*)alloc((size_t)200*200*4);
  __half* R1h    = (__half*)alloc((size_t)200*200*2);
  __half* R2h    = (__half*)alloc((size_t)200*200*2);
  float* sD      = (float*)alloc((size_t)N_NODES*2*4);
  float* sD2     = (float*)alloc((size_t)N_NODES*4);
  float* sR1     = (float*)alloc((size_t)200*2*4);
  float* sR2     = (float*)alloc((size_t)200*4);
  float* a2f     = (float*)alloc((size_t)200*4);
  float* a2of    = (float*)alloc((size_t)200*4);
  unsigned short* WswE  = (unsigned short*)alloc((size_t)26624*2);  // MFMA B-frag tables
  unsigned short* WswD  = (unsigned short*)alloc((size_t)26624*2);
  unsigned short* WswD2 = (unsigned short*)alloc((size_t)46592*2);
  // total ~26.6 MB -> ends ~66.6 MB < 72.4 MB (min d_out at esize=2)

  const int EB = (E_EDGES + 255) / 256;
  const int NB = (N_NODES + 255) / 256;        // 196

  k_init <<<dim3(NB + 1), dim3(256), 0, stream>>>((const unsigned short*)ent, (const unsigned int*)ent,
                                                  (const unsigned int*)elist, midx, cnt, nflag, fcnt, ifl);
  k_mset <<<dim3(2), dim3(256), 0, stream>>>(binp, ifl, midx, nflag, fcnt, flist);
  k_setup<<<dim3(12500 + 861), dim3(256), 0, stream>>>(ent, ah, aout, a2h, a2o, Went, ifl,
                                                       invn, aTs, aoTs, aTr, aoTr, a2f, a2of,
                                                       WswE, WswD, WswD2);
  k_rel  <<<dim3(400), dim3(256), 0, stream>>>(rtab, Wrel, etype, ifl, aTr, aoTr,
                                               a2f, a2of, R1h, sR1, R2h, sR2);

  k_count<<<dim3(EB), dim3(256), 0, stream>>>(elist, ifl, cnt);
  k_scanA<<<dim3(NB), dim3(256), 0, stream>>>(cnt, offs, bsum);
  k_scanC<<<dim3(NB), dim3(256), 0, stream>>>(offs, bsum);
  k_scatter<<<dim3(EB), dim3(256), 0, stream>>>(elist, etype, ifl, offs, cnt, csr);

  k_flag <<<dim3(B_BATCH), dim3(256), 0, stream>>>(binp, ifl, offs, csr, nflag, fcnt, flist);

  k_gemmD1<<<dim3(782), dim3(256), 0, stream>>>(ent, ifl, WswD, a2f, D12, sD);
  k_x1 <<<dim3(12288), dim3(256), 0, stream>>>(ent, ifl, flist, fcnt, aTs, a2f, R1h, sR1, D12, sD, offs, csr, X1);
  k_D2g<<<dim3(782), dim3(256), 0, stream>>>(X1, flist, fcnt, WswD2, a2of, D12, sD2);
  k_x2m<<<dim3(B_BATCH), dim3(256), 0, stream>>>(binp, X1, aoTs, a2of, R2h, sR2, D12, sD2, ifl, offs, csr, x2m);
  k_gemmEuf<<<dim3(782), dim3(256), 0, stream>>>(ent, ifl, WswE, invn, midx, x2m, dout);

  // LAST: overwrites all of out1 (incl. all scratch); reads only inputs + ifl
  k_his<<<dim3(B_BATCH), dim3(256), 0, stream>>>(binp, w_t2, b_t2, ifl, dout);
}